// Round 1
// baseline (16997.914 us; speedup 1.0000x reference)
//
#include <hip/hip_runtime.h>
#include <hip/hip_bf16.h>
#include <math.h>

#define N_TOK 2048
#define DIM   2048
#define NH    16
#define NOPE  128
#define ROPE_D 64
#define QKH   192   // NOPE + ROPE
#define VH    128
#define KVR   512
#define INTER 5632
#define VOCAB 32000
#define NLAYER 2
#define EPS   1e-6f

// ---------------- embedding gather ----------------
__global__ void k_embed(const int* __restrict__ tokens, const float* __restrict__ emb,
                        float* __restrict__ h) {
    int n = blockIdx.x;
    int t = tokens[n];
    const float4* src = (const float4*)(emb + (size_t)t * DIM);
    float4* dst = (float4*)(h + (size_t)n * DIM);
    for (int i = threadIdx.x; i < DIM / 4; i += blockDim.x) dst[i] = src[i];
}

// ---------------- rmsnorm (row-wise) ----------------
__global__ __launch_bounds__(256) void k_rmsnorm(const float* __restrict__ in, int in_stride, int in_off,
                                                 float* __restrict__ out, const float* __restrict__ w,
                                                 int len) {
    int row = blockIdx.x;
    const float* x = in + (size_t)row * in_stride + in_off;
    float ss = 0.f;
    for (int i = threadIdx.x; i < len; i += 256) { float v = x[i]; ss += v * v; }
    for (int off = 32; off > 0; off >>= 1) ss += __shfl_down(ss, off, 64);
    __shared__ float red[4];
    if ((threadIdx.x & 63) == 0) red[threadIdx.x >> 6] = ss;
    __syncthreads();
    float tot = red[0] + red[1] + red[2] + red[3];
    float inv = rsqrtf(tot / (float)len + EPS);
    for (int i = threadIdx.x; i < len; i += 256)
        out[(size_t)row * len + i] = x[i] * inv * w[i];
}

// ---------------- rope on q (all heads), in place ----------------
__global__ void k_rope_q(float* __restrict__ q, const float* __restrict__ cosb,
                         const float* __restrict__ sinb) {
    int idx = blockIdx.x * blockDim.x + threadIdx.x;  // N*NH*32 total
    int i = idx & 31;
    int hh = (idx >> 5) & (NH - 1);
    int n = idx >> 9;
    float c = cosb[n * 32 + i], s = sinb[n * 32 + i];
    float* p = q + (size_t)n * (NH * QKH) + hh * QKH + NOPE + 2 * i;
    float xr = p[0], xi = p[1];
    p[0] = xr * c - xi * s;
    p[1] = xr * s + xi * c;
}

// ---------------- rope on k_rope (1 head) ----------------
__global__ void k_rope_k(const float* __restrict__ kv, const float* __restrict__ cosb,
                         const float* __restrict__ sinb, float* __restrict__ krope) {
    int idx = blockIdx.x * blockDim.x + threadIdx.x;  // N*32 total
    int i = idx & 31;
    int n = idx >> 5;
    float c = cosb[n * 32 + i], s = sinb[n * 32 + i];
    const float* p = kv + (size_t)n * (ROPE_D + KVR) + 2 * i;
    float xr = p[0], xi = p[1];
    krope[n * ROPE_D + 2 * i] = xr * c - xi * s;
    krope[n * ROPE_D + 2 * i + 1] = xr * s + xi * c;
}

// ---------------- f32 tiled GEMM: C = A@B (+C) ----------------
// A: MxK row-major, B: KxN row-major, C: MxN row-major. All dims multiples of tile.
#define BM 64
#define BN 64
#define BK 16
__global__ __launch_bounds__(256) void k_gemm(const float* __restrict__ A, const float* __restrict__ B,
                                              float* __restrict__ C, int M, int Nc, int K,
                                              int accumulate) {
    __shared__ float As[BK][BM + 4];
    __shared__ float Bs[BK][BN];
    int tid = threadIdx.x;
    int row0 = blockIdx.y * BM;
    int col0 = blockIdx.x * BN;
    int tx = tid & 15, ty = tid >> 4;
    float acc[4][4] = {};
    for (int k0 = 0; k0 < K; k0 += BK) {
        {
            int r = tid >> 2, kc = (tid & 3) * 4;
            float4 v = *(const float4*)(A + (size_t)(row0 + r) * K + k0 + kc);
            As[kc + 0][r] = v.x; As[kc + 1][r] = v.y; As[kc + 2][r] = v.z; As[kc + 3][r] = v.w;
        }
        {
            int r = tid >> 4, c = (tid & 15) * 4;
            *(float4*)&Bs[r][c] = *(const float4*)(B + (size_t)(k0 + r) * Nc + col0 + c);
        }
        __syncthreads();
#pragma unroll
        for (int k = 0; k < BK; ++k) {
            float4 a4 = *(const float4*)&As[k][ty * 4];
            float4 b4 = *(const float4*)&Bs[k][tx * 4];
            float a[4] = {a4.x, a4.y, a4.z, a4.w};
            float b[4] = {b4.x, b4.y, b4.z, b4.w};
#pragma unroll
            for (int i = 0; i < 4; ++i)
#pragma unroll
                for (int j = 0; j < 4; ++j) acc[i][j] += a[i] * b[j];
        }
        __syncthreads();
    }
#pragma unroll
    for (int i = 0; i < 4; ++i) {
        float* cp = C + (size_t)(row0 + ty * 4 + i) * Nc + col0 + tx * 4;
        if (accumulate) {
            cp[0] += acc[i][0]; cp[1] += acc[i][1]; cp[2] += acc[i][2]; cp[3] += acc[i][3];
        } else {
            *(float4*)cp = make_float4(acc[i][0], acc[i][1], acc[i][2], acc[i][3]);
        }
    }
}

// ---------------- causal attention, one block per (q-row, head) ----------------
__global__ __launch_bounds__(256) void k_attn(const float* __restrict__ q,
                                              const float* __restrict__ kvb,
                                              const float* __restrict__ krope,
                                              float* __restrict__ o) {
    int n = blockIdx.x, hh = blockIdx.y;
    __shared__ __align__(16) float sc[N_TOK];
    __shared__ __align__(16) float qs[QKH];
    __shared__ float red[4];
    __shared__ float part[256];
    int tid = threadIdx.x;
    if (tid < QKH) qs[tid] = q[(size_t)n * (NH * QKH) + hh * QKH + tid];
    __syncthreads();
    const float scale = 1.0f / sqrtf((float)QKH);
    float lmax = -1e30f;
    const float4* qs4 = (const float4*)qs;
    for (int j = tid; j <= n; j += 256) {
        const float4* kn4 = (const float4*)(kvb + (size_t)j * (NH * (NOPE + VH)) + hh * (NOPE + VH));
        float d = 0.f;
#pragma unroll 8
        for (int i = 0; i < NOPE / 4; ++i) {
            float4 a = qs4[i], b = kn4[i];
            d += a.x * b.x + a.y * b.y + a.z * b.z + a.w * b.w;
        }
        const float4* kr4 = (const float4*)(krope + (size_t)j * ROPE_D);
#pragma unroll 8
        for (int i = 0; i < ROPE_D / 4; ++i) {
            float4 a = qs4[NOPE / 4 + i], b = kr4[i];
            d += a.x * b.x + a.y * b.y + a.z * b.z + a.w * b.w;
        }
        d *= scale;
        sc[j] = d;
        lmax = fmaxf(lmax, d);
    }
    for (int off = 32; off > 0; off >>= 1) lmax = fmaxf(lmax, __shfl_down(lmax, off, 64));
    if ((tid & 63) == 0) red[tid >> 6] = lmax;
    __syncthreads();
    float m = fmaxf(fmaxf(red[0], red[1]), fmaxf(red[2], red[3]));
    __syncthreads();
    float lsum = 0.f;
    for (int j = tid; j <= n; j += 256) { float e = expf(sc[j] - m); sc[j] = e; lsum += e; }
    for (int off = 32; off > 0; off >>= 1) lsum += __shfl_down(lsum, off, 64);
    if ((tid & 63) == 0) red[tid >> 6] = lsum;
    __syncthreads();
    float denom = red[0] + red[1] + red[2] + red[3];
    int d = tid & 127, half = tid >> 7;
    float acc = 0.f;
    for (int j = half; j <= n; j += 2)
        acc += sc[j] * kvb[(size_t)j * (NH * (NOPE + VH)) + hh * (NOPE + VH) + NOPE + d];
    part[tid] = acc;
    __syncthreads();
    if (tid < 128)
        o[(size_t)n * (NH * VH) + hh * VH + d] = (part[tid] + part[tid + 128]) / denom;
}

// ---------------- silu(a)*b -> a ----------------
__global__ void k_silu(float* __restrict__ a, const float* __restrict__ b, int n) {
    int i = blockIdx.x * blockDim.x + threadIdx.x;
    int stride = gridDim.x * blockDim.x;
    for (; i < n; i += stride) {
        float x = a[i];
        float s = x / (1.f + expf(-x));
        a[i] = s * b[i];
    }
}

static inline void gemm(const float* A, const float* B, float* C, int M, int Nc, int K,
                        int accumulate, hipStream_t stream) {
    dim3 grid(Nc / BN, M / BM);
    k_gemm<<<grid, 256, 0, stream>>>(A, B, C, M, Nc, K, accumulate);
}

extern "C" void kernel_launch(void* const* d_in, const int* in_sizes, int n_in,
                              void* d_out, int out_size, void* d_ws, size_t ws_size,
                              hipStream_t stream) {
    (void)in_sizes; (void)n_in; (void)out_size; (void)ws_size;
    const int* tokens = (const int*)d_in[0];
    const float* emb = (const float*)d_in[1];
    const float* qW = (const float*)d_in[2];
    const float* kvaW = (const float*)d_in[3];
    const float* kvnorm_w = (const float*)d_in[4];
    const float* kvbW = (const float*)d_in[5];
    const float* oW = (const float*)d_in[6];
    const float* w1 = (const float*)d_in[7];
    const float* w2 = (const float*)d_in[8];
    const float* w3 = (const float*)d_in[9];
    const float* attn_norm_w = (const float*)d_in[10];
    const float* ffn_norm_w = (const float*)d_in[11];
    const float* norm_w = (const float*)d_in[12];
    const float* outW = (const float*)d_in[13];
    const float* rope_cos = (const float*)d_in[14];
    const float* rope_sin = (const float*)d_in[15];

    float* ws = (float*)d_ws;
    float* h     = ws;
    float* x     = h + (size_t)N_TOK * DIM;
    float* buf1  = x + (size_t)N_TOK * DIM;           // q (N x 3072) or t1 (N x INTER)
    float* buf2  = buf1 + (size_t)N_TOK * INTER;      // kvb (N x 4096) or t2 (N x INTER)
    float* kv    = buf2 + (size_t)N_TOK * INTER;      // N x 576
    float* cbuf  = kv + (size_t)N_TOK * (ROPE_D + KVR);  // N x 512
    float* krope = cbuf + (size_t)N_TOK * KVR;        // N x 64

    k_embed<<<N_TOK, 256, 0, stream>>>(tokens, emb, h);

    for (int l = 0; l < NLAYER; ++l) {
        k_rmsnorm<<<N_TOK, 256, 0, stream>>>(h, DIM, 0, x, attn_norm_w + (size_t)l * DIM, DIM);
        gemm(x, qW + (size_t)l * DIM * (NH * QKH), buf1, N_TOK, NH * QKH, DIM, 0, stream);
        gemm(x, kvaW + (size_t)l * DIM * (ROPE_D + KVR), kv, N_TOK, ROPE_D + KVR, DIM, 0, stream);
        k_rope_q<<<N_TOK * NH * 32 / 256, 256, 0, stream>>>(buf1, rope_cos, rope_sin);
        k_rope_k<<<N_TOK * 32 / 256, 256, 0, stream>>>(kv, rope_cos, rope_sin, krope);
        k_rmsnorm<<<N_TOK, 256, 0, stream>>>(kv, ROPE_D + KVR, ROPE_D, cbuf,
                                             kvnorm_w + (size_t)l * KVR, KVR);
        gemm(cbuf, kvbW + (size_t)l * KVR * (NH * (NOPE + VH)), buf2, N_TOK,
             NH * (NOPE + VH), KVR, 0, stream);
        k_attn<<<dim3(N_TOK, NH), 256, 0, stream>>>(buf1, buf2, krope, x);
        gemm(x, oW + (size_t)l * (NH * VH) * DIM, h, N_TOK, DIM, NH * VH, 1, stream);
        k_rmsnorm<<<N_TOK, 256, 0, stream>>>(h, DIM, 0, x, ffn_norm_w + (size_t)l * DIM, DIM);
        gemm(x, w1 + (size_t)l * DIM * INTER, buf1, N_TOK, INTER, DIM, 0, stream);
        gemm(x, w2 + (size_t)l * DIM * INTER, buf2, N_TOK, INTER, DIM, 0, stream);
        k_silu<<<2048, 256, 0, stream>>>(buf1, buf2, N_TOK * INTER);
        gemm(buf1, w3 + (size_t)l * INTER * DIM, h, N_TOK, DIM, INTER, 1, stream);
    }
    k_rmsnorm<<<N_TOK, 256, 0, stream>>>(h, DIM, 0, x, norm_w, DIM);
    gemm(x, outW, (float*)d_out, N_TOK, VOCAB, DIM, 0, stream);
}

// Round 2
// 6000.036 us; speedup vs baseline: 2.8330x; 2.8330x over previous
//
#include <hip/hip_runtime.h>
#include <hip/hip_bf16.h>
#include <math.h>

#define N_TOK 2048
#define DIM   2048
#define NH    16
#define NOPE  128
#define ROPE_D 64
#define QKH   192
#define VH    128
#define KVR   512
#define INTER 5632
#define VOCAB 32000
#define NLAYER 2
#define EPS   1e-6f
#define KVBW  (NH * (NOPE + VH))   // 4096

typedef __bf16 bf16x8 __attribute__((ext_vector_type(8)));
typedef float  f32x4  __attribute__((ext_vector_type(4)));

__device__ __forceinline__ short f2bf(float f) {
    union { float f; unsigned u; } a; a.f = f;
    return (short)((a.u + 0x7fffu + ((a.u >> 16) & 1u)) >> 16);
}

// ---------------- embedding gather ----------------
__global__ void k_embed(const int* __restrict__ tokens, const float* __restrict__ emb,
                        float* __restrict__ h) {
    int n = blockIdx.x;
    int t = tokens[n];
    const float4* src = (const float4*)(emb + (size_t)t * DIM);
    float4* dst = (float4*)(h + (size_t)n * DIM);
    for (int i = threadIdx.x; i < DIM / 4; i += blockDim.x) dst[i] = src[i];
}

// ---------------- rmsnorm (row-wise) ----------------
__global__ __launch_bounds__(256) void k_rmsnorm(const float* __restrict__ in, int in_stride, int in_off,
                                                 float* __restrict__ out, const float* __restrict__ w,
                                                 int len) {
    int row = blockIdx.x;
    const float* x = in + (size_t)row * in_stride + in_off;
    float ss = 0.f;
    for (int i = threadIdx.x; i < len; i += 256) { float v = x[i]; ss += v * v; }
    for (int off = 32; off > 0; off >>= 1) ss += __shfl_down(ss, off, 64);
    __shared__ float red[4];
    if ((threadIdx.x & 63) == 0) red[threadIdx.x >> 6] = ss;
    __syncthreads();
    float tot = red[0] + red[1] + red[2] + red[3];
    float inv = rsqrtf(tot / (float)len + EPS);
    for (int i = threadIdx.x; i < len; i += 256)
        out[(size_t)row * len + i] = x[i] * inv * w[i];
}

// ---------------- rope on q (all heads), in place ----------------
__global__ void k_rope_q(float* __restrict__ q, const float* __restrict__ cosb,
                         const float* __restrict__ sinb) {
    int idx = blockIdx.x * blockDim.x + threadIdx.x;
    int i = idx & 31;
    int hh = (idx >> 5) & (NH - 1);
    int n = idx >> 9;
    float c = cosb[n * 32 + i], s = sinb[n * 32 + i];
    float* p = q + (size_t)n * (NH * QKH) + hh * QKH + NOPE + 2 * i;
    float xr = p[0], xi = p[1];
    p[0] = xr * c - xi * s;
    p[1] = xr * s + xi * c;
}

// ---------------- rope on k_rope (1 head) ----------------
__global__ void k_rope_k(const float* __restrict__ kv, const float* __restrict__ cosb,
                         const float* __restrict__ sinb, float* __restrict__ krope) {
    int idx = blockIdx.x * blockDim.x + threadIdx.x;
    int i = idx & 31;
    int n = idx >> 5;
    float c = cosb[n * 32 + i], s = sinb[n * 32 + i];
    const float* p = kv + (size_t)n * (ROPE_D + KVR) + 2 * i;
    float xr = p[0], xi = p[1];
    krope[n * ROPE_D + 2 * i] = xr * c - xi * s;
    krope[n * ROPE_D + 2 * i + 1] = xr * s + xi * c;
}

// ---------------- pack K_all[h][key][192] = concat(k_nope, k_rope) ----------------
__global__ void k_pack_K(const float* __restrict__ kvb, const float* __restrict__ krope,
                         float* __restrict__ Kall) {
    int key = blockIdx.x;
    for (int idx = threadIdx.x; idx < NH * QKH; idx += 256) {
        int h = idx / QKH, d = idx - h * QKH;
        float v = (d < NOPE) ? kvb[(size_t)key * KVBW + h * (NOPE + VH) + d]
                             : krope[(size_t)key * ROPE_D + (d - NOPE)];
        Kall[(size_t)h * N_TOK * QKH + (size_t)key * QKH + d] = v;
    }
}

// ---------------- bf16 MFMA GEMM, 128x128 tile, 4 waves ----------------
// C[M,N] = A[M,K] @ B[K,N] (BT: B stored as [N,K] row-major).
// ACC: C += ; CSKIP: skip blocks fully above causal diagonal; CKLIM: truncate K at row0+128.
template<int BT, int ACC, int CSKIP, int CKLIM>
__global__ __launch_bounds__(256)
void k_mm(const float* __restrict__ A, const float* __restrict__ B, float* __restrict__ C,
          int M, int N, int K, int lda, int ldb, int ldc,
          long long aoffz, long long boffz, long long coffz) {
    A += (long long)blockIdx.z * aoffz;
    B += (long long)blockIdx.z * boffz;
    C += (long long)blockIdx.z * coffz;
    int row0 = blockIdx.y * 128, col0 = blockIdx.x * 128;
    if (CSKIP && col0 > row0 + 127) return;
    int kend = CKLIM ? min(K, row0 + 128) : K;

    __shared__ short As[128][40];
    __shared__ short Bs[128][40];
    int tid = threadIdx.x;
    int lane = tid & 63, wave = tid >> 6;
    int wm = (wave & 1) * 64, wn = (wave >> 1) * 64;
    int fr = lane & 15, fg = lane >> 4;

    f32x4 acc[4][4] = {};

    for (int k0 = 0; k0 < kend; k0 += 32) {
        // stage A (f32 -> bf16), [m][k] layout
#pragma unroll
        for (int it = 0; it < 4; ++it) {
            int idx = tid + it * 256;
            int m = idx >> 3, c = idx & 7;
            float4 v = *(const float4*)(A + (size_t)(row0 + m) * lda + k0 + c * 4);
            short4 s4 = { f2bf(v.x), f2bf(v.y), f2bf(v.z), f2bf(v.w) };
            *(short4*)&As[m][c * 4] = s4;
        }
        // stage B -> Bs[n][k] (transposed layout for fragment reads)
        if (BT) {
#pragma unroll
            for (int it = 0; it < 4; ++it) {
                int idx = tid + it * 256;
                int n = idx >> 3, c = idx & 7;
                float4 v = *(const float4*)(B + (size_t)(col0 + n) * ldb + k0 + c * 4);
                short4 s4 = { f2bf(v.x), f2bf(v.y), f2bf(v.z), f2bf(v.w) };
                *(short4*)&Bs[n][c * 4] = s4;
            }
        } else {
            int nb = tid & 31, kb = (tid >> 5) * 4;
#pragma unroll
            for (int j = 0; j < 4; ++j) {
                int n = nb + 32 * j;
                short4 s4;
#pragma unroll
                for (int i = 0; i < 4; ++i) {
                    float v = 0.f;
                    if (col0 + n < N) v = B[(size_t)(k0 + kb + i) * ldb + col0 + n];
                    ((short*)&s4)[i] = f2bf(v);
                }
                *(short4*)&Bs[n][kb] = s4;
            }
        }
        __syncthreads();
        bf16x8 av[4], bv[4];
#pragma unroll
        for (int i = 0; i < 4; ++i) {
            av[i] = *(const bf16x8*)&As[wm + i * 16 + fr][fg * 8];
            bv[i] = *(const bf16x8*)&Bs[wn + i * 16 + fr][fg * 8];
        }
#pragma unroll
        for (int i = 0; i < 4; ++i)
#pragma unroll
            for (int j = 0; j < 4; ++j)
                acc[i][j] = __builtin_amdgcn_mfma_f32_16x16x32_bf16(av[i], bv[j], acc[i][j], 0, 0, 0);
        __syncthreads();
    }
#pragma unroll
    for (int i = 0; i < 4; ++i)
#pragma unroll
        for (int j = 0; j < 4; ++j)
#pragma unroll
            for (int q = 0; q < 4; ++q) {
                int row = row0 + wm + i * 16 + fg * 4 + q;
                int col = col0 + wn + j * 16 + fr;
                if (col < N) {
                    float* cp = C + (size_t)row * ldc + col;
                    if (ACC) *cp += acc[i][j][q]; else *cp = acc[i][j][q];
                }
            }
}

// ---------------- causal row softmax on S (f32, in place, scale folded) ----------------
__global__ __launch_bounds__(256) void k_softmax(float* __restrict__ S) {
    int r = blockIdx.x;
    float* p = S + (size_t)blockIdx.y * N_TOK * N_TOK + (size_t)r * N_TOK;
    const float scale = 0.07216878364870322f;  // 1/sqrt(192)
    int tid = threadIdx.x;
    float sv[8];
    float m = -1e30f;
#pragma unroll
    for (int jj = 0; jj < 8; ++jj) {
        int j = tid + jj * 256;
        sv[jj] = (j <= r) ? p[j] : -1e30f;
        m = fmaxf(m, sv[jj]);
    }
    for (int off = 32; off > 0; off >>= 1) m = fmaxf(m, __shfl_down(m, off, 64));
    __shared__ float red[4];
    if ((tid & 63) == 0) red[tid >> 6] = m;
    __syncthreads();
    m = fmaxf(fmaxf(red[0], red[1]), fmaxf(red[2], red[3]));
    __syncthreads();
    float sum = 0.f;
#pragma unroll
    for (int jj = 0; jj < 8; ++jj) {
        int j = tid + jj * 256;
        sv[jj] = (j <= r) ? __expf((sv[jj] - m) * scale) : 0.f;
        sum += sv[jj];
    }
    for (int off = 32; off > 0; off >>= 1) sum += __shfl_down(sum, off, 64);
    if ((tid & 63) == 0) red[tid >> 6] = sum;
    __syncthreads();
    float inv = 1.f / (red[0] + red[1] + red[2] + red[3]);
#pragma unroll
    for (int jj = 0; jj < 8; ++jj) {
        int j = tid + jj * 256;
        p[j] = sv[jj] * inv;
    }
}

// ---------------- silu(a)*b -> a ----------------
__global__ void k_silu(float* __restrict__ a, const float* __restrict__ b, int n) {
    int i = blockIdx.x * blockDim.x + threadIdx.x;
    int stride = gridDim.x * blockDim.x;
    for (; i < n; i += stride) {
        float x = a[i];
        a[i] = x / (1.f + __expf(-x)) * b[i];
    }
}

static inline void mm(const float* A, const float* B, float* C, int M, int N, int K,
                      int lda, int ldb, int ldc, int acc, hipStream_t s) {
    dim3 g((N + 127) / 128, M / 128, 1);
    if (acc) k_mm<0, 1, 0, 0><<<g, 256, 0, s>>>(A, B, C, M, N, K, lda, ldb, ldc, 0, 0, 0);
    else     k_mm<0, 0, 0, 0><<<g, 256, 0, s>>>(A, B, C, M, N, K, lda, ldb, ldc, 0, 0, 0);
}

extern "C" void kernel_launch(void* const* d_in, const int* in_sizes, int n_in,
                              void* d_out, int out_size, void* d_ws, size_t ws_size,
                              hipStream_t stream) {
    (void)in_sizes; (void)n_in; (void)out_size;
    const int* tokens = (const int*)d_in[0];
    const float* emb = (const float*)d_in[1];
    const float* qW = (const float*)d_in[2];
    const float* kvaW = (const float*)d_in[3];
    const float* kvnorm_w = (const float*)d_in[4];
    const float* kvbW = (const float*)d_in[5];
    const float* oW = (const float*)d_in[6];
    const float* w1 = (const float*)d_in[7];
    const float* w2 = (const float*)d_in[8];
    const float* w3 = (const float*)d_in[9];
    const float* attn_norm_w = (const float*)d_in[10];
    const float* ffn_norm_w = (const float*)d_in[11];
    const float* norm_w = (const float*)d_in[12];
    const float* outW = (const float*)d_in[13];
    const float* rope_cos = (const float*)d_in[14];
    const float* rope_sin = (const float*)d_in[15];

    const size_t H_E = (size_t)N_TOK * DIM;            // 4.19M
    const size_t KV_E = (size_t)N_TOK * (ROPE_D + KVR);
    const size_t CB_E = (size_t)N_TOK * KVR;
    const size_t KR_E = (size_t)N_TOK * ROPE_D;
    const size_t KVB_E = (size_t)N_TOK * KVBW;
    const size_t Q_E = (size_t)N_TOK * NH * QKH;       // 6.29M
    const size_t KA_E = (size_t)NH * N_TOK * QKH;      // 6.29M
    const size_t AO_E = (size_t)N_TOK * NH * VH;       // 4.19M
    const size_t FFN_E = (size_t)N_TOK * INTER;        // 11.53M
    const size_t S_H = (size_t)N_TOK * N_TOK;          // 4.19M per head

    float* ws = (float*)d_ws;
    float* h = ws;
    float* x = h + H_E;
    float* kv = x + H_E;
    float* cbuf = kv + KV_E;
    float* krope = cbuf + CB_E;
    float* kvb = krope + KR_E;
    float* region = kvb + KVB_E;
    size_t fixed = (size_t)(region - ws);
    size_t avail = ws_size / 4 > fixed ? ws_size / 4 - fixed : 0;

    int ch = 1;
    {
        int cands[5] = {16, 8, 4, 2, 1};
        for (int ci = 0; ci < 5; ++ci) {
            size_t need = Q_E + KA_E + AO_E + (size_t)cands[ci] * S_H;
            size_t ffn_need = 2 * FFN_E;
            size_t tot = need > ffn_need ? need : ffn_need;
            if (avail >= tot) { ch = cands[ci]; break; }
        }
    }
    float* q = region;
    float* Kall = q + Q_E;
    float* attn_out = Kall + KA_E;
    float* S = attn_out + AO_E;
    float* ffn1 = region;           // aliases q/Kall (dead during FFN)
    float* ffn2 = region + FFN_E;   // aliases attn_out/S (dead during FFN)

    k_embed<<<N_TOK, 256, 0, stream>>>(tokens, emb, h);

    for (int l = 0; l < NLAYER; ++l) {
        k_rmsnorm<<<N_TOK, 256, 0, stream>>>(h, DIM, 0, x, attn_norm_w + (size_t)l * DIM, DIM);
        mm(x, qW + (size_t)l * DIM * NH * QKH, q, N_TOK, NH * QKH, DIM, DIM, NH * QKH, NH * QKH, 0, stream);
        mm(x, kvaW + (size_t)l * DIM * (ROPE_D + KVR), kv, N_TOK, ROPE_D + KVR, DIM,
           DIM, ROPE_D + KVR, ROPE_D + KVR, 0, stream);
        k_rope_q<<<N_TOK * NH * 32 / 256, 256, 0, stream>>>(q, rope_cos, rope_sin);
        k_rope_k<<<N_TOK * 32 / 256, 256, 0, stream>>>(kv, rope_cos, rope_sin, krope);
        k_rmsnorm<<<N_TOK, 256, 0, stream>>>(kv, ROPE_D + KVR, ROPE_D, cbuf,
                                             kvnorm_w + (size_t)l * KVR, KVR);
        mm(cbuf, kvbW + (size_t)l * KVR * KVBW, kvb, N_TOK, KVBW, KVR, KVR, KVBW, KVBW, 0, stream);
        k_pack_K<<<N_TOK, 256, 0, stream>>>(kvb, krope, Kall);

        for (int c = 0; c < NH / ch; ++c) {
            int h0 = c * ch;
            // S = Q_h @ K_h^T  (skip blocks above diagonal)
            k_mm<1, 0, 1, 0><<<dim3(16, 16, ch), 256, 0, stream>>>(
                q + (size_t)h0 * QKH, Kall + (size_t)h0 * N_TOK * QKH, S,
                N_TOK, N_TOK, QKH, NH * QKH, QKH, N_TOK,
                QKH, (long long)N_TOK * QKH, (long long)S_H);
            k_softmax<<<dim3(N_TOK, ch), 256, 0, stream>>>(S);
            // O_h = P @ V_h   (K-loop truncated at diagonal)
            k_mm<0, 0, 0, 1><<<dim3(1, 16, ch), 256, 0, stream>>>(
                S, kvb + (size_t)h0 * (NOPE + VH) + NOPE, attn_out + (size_t)h0 * VH,
                N_TOK, VH, N_TOK, N_TOK, KVBW, NH * VH,
                (long long)S_H, NOPE + VH, VH);
        }
        mm(attn_out, oW + (size_t)l * NH * VH * DIM, h, N_TOK, DIM, NH * VH,
           NH * VH, DIM, DIM, 1, stream);

        k_rmsnorm<<<N_TOK, 256, 0, stream>>>(h, DIM, 0, x, ffn_norm_w + (size_t)l * DIM, DIM);
        mm(x, w1 + (size_t)l * DIM * INTER, ffn1, N_TOK, INTER, DIM, DIM, INTER, INTER, 0, stream);
        mm(x, w2 + (size_t)l * DIM * INTER, ffn2, N_TOK, INTER, DIM, DIM, INTER, INTER, 0, stream);
        k_silu<<<2048, 256, 0, stream>>>(ffn1, ffn2, N_TOK * INTER);
        mm(ffn1, w3 + (size_t)l * INTER * DIM, h, N_TOK, DIM, INTER, INTER, DIM, DIM, 1, stream);
    }
    k_rmsnorm<<<N_TOK, 256, 0, stream>>>(h, DIM, 0, x, norm_w, DIM);
    mm(x, outW, (float*)d_out, N_TOK, VOCAB, DIM, DIM, VOCAB, VOCAB, 0, stream);
}

// Round 3
// 2351.581 us; speedup vs baseline: 7.2283x; 2.5515x over previous
//
#include <hip/hip_runtime.h>
#include <hip/hip_bf16.h>
#include <math.h>

#define N_TOK 2048
#define DIM   2048
#define NH    16
#define NOPE  128
#define ROPE_D 64
#define QKH   192
#define VH    128
#define KVR   512
#define INTER 5632
#define VOCAB 32000
#define NLAYER 2
#define EPS   1e-6f

typedef __hip_bfloat16 bf16;
typedef __bf16 bf16x8 __attribute__((ext_vector_type(8)));
typedef float  f32x4  __attribute__((ext_vector_type(4)));

__device__ __forceinline__ float bf2f(unsigned short u) {
    union { unsigned u; float f; } a; a.u = ((unsigned)u) << 16; return a.f;
}
__device__ __forceinline__ unsigned short f2bfu(float f) {
    union { float f; unsigned u; } a; a.f = f;
    return (unsigned short)((a.u + 0x7fffu + ((a.u >> 16) & 1u)) >> 16);
}

__device__ __forceinline__ void gload16(const void* g, void* l) {
    __builtin_amdgcn_global_load_lds((const __attribute__((address_space(1))) void*)g,
                                     (__attribute__((address_space(3))) void*)l, 16, 0, 0);
}

// ---------------- embedding gather ----------------
__global__ void k_embed(const int* __restrict__ tokens, const float* __restrict__ emb,
                        float* __restrict__ h) {
    int n = blockIdx.x;
    int t = tokens[n];
    const float4* src = (const float4*)(emb + (size_t)t * DIM);
    float4* dst = (float4*)(h + (size_t)n * DIM);
    for (int i = threadIdx.x; i < DIM / 4; i += blockDim.x) dst[i] = src[i];
}

// ---------------- rmsnorm f32 -> bf16 ----------------
__global__ __launch_bounds__(256) void k_rmsnorm(const float* __restrict__ in, int in_stride, int in_off,
                                                 bf16* __restrict__ out, const float* __restrict__ w,
                                                 int len) {
    int row = blockIdx.x;
    const float* x = in + (size_t)row * in_stride + in_off;
    float ss = 0.f;
    for (int i = threadIdx.x; i < len; i += 256) { float v = x[i]; ss += v * v; }
    for (int off = 32; off > 0; off >>= 1) ss += __shfl_down(ss, off, 64);
    __shared__ float red[4];
    if ((threadIdx.x & 63) == 0) red[threadIdx.x >> 6] = ss;
    __syncthreads();
    float tot = red[0] + red[1] + red[2] + red[3];
    float inv = rsqrtf(tot / (float)len + EPS);
    for (int i = threadIdx.x; i < len; i += 256)
        out[(size_t)row * len + i] = __float2bfloat16(x[i] * inv * w[i]);
}

// ---------------- transpose + convert: W[K][ncols] f32 (ld ldw, col base c0) -> Out[npad][K] bf16 ----------------
__global__ __launch_bounds__(256)
void k_convT(const float* __restrict__ W, bf16* __restrict__ Out,
             int K, int ldw, int ncols, int c0base, int c0step,
             long long inz, long long outz) {
    __shared__ float T[32][65];
    const float* Wz = W + (long long)blockIdx.z * inz;
    bf16* Oz = Out + (long long)blockIdx.z * outz;
    int c0 = c0base + blockIdx.z * c0step;
    int n0 = blockIdx.x * 64, k0 = blockIdx.y * 32;
    int tid = threadIdx.x;
    int rr = tid >> 4, cc = (tid & 15) * 4;
#pragma unroll
    for (int p = 0; p < 2; ++p) {
        int k = k0 + rr + p * 16;
        float4 v = make_float4(0.f, 0.f, 0.f, 0.f);
        if (n0 + cc < ncols) v = *(const float4*)(Wz + (size_t)k * ldw + c0 + n0 + cc);
        T[rr + p * 16][cc + 0] = v.x; T[rr + p * 16][cc + 1] = v.y;
        T[rr + p * 16][cc + 2] = v.z; T[rr + p * 16][cc + 3] = v.w;
    }
    __syncthreads();
    int n = tid >> 2, kc = (tid & 3) * 8;
    __align__(16) bf16 tmp[8];
#pragma unroll
    for (int e = 0; e < 8; ++e) tmp[e] = __float2bfloat16(T[kc + e][n]);
    *(int4*)(Oz + (size_t)(n0 + n) * K + k0 + kc) = *(const int4*)tmp;
}

// ---------------- bf16 MFMA GEMM, m97 structure: 128x128 tile, BK=32, global_load_lds ----------------
// A[M][K] bf16 (row-major, lda), Bt[N][K] bf16 (row-major, ldb). OUT: 0=f32 store, 1=f32 +=, 2=bf16 store.
template<int OUT, int CSKIP, int CKLIM>
__global__ __launch_bounds__(256)
void k_mm(const bf16* __restrict__ A, const bf16* __restrict__ Bt, void* __restrict__ Cv,
          int Nreal, int K, int lda, int ldb, int ldc,
          long long aoffz, long long boffz, long long coffz) {
    int row0 = blockIdx.y * 128, col0 = blockIdx.x * 128;
    if (CSKIP && col0 > row0 + 127) return;
    int kend = CKLIM ? min(K, row0 + 128) : K;
    const bf16* Ab = A + (long long)blockIdx.z * aoffz;
    const bf16* Bb = Bt + (long long)blockIdx.z * boffz;
    __shared__ bf16 As[128 * 32];
    __shared__ bf16 Bs[128 * 32];
    int tid = threadIdx.x;
    int lane = tid & 63, wave = tid >> 6;
    int wm = (wave & 1) * 64, wn = (wave >> 1) * 64;
    int fr = lane & 15, fg = lane >> 4;
    f32x4 acc[4][4] = {};
    for (int k0 = 0; k0 < kend; k0 += 32) {
#pragma unroll
        for (int it = 0; it < 2; ++it) {
            int idx = it * 256 + tid;
            int m = idx >> 2, c = idx & 3;
            gload16(Ab + (size_t)(row0 + m) * lda + k0 + c * 8, As + idx * 8);
        }
#pragma unroll
        for (int it = 0; it < 2; ++it) {
            int idx = it * 256 + tid;
            int m = idx >> 2, c = idx & 3;
            gload16(Bb + (size_t)(col0 + m) * ldb + k0 + c * 8, Bs + idx * 8);
        }
        __syncthreads();
        bf16x8 av[4], bv[4];
#pragma unroll
        for (int i = 0; i < 4; ++i) {
            av[i] = *(const bf16x8*)(As + (wm + i * 16 + fr) * 32 + fg * 8);
            bv[i] = *(const bf16x8*)(Bs + (wn + i * 16 + fr) * 32 + fg * 8);
        }
#pragma unroll
        for (int i = 0; i < 4; ++i)
#pragma unroll
            for (int j = 0; j < 4; ++j)
                acc[i][j] = __builtin_amdgcn_mfma_f32_16x16x32_bf16(av[i], bv[j], acc[i][j], 0, 0, 0);
        __syncthreads();
    }
    float* Cf = (float*)Cv + (OUT != 2 ? (long long)blockIdx.z * coffz : 0);
    bf16* Cb = (bf16*)Cv + (OUT == 2 ? (long long)blockIdx.z * coffz : 0);
#pragma unroll
    for (int i = 0; i < 4; ++i)
#pragma unroll
        for (int j = 0; j < 4; ++j)
#pragma unroll
            for (int q = 0; q < 4; ++q) {
                int row = row0 + wm + i * 16 + fg * 4 + q;
                int col = col0 + wn + j * 16 + fr;
                if (col < Nreal) {
                    size_t off = (size_t)row * ldc + col;
                    if (OUT == 0) Cf[off] = acc[i][j][q];
                    else if (OUT == 1) Cf[off] += acc[i][j][q];
                    else Cb[off] = __float2bfloat16(acc[i][j][q]);
                }
            }
}

// ---------------- q rope + pack to [h][n][192] bf16 ----------------
__global__ __launch_bounds__(256) void k_qpack(const float* __restrict__ q,
        const float* __restrict__ cosb, const float* __restrict__ sinb,
        bf16* __restrict__ qb) {
    int n = blockIdx.x;
    __shared__ float c[32], s[32];
    if (threadIdx.x < 32) {
        c[threadIdx.x] = cosb[n * 32 + threadIdx.x];
        s[threadIdx.x] = sinb[n * 32 + threadIdx.x];
    }
    __syncthreads();
    const float* row = q + (size_t)n * (NH * QKH);
    for (int idx = threadIdx.x; idx < NH * QKH; idx += 256) {
        int h = idx / QKH, d = idx - h * QKH;
        float v;
        if (d < NOPE) v = row[idx];
        else {
            int i = (d - NOPE) >> 1;
            float xr = row[h * QKH + NOPE + 2 * i], xi = row[h * QKH + NOPE + 2 * i + 1];
            v = ((d & 1) == 0) ? xr * c[i] - xi * s[i] : xr * s[i] + xi * c[i];
        }
        qb[(size_t)h * (N_TOK * QKH) + (size_t)n * QKH + d] = __float2bfloat16(v);
    }
}

// ---------------- K pack: [h][key][192] bf16 = concat(kvb nope, rope(kv[0:64])) ----------------
__global__ __launch_bounds__(256) void k_packK(const float* __restrict__ kvb,
        const float* __restrict__ kvf, const float* __restrict__ cosb, const float* __restrict__ sinb,
        bf16* __restrict__ Kb) {
    int key = blockIdx.x;
    __shared__ float rp[ROPE_D];
    if (threadIdx.x < 32) {
        float c = cosb[key * 32 + threadIdx.x], s = sinb[key * 32 + threadIdx.x];
        float xr = kvf[(size_t)key * (ROPE_D + KVR) + 2 * threadIdx.x];
        float xi = kvf[(size_t)key * (ROPE_D + KVR) + 2 * threadIdx.x + 1];
        rp[2 * threadIdx.x] = xr * c - xi * s;
        rp[2 * threadIdx.x + 1] = xr * s + xi * c;
    }
    __syncthreads();
    const float* row = kvb + (size_t)key * (NH * (NOPE + VH));
    for (int idx = threadIdx.x; idx < NH * QKH; idx += 256) {
        int h = idx / QKH, d = idx - h * QKH;
        float v = (d < NOPE) ? row[h * (NOPE + VH) + d] : rp[d - NOPE];
        Kb[(size_t)h * (N_TOK * QKH) + (size_t)key * QKH + d] = __float2bfloat16(v);
    }
}

// ---------------- causal row softmax: S f32 -> P bf16 ----------------
__global__ __launch_bounds__(256) void k_softmax(const float* __restrict__ S, bf16* __restrict__ P) {
    int r = blockIdx.x;
    const float* p = S + (size_t)blockIdx.y * N_TOK * N_TOK + (size_t)r * N_TOK;
    bf16* o = P + (size_t)blockIdx.y * N_TOK * N_TOK + (size_t)r * N_TOK;
    const float scale = 0.07216878364870322f;  // 1/sqrt(192)
    int tid = threadIdx.x;
    float sv[8];
    float m = -1e30f;
#pragma unroll
    for (int jj = 0; jj < 8; ++jj) {
        int j = tid + jj * 256;
        sv[jj] = (j <= r) ? p[j] : -1e30f;
        m = fmaxf(m, sv[jj]);
    }
    for (int off = 32; off > 0; off >>= 1) m = fmaxf(m, __shfl_down(m, off, 64));
    __shared__ float red[4];
    if ((tid & 63) == 0) red[tid >> 6] = m;
    __syncthreads();
    m = fmaxf(fmaxf(red[0], red[1]), fmaxf(red[2], red[3]));
    __syncthreads();
    float sum = 0.f;
#pragma unroll
    for (int jj = 0; jj < 8; ++jj) {
        int j = tid + jj * 256;
        sv[jj] = (j <= r) ? __expf((sv[jj] - m) * scale) : 0.f;
        sum += sv[jj];
    }
    for (int off = 32; off > 0; off >>= 1) sum += __shfl_down(sum, off, 64);
    if ((tid & 63) == 0) red[tid >> 6] = sum;
    __syncthreads();
    float inv = 1.f / (red[0] + red[1] + red[2] + red[3]);
#pragma unroll
    for (int jj = 0; jj < 8; ++jj) {
        int j = tid + jj * 256;
        o[j] = __float2bfloat16(sv[jj] * inv);
    }
}

// ---------------- silu(a)*b -> a, bf16 vectorized ----------------
__global__ void k_silu(bf16* __restrict__ a, const bf16* __restrict__ b, int n) {
    int i = (blockIdx.x * blockDim.x + threadIdx.x) * 8;
    int stride = gridDim.x * blockDim.x * 8;
    for (; i < n; i += stride) {
        uint4 ua = *(const uint4*)((const unsigned short*)a + i);
        uint4 ub = *(const uint4*)((const unsigned short*)b + i);
        unsigned* pa = &ua.x; const unsigned* pb = &ub.x;
#pragma unroll
        for (int w = 0; w < 4; ++w) {
            float x0 = bf2f((unsigned short)(pa[w] & 0xffffu));
            float x1 = bf2f((unsigned short)(pa[w] >> 16));
            float y0 = bf2f((unsigned short)(pb[w] & 0xffffu));
            float y1 = bf2f((unsigned short)(pb[w] >> 16));
            float r0 = x0 / (1.f + __expf(-x0)) * y0;
            float r1 = x1 / (1.f + __expf(-x1)) * y1;
            pa[w] = (unsigned)f2bfu(r0) | ((unsigned)f2bfu(r1) << 16);
        }
        *(uint4*)((unsigned short*)a + i) = ua;
    }
}

extern "C" void kernel_launch(void* const* d_in, const int* in_sizes, int n_in,
                              void* d_out, int out_size, void* d_ws, size_t ws_size,
                              hipStream_t stream) {
    (void)in_sizes; (void)n_in; (void)out_size;
    const int* tokens = (const int*)d_in[0];
    const float* emb = (const float*)d_in[1];
    const float* qW = (const float*)d_in[2];
    const float* kvaW = (const float*)d_in[3];
    const float* kvnorm_w = (const float*)d_in[4];
    const float* kvbW = (const float*)d_in[5];
    const float* oW = (const float*)d_in[6];
    const float* w1 = (const float*)d_in[7];
    const float* w2 = (const float*)d_in[8];
    const float* w3 = (const float*)d_in[9];
    const float* attn_norm_w = (const float*)d_in[10];
    const float* ffn_norm_w = (const float*)d_in[11];
    const float* norm_w = (const float*)d_in[12];
    const float* outW = (const float*)d_in[13];
    const float* rope_cos = (const float*)d_in[14];
    const float* rope_sin = (const float*)d_in[15];

    float* ws = (float*)d_ws;
    size_t off = 0;
    auto allocF = [&](size_t fl) { float* p = ws + off; off += (fl + 63) & ~63ULL; return p; };
    float* h    = allocF(4194304);            // [2048][2048] f32
    bf16* xb    = (bf16*)allocF(2097152);     // [2048][2048] bf16
    float* kvf  = allocF(1179648);            // [2048][576] f32
    bf16* cb    = (bf16*)allocF(524288);      // [2048][512] bf16
    bf16* qb    = (bf16*)allocF(3145728);     // [16][2048][192] bf16
    bf16* Kb    = (bf16*)allocF(3145728);     // [16][2048][192] bf16
    bf16* Vt    = (bf16*)allocF(2097152);     // [16][128][2048] bf16
    bf16* aout  = (bf16*)allocF(2097152);     // [2048][2048] bf16
    bf16* qWt   = (bf16*)allocF(3145728);     // [3072][2048]
    bf16* kvaWt = (bf16*)allocF(655360);      // [640][2048] (576 padded)
    bf16* kvbWt = (bf16*)allocF(1048576);     // [4096][512]
    bf16* oWt   = (bf16*)allocF(2097152);     // [2048][2048]
    bf16* w1t   = (bf16*)allocF(5767168);     // [5632][2048]
    bf16* w2t   = (bf16*)allocF(5767168);
    bf16* w3t   = (bf16*)allocF(5767168);     // [2048][5632]
    float* scr  = ws + off;
    size_t availF = (ws_size / 4 > off) ? ws_size / 4 - off : 0;

    int ch = 1, oc = 25;
    {
        const int chs[8] = {4, 4, 2, 4, 2, 1, 1, 1};
        const int ocs[8] = {1, 2, 2, 5, 5, 5, 10, 25};
        for (int i = 0; i < 8; ++i) {
            size_t need = 11534336;                         // ffn (2x bf16 [2048][5632])
            size_t a1 = (size_t)chs[i] * 6291456;           // attn S+P per chunk
            size_t a2 = (size_t)32768000 / ocs[i];          // outW chunk
            if (a1 > need) need = a1;
            if (a2 > need) need = a2;
            if (8388608 > need) need = 8388608;             // kvb f32
            if (need <= availF) { ch = chs[i]; oc = ocs[i]; break; }
        }
    }
    float* qf   = scr;                           // [2048][3072] f32 (transient)
    float* kvbf = scr;                           // [2048][4096] f32 (transient)
    float* S    = scr;                           // [ch][2048][2048] f32
    bf16* P     = (bf16*)(S + (size_t)ch * 4194304);
    bf16* f1    = (bf16*)scr;                    // [2048][5632] bf16
    bf16* f2    = f1 + 11534336;
    bf16* oWtc  = (bf16*)scr;                    // outW chunk [cn][2048]

    auto convT = [&](const float* W, bf16* Out, int K, int ldw, int ncols, int npad,
                     int c0base, int c0step, long long outz, int nz) {
        dim3 g(npad / 64, K / 32, nz);
        k_convT<<<g, 256, 0, stream>>>(W, Out, K, ldw, ncols, c0base, c0step, 0, outz);
    };

    k_embed<<<N_TOK, 256, 0, stream>>>(tokens, emb, h);

    for (int l = 0; l < NLAYER; ++l) {
        convT(qW + (size_t)l * DIM * 3072, qWt, 2048, 3072, 3072, 3072, 0, 0, 0, 1);
        convT(kvaW + (size_t)l * DIM * 576, kvaWt, 2048, 576, 576, 640, 0, 0, 0, 1);
        convT(kvbW + (size_t)l * 512 * 4096, kvbWt, 512, 4096, 4096, 4096, 0, 0, 0, 1);
        convT(oW + (size_t)l * 2048 * 2048, oWt, 2048, 2048, 2048, 2048, 0, 0, 0, 1);
        convT(w1 + (size_t)l * DIM * INTER, w1t, 2048, 5632, 5632, 5632, 0, 0, 0, 1);
        convT(w2 + (size_t)l * DIM * INTER, w2t, 2048, 5632, 5632, 5632, 0, 0, 0, 1);
        convT(w3 + (size_t)l * INTER * DIM, w3t, 5632, 2048, 2048, 2048, 0, 0, 0, 1);

        k_rmsnorm<<<N_TOK, 256, 0, stream>>>(h, 2048, 0, xb, attn_norm_w + (size_t)l * DIM, 2048);
        k_mm<0, 0, 0><<<dim3(24, 16), 256, 0, stream>>>(xb, qWt, qf, 3072, 2048, 2048, 2048, 3072, 0, 0, 0);
        k_mm<0, 0, 0><<<dim3(5, 16), 256, 0, stream>>>(xb, kvaWt, kvf, 576, 2048, 2048, 2048, 576, 0, 0, 0);
        k_qpack<<<N_TOK, 256, 0, stream>>>(qf, rope_cos, rope_sin, qb);
        k_rmsnorm<<<N_TOK, 256, 0, stream>>>(kvf, 576, 64, cb, kvnorm_w + (size_t)l * KVR, 512);
        k_mm<0, 0, 0><<<dim3(32, 16), 256, 0, stream>>>(cb, kvbWt, kvbf, 4096, 512, 512, 512, 4096, 0, 0, 0);
        k_packK<<<N_TOK, 256, 0, stream>>>(kvbf, kvf, rope_cos, rope_sin, Kb);
        // V^T per head: [128][2048] bf16
        {
            dim3 g(2, 64, 16);
            k_convT<<<g, 256, 0, stream>>>(kvbf, Vt, 2048, 4096, 128, 128, 256, 0, (long long)128 * 2048);
        }
        for (int c = 0; c < NH / ch; ++c) {
            size_t h0 = (size_t)c * ch;
            k_mm<0, 1, 0><<<dim3(16, 16, ch), 256, 0, stream>>>(
                qb + h0 * N_TOK * QKH, Kb + h0 * N_TOK * QKH, S,
                2048, 192, 192, 192, 2048, (long long)N_TOK * QKH, (long long)N_TOK * QKH, 4194304LL);
            k_softmax<<<dim3(N_TOK, ch), 256, 0, stream>>>(S, P);
            k_mm<2, 0, 1><<<dim3(1, 16, ch), 256, 0, stream>>>(
                P, Vt + h0 * 128 * 2048, aout + h0 * 128,
                128, 2048, 2048, 2048, 2048, 4194304LL, (long long)128 * 2048, 128LL);
        }
        k_mm<1, 0, 0><<<dim3(16, 16), 256, 0, stream>>>(aout, oWt, h, 2048, 2048, 2048, 2048, 2048, 0, 0, 0);

        k_rmsnorm<<<N_TOK, 256, 0, stream>>>(h, 2048, 0, xb, ffn_norm_w + (size_t)l * DIM, 2048);
        k_mm<2, 0, 0><<<dim3(44, 16), 256, 0, stream>>>(xb, w1t, f1, 5632, 2048, 2048, 2048, 5632, 0, 0, 0);
        k_mm<2, 0, 0><<<dim3(44, 16), 256, 0, stream>>>(xb, w2t, f2, 5632, 2048, 2048, 2048, 5632, 0, 0, 0);
        k_silu<<<2048, 256, 0, stream>>>(f1, f2, N_TOK * INTER);
        k_mm<1, 0, 0><<<dim3(16, 16), 256, 0, stream>>>(f1, w3t, h, 2048, 5632, 5632, 5632, 2048, 0, 0, 0);
    }
    k_rmsnorm<<<N_TOK, 256, 0, stream>>>(h, 2048, 0, xb, norm_w, 2048);
    int cn = 32000 / oc;
    for (int c2 = 0; c2 < oc; ++c2) {
        convT(outW, oWtc, 2048, 32000, cn, cn, c2 * cn, 0, 0, 1);
        k_mm<0, 0, 0><<<dim3(cn / 128, 16), 256, 0, stream>>>(
            xb, oWtc, (float*)d_out + (size_t)c2 * cn, cn, 2048, 2048, 2048, 32000, 0, 0, 0);
    }
}

// Round 4
// 1924.133 us; speedup vs baseline: 8.8341x; 1.2222x over previous
//
#include <hip/hip_runtime.h>
#include <hip/hip_bf16.h>
#include <math.h>

#define N_TOK 2048
#define DIM   2048
#define NH    16
#define NOPE  128
#define ROPE_D 64
#define QKH   192
#define VH    128
#define KVR   512
#define INTER 5632
#define VOCAB 32000
#define NLAYER 2
#define EPS   1e-6f

typedef __hip_bfloat16 bf16;
typedef __bf16 bf16x8 __attribute__((ext_vector_type(8)));
typedef float  f32x4  __attribute__((ext_vector_type(4)));

__device__ __forceinline__ float bf2f(unsigned short u) {
    union { unsigned u; float f; } a; a.u = ((unsigned)u) << 16; return a.f;
}
__device__ __forceinline__ unsigned short f2bfu(float f) {
    union { float f; unsigned u; } a; a.f = f;
    return (unsigned short)((a.u + 0x7fffu + ((a.u >> 16) & 1u)) >> 16);
}

__device__ __forceinline__ void gload16(const void* g, void* l) {
    __builtin_amdgcn_global_load_lds((const __attribute__((address_space(1))) void*)g,
                                     (__attribute__((address_space(3))) void*)l, 16, 0, 0);
}

// ---------------- embedding gather ----------------
__global__ void k_embed(const int* __restrict__ tokens, const float* __restrict__ emb,
                        float* __restrict__ h) {
    int n = blockIdx.x;
    int t = tokens[n];
    const float4* src = (const float4*)(emb + (size_t)t * DIM);
    float4* dst = (float4*)(h + (size_t)n * DIM);
    for (int i = threadIdx.x; i < DIM / 4; i += blockDim.x) dst[i] = src[i];
}

// ---------------- rmsnorm f32 -> bf16 ----------------
__global__ __launch_bounds__(256) void k_rmsnorm(const float* __restrict__ in, int in_stride, int in_off,
                                                 bf16* __restrict__ out, const float* __restrict__ w,
                                                 int len) {
    int row = blockIdx.x;
    const float* x = in + (size_t)row * in_stride + in_off;
    float ss = 0.f;
    for (int i = threadIdx.x; i < len; i += 256) { float v = x[i]; ss += v * v; }
    for (int off = 32; off > 0; off >>= 1) ss += __shfl_down(ss, off, 64);
    __shared__ float red[4];
    if ((threadIdx.x & 63) == 0) red[threadIdx.x >> 6] = ss;
    __syncthreads();
    float tot = red[0] + red[1] + red[2] + red[3];
    float inv = rsqrtf(tot / (float)len + EPS);
    for (int i = threadIdx.x; i < len; i += 256)
        out[(size_t)row * len + i] = __float2bfloat16(x[i] * inv * w[i]);
}

// ---------------- transpose + convert: W[K][ncols] f32 -> Out[npad][K] bf16 ----------------
__global__ __launch_bounds__(256)
void k_convT(const float* __restrict__ W, bf16* __restrict__ Out,
             int K, int ldw, int ncols, int c0base, int c0step,
             long long inz, long long outz) {
    __shared__ float T[32][65];
    const float* Wz = W + (long long)blockIdx.z * inz;
    bf16* Oz = Out + (long long)blockIdx.z * outz;
    int c0 = c0base + blockIdx.z * c0step;
    int n0 = blockIdx.x * 64, k0 = blockIdx.y * 32;
    int tid = threadIdx.x;
    int rr = tid >> 4, cc = (tid & 15) * 4;
#pragma unroll
    for (int p = 0; p < 2; ++p) {
        int k = k0 + rr + p * 16;
        float4 v = make_float4(0.f, 0.f, 0.f, 0.f);
        if (n0 + cc < ncols) v = *(const float4*)(Wz + (size_t)k * ldw + c0 + n0 + cc);
        T[rr + p * 16][cc + 0] = v.x; T[rr + p * 16][cc + 1] = v.y;
        T[rr + p * 16][cc + 2] = v.z; T[rr + p * 16][cc + 3] = v.w;
    }
    __syncthreads();
    int n = tid >> 2, kc = (tid & 3) * 8;
    __align__(16) bf16 tmp[8];
#pragma unroll
    for (int e = 0; e < 8; ++e) tmp[e] = __float2bfloat16(T[kc + e][n]);
    *(int4*)(Oz + (size_t)(n0 + n) * K + k0 + kc) = *(const int4*)tmp;
}

// ---------------- bf16 MFMA GEMM, 128x128 tile, BK=32, global_load_lds ----------------
// Grid: (M/128, N/128) -- x indexes ROW panels so resident blocks share B panels.
// A[M][K] bf16 (lda), Bt[N][K] bf16 (ldb). OUT: 0=f32 store, 1=f32 +=, 2=bf16 store.
template<int OUT>
__global__ __launch_bounds__(256)
void k_mm(const bf16* __restrict__ A, const bf16* __restrict__ Bt, void* __restrict__ Cv,
          int Nreal, int K, int lda, int ldb, int ldc) {
    int row0 = blockIdx.x * 128, col0 = blockIdx.y * 128;
    __shared__ bf16 As[128 * 32];
    __shared__ bf16 Bs[128 * 32];
    int tid = threadIdx.x;
    int lane = tid & 63, wave = tid >> 6;
    int wm = (wave & 1) * 64, wn = (wave >> 1) * 64;
    int fr = lane & 15, fg = lane >> 4;
    f32x4 acc[4][4] = {};
    for (int k0 = 0; k0 < K; k0 += 32) {
#pragma unroll
        for (int it = 0; it < 2; ++it) {
            int idx = it * 256 + tid;
            int m = idx >> 2, c = idx & 3;
            gload16(A + (size_t)(row0 + m) * lda + k0 + c * 8, As + idx * 8);
        }
#pragma unroll
        for (int it = 0; it < 2; ++it) {
            int idx = it * 256 + tid;
            int m = idx >> 2, c = idx & 3;
            gload16(Bt + (size_t)(col0 + m) * ldb + k0 + c * 8, Bs + idx * 8);
        }
        __syncthreads();
        bf16x8 av[4], bv[4];
#pragma unroll
        for (int i = 0; i < 4; ++i) {
            av[i] = *(const bf16x8*)(As + (wm + i * 16 + fr) * 32 + fg * 8);
            bv[i] = *(const bf16x8*)(Bs + (wn + i * 16 + fr) * 32 + fg * 8);
        }
#pragma unroll
        for (int i = 0; i < 4; ++i)
#pragma unroll
            for (int j = 0; j < 4; ++j)
                acc[i][j] = __builtin_amdgcn_mfma_f32_16x16x32_bf16(av[i], bv[j], acc[i][j], 0, 0, 0);
        __syncthreads();
    }
    float* Cf = (float*)Cv;
    bf16* Cb = (bf16*)Cv;
#pragma unroll
    for (int i = 0; i < 4; ++i)
#pragma unroll
        for (int j = 0; j < 4; ++j)
#pragma unroll
            for (int q = 0; q < 4; ++q) {
                int row = row0 + wm + i * 16 + fg * 4 + q;
                int col = col0 + wn + j * 16 + fr;
                if (col < Nreal) {
                    size_t off = (size_t)row * ldc + col;
                    if (OUT == 0) Cf[off] = acc[i][j][q];
                    else if (OUT == 1) Cf[off] += acc[i][j][q];
                    else Cb[off] = __float2bfloat16(acc[i][j][q]);
                }
            }
}

// ---------------- q rope + pack to [h][n][192] bf16 ----------------
__global__ __launch_bounds__(256) void k_qpack(const float* __restrict__ q,
        const float* __restrict__ cosb, const float* __restrict__ sinb,
        bf16* __restrict__ qb) {
    int n = blockIdx.x;
    __shared__ float c[32], s[32];
    if (threadIdx.x < 32) {
        c[threadIdx.x] = cosb[n * 32 + threadIdx.x];
        s[threadIdx.x] = sinb[n * 32 + threadIdx.x];
    }
    __syncthreads();
    const float* row = q + (size_t)n * (NH * QKH);
    for (int idx = threadIdx.x; idx < NH * QKH; idx += 256) {
        int h = idx / QKH, d = idx - h * QKH;
        float v;
        if (d < NOPE) v = row[idx];
        else {
            int i = (d - NOPE) >> 1;
            float xr = row[h * QKH + NOPE + 2 * i], xi = row[h * QKH + NOPE + 2 * i + 1];
            v = ((d & 1) == 0) ? xr * c[i] - xi * s[i] : xr * s[i] + xi * c[i];
        }
        qb[(size_t)h * (N_TOK * QKH) + (size_t)n * QKH + d] = __float2bfloat16(v);
    }
}

// ---------------- K pack: [h][key][192] bf16 ----------------
__global__ __launch_bounds__(256) void k_packK(const float* __restrict__ kvb,
        const float* __restrict__ kvf, const float* __restrict__ cosb, const float* __restrict__ sinb,
        bf16* __restrict__ Kb) {
    int key = blockIdx.x;
    __shared__ float rp[ROPE_D];
    if (threadIdx.x < 32) {
        float c = cosb[key * 32 + threadIdx.x], s = sinb[key * 32 + threadIdx.x];
        float xr = kvf[(size_t)key * (ROPE_D + KVR) + 2 * threadIdx.x];
        float xi = kvf[(size_t)key * (ROPE_D + KVR) + 2 * threadIdx.x + 1];
        rp[2 * threadIdx.x] = xr * c - xi * s;
        rp[2 * threadIdx.x + 1] = xr * s + xi * c;
    }
    __syncthreads();
    const float* row = kvb + (size_t)key * (NH * (NOPE + VH));
    for (int idx = threadIdx.x; idx < NH * QKH; idx += 256) {
        int h = idx / QKH, d = idx - h * QKH;
        float v = (d < NOPE) ? row[h * (NOPE + VH) + d] : rp[d - NOPE];
        Kb[(size_t)h * (N_TOK * QKH) + (size_t)key * QKH + d] = __float2bfloat16(v);
    }
}

// ---------------- fused flash attention: grid (NH, 16 q-panels), 4 waves ----------------
__global__ __launch_bounds__(256, 2)
void k_flash(const bf16* __restrict__ qb, const bf16* __restrict__ Kb,
             const bf16* __restrict__ Vt, bf16* __restrict__ aout) {
    int h = blockIdx.x, qp = blockIdx.y;
    __shared__ short Ks[64 * 200];   // [key][192] pad->200 (2-way free)
    __shared__ short Vs[128 * 72];   // [vdim][key64] pad->72
    __shared__ short Ps[128 * 72];   // [qrow][key64] pad->72 (wave-private bands)
    int t = threadIdx.x;
    int lane = t & 63, w = t >> 6;
    int fr = lane & 15, fg = lane >> 4;
    const float scale = 0.07216878364870322f;  // 1/sqrt(192)

    // Q fragments in registers (A-operand layout: row=fr, k=fg*8+e)
    bf16x8 aq[2][6];
    const bf16* Qsrc = qb + ((size_t)h * N_TOK + qp * 128 + w * 32) * QKH;
#pragma unroll
    for (int i = 0; i < 2; ++i)
#pragma unroll
        for (int ks = 0; ks < 6; ++ks)
            aq[i][ks] = *(const bf16x8*)(Qsrc + (size_t)(i * 16 + fr) * QKH + ks * 32 + fg * 8);

    f32x4 acc_o[2][8] = {};
    float m_r[2][4], l_r[2][4];
#pragma unroll
    for (int i = 0; i < 2; ++i)
#pragma unroll
        for (int q = 0; q < 4; ++q) { m_r[i][q] = -1e30f; l_r[i][q] = 0.f; }

    int nkt = 2 * qp + 2;
    const bf16* Kbase = Kb + (size_t)h * N_TOK * QKH;
    const bf16* Vbase = Vt + (size_t)h * VH * N_TOK;

    for (int kt = 0; kt < nkt; ++kt) {
        __syncthreads();  // protect Ks/Vs (prev readers done)
        {
            const bf16* Ksrc = Kbase + (size_t)kt * 64 * QKH;
#pragma unroll
            for (int c = 0; c < 6; ++c) {
                int idx = c * 256 + t;
                int row = idx / 24, c16 = idx - row * 24;
                int4 v = *(const int4*)(Ksrc + row * QKH + c16 * 8);
                *(int4*)(Ks + row * 200 + c16 * 8) = v;
            }
            const bf16* Vsrc = Vbase + kt * 64;
#pragma unroll
            for (int c = 0; c < 4; ++c) {
                int idx = c * 256 + t;
                int row = idx >> 3, c8 = idx & 7;
                int4 v = *(const int4*)(Vsrc + (size_t)row * N_TOK + c8 * 8);
                *(int4*)(Vs + row * 72 + c8 * 8) = v;
            }
        }
        __syncthreads();
        // S = Q @ K^T  (raw, scale folded into exp)
        f32x4 acc_s[2][4] = {};
#pragma unroll
        for (int ks = 0; ks < 6; ++ks) {
            bf16x8 bv[4];
#pragma unroll
            for (int j = 0; j < 4; ++j)
                bv[j] = *(const bf16x8*)(Ks + (j * 16 + fr) * 200 + ks * 32 + fg * 8);
#pragma unroll
            for (int i = 0; i < 2; ++i)
#pragma unroll
                for (int j = 0; j < 4; ++j)
                    acc_s[i][j] = __builtin_amdgcn_mfma_f32_16x16x32_bf16(aq[i][ks], bv[j], acc_s[i][j], 0, 0, 0);
        }
        if (kt >= 2 * qp) {  // causal mask (only last two tiles)
            int colb = kt * 64;
            int rowb = qp * 128 + w * 32;
#pragma unroll
            for (int i = 0; i < 2; ++i)
#pragma unroll
                for (int j = 0; j < 4; ++j)
#pragma unroll
                    for (int q = 0; q < 4; ++q)
                        if (colb + j * 16 + fr > rowb + i * 16 + fg * 4 + q)
                            acc_s[i][j][q] = -1e30f;
        }
        // online softmax (rows owned per-lane: row = w*32 + i*16 + fg*4 + q)
#pragma unroll
        for (int i = 0; i < 2; ++i) {
#pragma unroll
            for (int q = 0; q < 4; ++q) {
                float tmax = fmaxf(fmaxf(acc_s[i][0][q], acc_s[i][1][q]),
                                   fmaxf(acc_s[i][2][q], acc_s[i][3][q]));
                tmax = fmaxf(tmax, __shfl_xor(tmax, 1, 64));
                tmax = fmaxf(tmax, __shfl_xor(tmax, 2, 64));
                tmax = fmaxf(tmax, __shfl_xor(tmax, 4, 64));
                tmax = fmaxf(tmax, __shfl_xor(tmax, 8, 64));
                float mn = fmaxf(m_r[i][q], tmax);
                float sc = __expf(scale * (m_r[i][q] - mn));
                m_r[i][q] = mn;
                float s0 = 0.f;
#pragma unroll
                for (int j = 0; j < 4; ++j) {
                    float pv = __expf(scale * (acc_s[i][j][q] - mn));
                    acc_s[i][j][q] = pv;
                    s0 += pv;
                }
                s0 += __shfl_xor(s0, 1, 64);
                s0 += __shfl_xor(s0, 2, 64);
                s0 += __shfl_xor(s0, 4, 64);
                s0 += __shfl_xor(s0, 8, 64);
                l_r[i][q] = l_r[i][q] * sc + s0;
#pragma unroll
                for (int jo = 0; jo < 8; ++jo) acc_o[i][jo][q] *= sc;
            }
        }
        // P -> LDS (wave-private 32-row band), re-layout to A-operand
#pragma unroll
        for (int i = 0; i < 2; ++i)
#pragma unroll
            for (int j = 0; j < 4; ++j)
#pragma unroll
                for (int q = 0; q < 4; ++q)
                    Ps[(w * 32 + i * 16 + fg * 4 + q) * 72 + j * 16 + fr] =
                        (short)f2bfu(acc_s[i][j][q]);
        // O += P @ V
#pragma unroll
        for (int ks2 = 0; ks2 < 2; ++ks2) {
            bf16x8 pa[2];
#pragma unroll
            for (int i = 0; i < 2; ++i)
                pa[i] = *(const bf16x8*)(Ps + (w * 32 + i * 16 + fr) * 72 + ks2 * 32 + fg * 8);
#pragma unroll
            for (int jo = 0; jo < 8; ++jo) {
                bf16x8 vb = *(const bf16x8*)(Vs + (jo * 16 + fr) * 72 + ks2 * 32 + fg * 8);
#pragma unroll
                for (int i = 0; i < 2; ++i)
                    acc_o[i][jo] = __builtin_amdgcn_mfma_f32_16x16x32_bf16(pa[i], vb, acc_o[i][jo], 0, 0, 0);
            }
        }
    }
    bf16* obase = aout + (size_t)(qp * 128 + w * 32) * (NH * VH) + h * VH;
#pragma unroll
    for (int i = 0; i < 2; ++i)
#pragma unroll
        for (int q = 0; q < 4; ++q) {
            float inv = 1.f / l_r[i][q];
#pragma unroll
            for (int jo = 0; jo < 8; ++jo)
                obase[(size_t)(i * 16 + fg * 4 + q) * (NH * VH) + jo * 16 + fr] =
                    __float2bfloat16(acc_o[i][jo][q] * inv);
        }
}

// ---------------- silu(a)*b -> a, bf16 vectorized ----------------
__global__ void k_silu(bf16* __restrict__ a, const bf16* __restrict__ b, int n) {
    int i = (blockIdx.x * blockDim.x + threadIdx.x) * 8;
    int stride = gridDim.x * blockDim.x * 8;
    for (; i < n; i += stride) {
        uint4 ua = *(const uint4*)((const unsigned short*)a + i);
        uint4 ub = *(const uint4*)((const unsigned short*)b + i);
        unsigned* pa = &ua.x; const unsigned* pb = &ub.x;
#pragma unroll
        for (int w = 0; w < 4; ++w) {
            float x0 = bf2f((unsigned short)(pa[w] & 0xffffu));
            float x1 = bf2f((unsigned short)(pa[w] >> 16));
            float y0 = bf2f((unsigned short)(pb[w] & 0xffffu));
            float y1 = bf2f((unsigned short)(pb[w] >> 16));
            float r0 = x0 / (1.f + __expf(-x0)) * y0;
            float r1 = x1 / (1.f + __expf(-x1)) * y1;
            pa[w] = (unsigned)f2bfu(r0) | ((unsigned)f2bfu(r1) << 16);
        }
        *(uint4*)((unsigned short*)a + i) = ua;
    }
}

extern "C" void kernel_launch(void* const* d_in, const int* in_sizes, int n_in,
                              void* d_out, int out_size, void* d_ws, size_t ws_size,
                              hipStream_t stream) {
    (void)in_sizes; (void)n_in; (void)out_size;
    const int* tokens = (const int*)d_in[0];
    const float* emb = (const float*)d_in[1];
    const float* qW = (const float*)d_in[2];
    const float* kvaW = (const float*)d_in[3];
    const float* kvnorm_w = (const float*)d_in[4];
    const float* kvbW = (const float*)d_in[5];
    const float* oW = (const float*)d_in[6];
    const float* w1 = (const float*)d_in[7];
    const float* w2 = (const float*)d_in[8];
    const float* w3 = (const float*)d_in[9];
    const float* attn_norm_w = (const float*)d_in[10];
    const float* ffn_norm_w = (const float*)d_in[11];
    const float* norm_w = (const float*)d_in[12];
    const float* outW = (const float*)d_in[13];
    const float* rope_cos = (const float*)d_in[14];
    const float* rope_sin = (const float*)d_in[15];

    float* ws = (float*)d_ws;
    size_t off = 0;
    auto allocF = [&](size_t fl) { float* p = ws + off; off += (fl + 63) & ~63ULL; return p; };
    float* h    = allocF(4194304);            // [2048][2048] f32
    bf16* xb    = (bf16*)allocF(2097152);     // [2048][2048] bf16
    float* kvf  = allocF(1179648);            // [2048][576] f32
    bf16* cb    = (bf16*)allocF(524288);      // [2048][512] bf16
    bf16* qb    = (bf16*)allocF(3145728);     // [16][2048][192] bf16
    bf16* Kb    = (bf16*)allocF(3145728);     // [16][2048][192] bf16
    bf16* Vt    = (bf16*)allocF(2097152);     // [16][128][2048] bf16
    bf16* aout  = (bf16*)allocF(2097152);     // [2048][2048] bf16
    bf16* qWt   = (bf16*)allocF(3145728);     // [3072][2048]
    bf16* kvaWt = (bf16*)allocF(655360);      // [640][2048]
    bf16* kvbWt = (bf16*)allocF(1048576);     // [4096][512]
    bf16* oWt   = (bf16*)allocF(2097152);     // [2048][2048]
    bf16* w1t   = (bf16*)allocF(5767168);     // [5632][2048]
    bf16* w2t   = (bf16*)allocF(5767168);
    bf16* w3t   = (bf16*)allocF(5767168);     // [2048][5632]
    float* scr  = ws + off;
    size_t availF = (ws_size / 4 > off) ? ws_size / 4 - off : 0;

    int oc = 25;
    {
        const int ocs[3] = {1, 5, 25};
        for (int i = 0; i < 3; ++i) {
            size_t need = 11534336;                        // ffn f1+f2
            size_t a2 = (size_t)32768000 / ocs[i];         // outW chunk (bf16, in floats)
            if (a2 > need) need = a2;
            if (8388608 > need) need = 8388608;            // kvbf f32
            if (need <= availF) { oc = ocs[i]; break; }
        }
    }
    float* qf   = scr;                          // [2048][3072] f32 (transient)
    float* kvbf = scr;                          // [2048][4096] f32 (transient)
    bf16* f1    = (bf16*)scr;                   // [2048][5632] bf16
    bf16* f2    = f1 + 11534336;
    bf16* oWtc  = (bf16*)scr;                   // outW chunk [cn][2048]

    auto convT = [&](const float* W, bf16* Out, int K, int ldw, int ncols, int npad,
                     int c0) {
        dim3 g(npad / 64, K / 32, 1);
        k_convT<<<g, 256, 0, stream>>>(W, Out, K, ldw, ncols, c0, 0, 0, 0);
    };

    k_embed<<<N_TOK, 256, 0, stream>>>(tokens, emb, h);

    for (int l = 0; l < NLAYER; ++l) {
        convT(qW + (size_t)l * DIM * 3072, qWt, 2048, 3072, 3072, 3072, 0);
        convT(kvaW + (size_t)l * DIM * 576, kvaWt, 2048, 576, 576, 640, 0);
        convT(kvbW + (size_t)l * 512 * 4096, kvbWt, 512, 4096, 4096, 4096, 0);
        convT(oW + (size_t)l * 2048 * 2048, oWt, 2048, 2048, 2048, 2048, 0);
        convT(w1 + (size_t)l * DIM * INTER, w1t, 2048, 5632, 5632, 5632, 0);
        convT(w2 + (size_t)l * DIM * INTER, w2t, 2048, 5632, 5632, 5632, 0);
        convT(w3 + (size_t)l * INTER * DIM, w3t, 5632, 2048, 2048, 2048, 0);

        k_rmsnorm<<<N_TOK, 256, 0, stream>>>(h, 2048, 0, xb, attn_norm_w + (size_t)l * DIM, 2048);
        k_mm<0><<<dim3(16, 24), 256, 0, stream>>>(xb, qWt, qf, 3072, 2048, 2048, 2048, 3072);
        k_mm<0><<<dim3(16, 5), 256, 0, stream>>>(xb, kvaWt, kvf, 576, 2048, 2048, 2048, 576);
        k_qpack<<<N_TOK, 256, 0, stream>>>(qf, rope_cos, rope_sin, qb);
        k_rmsnorm<<<N_TOK, 256, 0, stream>>>(kvf, 576, 64, cb, kvnorm_w + (size_t)l * KVR, 512);
        k_mm<0><<<dim3(16, 32), 256, 0, stream>>>(cb, kvbWt, kvbf, 4096, 512, 512, 512, 4096);
        k_packK<<<N_TOK, 256, 0, stream>>>(kvbf, kvf, rope_cos, rope_sin, Kb);
        {   // V^T per head: [128][2048] bf16 (cols h*256+128 of kvbf)
            dim3 g(2, 64, 16);
            k_convT<<<g, 256, 0, stream>>>(kvbf, Vt, 2048, 4096, 128, 128, 256, 0,
                                           (long long)128 * 2048);
        }
        k_flash<<<dim3(NH, 16), 256, 0, stream>>>(qb, Kb, Vt, aout);
        k_mm<1><<<dim3(16, 16), 256, 0, stream>>>(aout, oWt, h, 2048, 2048, 2048, 2048, 2048);

        k_rmsnorm<<<N_TOK, 256, 0, stream>>>(h, 2048, 0, xb, ffn_norm_w + (size_t)l * DIM, 2048);
        k_mm<2><<<dim3(16, 44), 256, 0, stream>>>(xb, w1t, f1, 5632, 2048, 2048, 2048, 5632);
        k_mm<2><<<dim3(16, 44), 256, 0, stream>>>(xb, w2t, f2, 5632, 2048, 2048, 2048, 5632);
        k_silu<<<2048, 256, 0, stream>>>(f1, f2, N_TOK * INTER);
        k_mm<1><<<dim3(16, 16), 256, 0, stream>>>(f1, w3t, h, 2048, 5632, 5632, 5632, 2048);
    }
    k_rmsnorm<<<N_TOK, 256, 0, stream>>>(h, 2048, 0, xb, norm_w, 2048);
    int cn = 32000 / oc;
    for (int c2 = 0; c2 < oc; ++c2) {
        convT(outW, oWtc, 2048, 32000, cn, cn, c2 * cn);
        k_mm<0><<<dim3(16, cn / 128), 256, 0, stream>>>(
            xb, oWtc, (float*)d_out + (size_t)c2 * cn, cn, 2048, 2048, 2048, 32000);
    }
}

// Round 5
// 1776.336 us; speedup vs baseline: 9.5691x; 1.0832x over previous
//
#include <hip/hip_runtime.h>
#include <hip/hip_bf16.h>
#include <math.h>

#define N_TOK 2048
#define DIM   2048
#define NH    16
#define NOPE  128
#define ROPE_D 64
#define QKH   192
#define VH    128
#define KVR   512
#define INTER 5632
#define VOCAB 32000
#define NLAYER 2
#define EPS   1e-6f

typedef __hip_bfloat16 bf16;
typedef __bf16 bf16x8 __attribute__((ext_vector_type(8)));
typedef float  f32x4  __attribute__((ext_vector_type(4)));

__device__ __forceinline__ float bf2f(unsigned short u) {
    union { unsigned u; float f; } a; a.u = ((unsigned)u) << 16; return a.f;
}
__device__ __forceinline__ unsigned short f2bfu(float f) {
    union { float f; unsigned u; } a; a.f = f;
    return (unsigned short)((a.u + 0x7fffu + ((a.u >> 16) & 1u)) >> 16);
}

__device__ __forceinline__ void gload16(const void* g, void* l) {
    __builtin_amdgcn_global_load_lds((const __attribute__((address_space(1))) void*)g,
                                     (__attribute__((address_space(3))) void*)l, 16, 0, 0);
}

// ---------------- embedding gather ----------------
__global__ void k_embed(const int* __restrict__ tokens, const float* __restrict__ emb,
                        float* __restrict__ h) {
    int n = blockIdx.x;
    int t = tokens[n];
    const float4* src = (const float4*)(emb + (size_t)t * DIM);
    float4* dst = (float4*)(h + (size_t)n * DIM);
    for (int i = threadIdx.x; i < DIM / 4; i += blockDim.x) dst[i] = src[i];
}

// ---------------- rmsnorm f32 -> bf16 ----------------
__global__ __launch_bounds__(256) void k_rmsnorm(const float* __restrict__ in, int in_stride, int in_off,
                                                 bf16* __restrict__ out, const float* __restrict__ w,
                                                 int len) {
    int row = blockIdx.x;
    const float* x = in + (size_t)row * in_stride + in_off;
    float ss = 0.f;
    for (int i = threadIdx.x; i < len; i += 256) { float v = x[i]; ss += v * v; }
    for (int off = 32; off > 0; off >>= 1) ss += __shfl_down(ss, off, 64);
    __shared__ float red[4];
    if ((threadIdx.x & 63) == 0) red[threadIdx.x >> 6] = ss;
    __syncthreads();
    float tot = red[0] + red[1] + red[2] + red[3];
    float inv = rsqrtf(tot / (float)len + EPS);
    for (int i = threadIdx.x; i < len; i += 256)
        out[(size_t)row * len + i] = __float2bfloat16(x[i] * inv * w[i]);
}

// ---------------- transpose + convert: W[K][ncols] f32 -> Out[npad][K] bf16 ----------------
__global__ __launch_bounds__(256)
void k_convT(const float* __restrict__ W, bf16* __restrict__ Out,
             int K, int ldw, int ncols, int c0base, int c0step,
             long long inz, long long outz) {
    __shared__ float T[32][65];
    const float* Wz = W + (long long)blockIdx.z * inz;
    bf16* Oz = Out + (long long)blockIdx.z * outz;
    int c0 = c0base + blockIdx.z * c0step;
    int n0 = blockIdx.x * 64, k0 = blockIdx.y * 32;
    int tid = threadIdx.x;
    int rr = tid >> 4, cc = (tid & 15) * 4;
#pragma unroll
    for (int p = 0; p < 2; ++p) {
        int k = k0 + rr + p * 16;
        float4 v = make_float4(0.f, 0.f, 0.f, 0.f);
        if (n0 + cc < ncols) v = *(const float4*)(Wz + (size_t)k * ldw + c0 + n0 + cc);
        T[rr + p * 16][cc + 0] = v.x; T[rr + p * 16][cc + 1] = v.y;
        T[rr + p * 16][cc + 2] = v.z; T[rr + p * 16][cc + 3] = v.w;
    }
    __syncthreads();
    int n = tid >> 2, kc = (tid & 3) * 8;
    __align__(16) bf16 tmp[8];
#pragma unroll
    for (int e = 0; e < 8; ++e) tmp[e] = __float2bfloat16(T[kc + e][n]);
    *(int4*)(Oz + (size_t)(n0 + n) * K + k0 + kc) = *(const int4*)tmp;
}

// ---------------- bf16 MFMA GEMM, 128x128 tile, BK=32 (2-phase, for small N) ----------------
template<int OUT>
__global__ __launch_bounds__(256)
void k_mm(const bf16* __restrict__ A, const bf16* __restrict__ Bt, void* __restrict__ Cv,
          int Nreal, int K, int lda, int ldb, int ldc) {
    int row0 = blockIdx.x * 128, col0 = blockIdx.y * 128;
    __shared__ bf16 As[128 * 32];
    __shared__ bf16 Bs[128 * 32];
    int tid = threadIdx.x;
    int lane = tid & 63, wave = tid >> 6;
    int wm = (wave & 1) * 64, wn = (wave >> 1) * 64;
    int fr = lane & 15, fg = lane >> 4;
    f32x4 acc[4][4] = {};
    for (int k0 = 0; k0 < K; k0 += 32) {
#pragma unroll
        for (int it = 0; it < 2; ++it) {
            int idx = it * 256 + tid;
            int m = idx >> 2, c = idx & 3;
            gload16(A + (size_t)(row0 + m) * lda + k0 + c * 8, As + idx * 8);
        }
#pragma unroll
        for (int it = 0; it < 2; ++it) {
            int idx = it * 256 + tid;
            int m = idx >> 2, c = idx & 3;
            gload16(Bt + (size_t)(col0 + m) * ldb + k0 + c * 8, Bs + idx * 8);
        }
        __syncthreads();
        bf16x8 av[4], bv[4];
#pragma unroll
        for (int i = 0; i < 4; ++i) {
            av[i] = *(const bf16x8*)(As + (wm + i * 16 + fr) * 32 + fg * 8);
            bv[i] = *(const bf16x8*)(Bs + (wn + i * 16 + fr) * 32 + fg * 8);
        }
#pragma unroll
        for (int i = 0; i < 4; ++i)
#pragma unroll
            for (int j = 0; j < 4; ++j)
                acc[i][j] = __builtin_amdgcn_mfma_f32_16x16x32_bf16(av[i], bv[j], acc[i][j], 0, 0, 0);
        __syncthreads();
    }
    float* Cf = (float*)Cv;
    bf16* Cb = (bf16*)Cv;
#pragma unroll
    for (int i = 0; i < 4; ++i)
#pragma unroll
        for (int j = 0; j < 4; ++j)
#pragma unroll
            for (int q = 0; q < 4; ++q) {
                int row = row0 + wm + i * 16 + fg * 4 + q;
                int col = col0 + wn + j * 16 + fr;
                if (col < Nreal) {
                    size_t off = (size_t)row * ldc + col;
                    if (OUT == 0) Cf[off] = acc[i][j][q];
                    else if (OUT == 1) Cf[off] += acc[i][j][q];
                    else Cb[off] = __float2bfloat16(acc[i][j][q]);
                }
            }
}

// ---------------- bf16 MFMA GEMM, 256x256 tile, BK=32, ring-4 LDS, 8-phase/group ----------------
// Counted vmcnt(8) gates (never 0 mid-loop), setprio around MFMA clusters, raw barriers.
// Requires: M%256==0 rows at row0, N%256==0, K%128==0, K>=512. 128 KiB dynamic LDS.
#define TILE8(u, DOSTAGE, GATE) { \
    const int t = t0 + (u); \
    const bf16* sAb = sA_ + (u) * 8192; \
    const bf16* sBb = sB_ + (u) * 8192; \
    bf16* dA = sA_ + (((u) + 3) & 3) * 8192; \
    bf16* dB = sB_ + (((u) + 3) & 3) * 8192; \
    if (DOSTAGE) { \
        size_t kk = (size_t)(t + 3) * 32; \
        gload16(Ag + (size_t)(row0 + (tid >> 2)) * lda + kk + (tid & 3) * 8, dA + tid * 8); \
        gload16(Ag + (size_t)(row0 + 128 + (tid >> 2)) * lda + kk + (tid & 3) * 8, dA + 4096 + tid * 8); \
    } \
    bf16x8 av[8], bv0, bv1; \
    _Pragma("unroll") \
    for (int m = 0; m < 8; ++m) \
        av[m] = *(const bf16x8*)(sAb + (wm * 128 + m * 16 + fr) * 32 + fg * 8); \
    bv0 = *(const bf16x8*)(sBb + (wn * 64 + fr) * 32 + fg * 8); \
    bv1 = *(const bf16x8*)(sBb + (wn * 64 + 16 + fr) * 32 + fg * 8); \
    __builtin_amdgcn_s_barrier(); \
    __builtin_amdgcn_s_setprio(1); \
    _Pragma("unroll") \
    for (int m = 0; m < 8; ++m) { \
        acc[m][0] = __builtin_amdgcn_mfma_f32_16x16x32_bf16(av[m], bv0, acc[m][0], 0, 0, 0); \
        acc[m][1] = __builtin_amdgcn_mfma_f32_16x16x32_bf16(av[m], bv1, acc[m][1], 0, 0, 0); \
    } \
    __builtin_amdgcn_s_setprio(0); \
    __builtin_amdgcn_s_barrier(); \
    if (DOSTAGE) { \
        size_t kk = (size_t)(t + 3) * 32; \
        gload16(Bg + (size_t)(col0 + (tid >> 2)) * ldb + kk + (tid & 3) * 8, dB + tid * 8); \
        gload16(Bg + (size_t)(col0 + 128 + (tid >> 2)) * ldb + kk + (tid & 3) * 8, dB + 4096 + tid * 8); \
    } \
    bf16x8 bv2 = *(const bf16x8*)(sBb + (wn * 64 + 32 + fr) * 32 + fg * 8); \
    bf16x8 bv3 = *(const bf16x8*)(sBb + (wn * 64 + 48 + fr) * 32 + fg * 8); \
    __builtin_amdgcn_s_barrier(); \
    __builtin_amdgcn_s_setprio(1); \
    _Pragma("unroll") \
    for (int m = 0; m < 8; ++m) { \
        acc[m][2] = __builtin_amdgcn_mfma_f32_16x16x32_bf16(av[m], bv2, acc[m][2], 0, 0, 0); \
        acc[m][3] = __builtin_amdgcn_mfma_f32_16x16x32_bf16(av[m], bv3, acc[m][3], 0, 0, 0); \
    } \
    __builtin_amdgcn_s_setprio(0); \
    GATE; \
    __builtin_amdgcn_s_barrier(); \
    __builtin_amdgcn_sched_barrier(0); \
}

template<int OUT>
__global__ __launch_bounds__(512, 2)
void k_mm8(const bf16* __restrict__ Ag, const bf16* __restrict__ Bg, void* __restrict__ Cv,
           int K, int lda, int ldb, int ldc) {
    extern __shared__ char smem_raw[];
    bf16* sA_ = (bf16*)smem_raw;            // 4 bufs x 256x32
    bf16* sB_ = sA_ + 4 * 8192;             // 4 bufs x 256x32
    int tid = threadIdx.x;
    int lane = tid & 63, wid = tid >> 6;
    int wm = wid >> 2, wn = wid & 3;        // 2 x 4 waves, wave tile 128x64
    int fr = lane & 15, fg = lane >> 4;
    int row0 = blockIdx.x * 256, col0 = blockIdx.y * 256;

    f32x4 acc[8][4] = {};
    int nt = K >> 5;

    // prologue: stage tiles 0,1,2 (A then B per tile; 4 loads/thread/tile)
#pragma unroll
    for (int t = 0; t < 3; ++t) {
        size_t kk = (size_t)t * 32;
        bf16* dA = sA_ + t * 8192;
        bf16* dB = sB_ + t * 8192;
        gload16(Ag + (size_t)(row0 + (tid >> 2)) * lda + kk + (tid & 3) * 8, dA + tid * 8);
        gload16(Ag + (size_t)(row0 + 128 + (tid >> 2)) * lda + kk + (tid & 3) * 8, dA + 4096 + tid * 8);
        gload16(Bg + (size_t)(col0 + (tid >> 2)) * ldb + kk + (tid & 3) * 8, dB + tid * 8);
        gload16(Bg + (size_t)(col0 + 128 + (tid >> 2)) * ldb + kk + (tid & 3) * 8, dB + 4096 + tid * 8);
    }
    asm volatile("s_waitcnt vmcnt(8)" ::: "memory");
    __builtin_amdgcn_s_barrier();
    __builtin_amdgcn_sched_barrier(0);

    int ngroups = nt >> 2;
    for (int g = 0; g < ngroups - 1; ++g) {
        int t0 = g * 4;
        TILE8(0, 1, asm volatile("s_waitcnt vmcnt(8)" ::: "memory"));
        TILE8(1, 1, asm volatile("s_waitcnt vmcnt(8)" ::: "memory"));
        TILE8(2, 1, asm volatile("s_waitcnt vmcnt(8)" ::: "memory"));
        TILE8(3, 1, asm volatile("s_waitcnt vmcnt(8)" ::: "memory"));
    }
    {
        int t0 = nt - 4;
        TILE8(0, 1, asm volatile("s_waitcnt vmcnt(8)" ::: "memory"));
        TILE8(1, 0, asm volatile("s_waitcnt vmcnt(4)" ::: "memory"));
        TILE8(2, 0, asm volatile("s_waitcnt vmcnt(0)" ::: "memory"));
        TILE8(3, 0, (void)0);
    }

    float* Cf = (float*)Cv;
    bf16* Cb = (bf16*)Cv;
#pragma unroll
    for (int m = 0; m < 8; ++m)
#pragma unroll
        for (int n = 0; n < 4; ++n)
#pragma unroll
            for (int q = 0; q < 4; ++q) {
                int row = row0 + wm * 128 + m * 16 + fg * 4 + q;
                int col = col0 + wn * 64 + n * 16 + fr;
                size_t off = (size_t)row * ldc + col;
                if (OUT == 0) Cf[off] = acc[m][n][q];
                else if (OUT == 1) Cf[off] += acc[m][n][q];
                else Cb[off] = __float2bfloat16(acc[m][n][q]);
            }
}

// ---------------- q rope + pack to [h][n][192] bf16 ----------------
__global__ __launch_bounds__(256) void k_qpack(const float* __restrict__ q,
        const float* __restrict__ cosb, const float* __restrict__ sinb,
        bf16* __restrict__ qb) {
    int n = blockIdx.x;
    __shared__ float c[32], s[32];
    if (threadIdx.x < 32) {
        c[threadIdx.x] = cosb[n * 32 + threadIdx.x];
        s[threadIdx.x] = sinb[n * 32 + threadIdx.x];
    }
    __syncthreads();
    const float* row = q + (size_t)n * (NH * QKH);
    for (int idx = threadIdx.x; idx < NH * QKH; idx += 256) {
        int h = idx / QKH, d = idx - h * QKH;
        float v;
        if (d < NOPE) v = row[idx];
        else {
            int i = (d - NOPE) >> 1;
            float xr = row[h * QKH + NOPE + 2 * i], xi = row[h * QKH + NOPE + 2 * i + 1];
            v = ((d & 1) == 0) ? xr * c[i] - xi * s[i] : xr * s[i] + xi * c[i];
        }
        qb[(size_t)h * (N_TOK * QKH) + (size_t)n * QKH + d] = __float2bfloat16(v);
    }
}

// ---------------- K pack: [h][key][192] bf16 ----------------
__global__ __launch_bounds__(256) void k_packK(const float* __restrict__ kvb,
        const float* __restrict__ kvf, const float* __restrict__ cosb, const float* __restrict__ sinb,
        bf16* __restrict__ Kb) {
    int key = blockIdx.x;
    __shared__ float rp[ROPE_D];
    if (threadIdx.x < 32) {
        float c = cosb[key * 32 + threadIdx.x], s = sinb[key * 32 + threadIdx.x];
        float xr = kvf[(size_t)key * (ROPE_D + KVR) + 2 * threadIdx.x];
        float xi = kvf[(size_t)key * (ROPE_D + KVR) + 2 * threadIdx.x + 1];
        rp[2 * threadIdx.x] = xr * c - xi * s;
        rp[2 * threadIdx.x + 1] = xr * s + xi * c;
    }
    __syncthreads();
    const float* row = kvb + (size_t)key * (NH * (NOPE + VH));
    for (int idx = threadIdx.x; idx < NH * QKH; idx += 256) {
        int h = idx / QKH, d = idx - h * QKH;
        float v = (d < NOPE) ? row[h * (NOPE + VH) + d] : rp[d - NOPE];
        Kb[(size_t)h * (N_TOK * QKH) + (size_t)key * QKH + d] = __float2bfloat16(v);
    }
}

// ---------------- fused flash attention: grid (NH, 16 q-panels), 4 waves ----------------
__global__ __launch_bounds__(256, 2)
void k_flash(const bf16* __restrict__ qb, const bf16* __restrict__ Kb,
             const bf16* __restrict__ Vt, bf16* __restrict__ aout) {
    int h = blockIdx.x, qp = blockIdx.y;
    __shared__ short Ks[64 * 200];
    __shared__ short Vs[128 * 72];
    __shared__ short Ps[128 * 72];
    int t = threadIdx.x;
    int lane = t & 63, w = t >> 6;
    int fr = lane & 15, fg = lane >> 4;
    const float scale = 0.07216878364870322f;  // 1/sqrt(192)

    bf16x8 aq[2][6];
    const bf16* Qsrc = qb + ((size_t)h * N_TOK + qp * 128 + w * 32) * QKH;
#pragma unroll
    for (int i = 0; i < 2; ++i)
#pragma unroll
        for (int ks = 0; ks < 6; ++ks)
            aq[i][ks] = *(const bf16x8*)(Qsrc + (size_t)(i * 16 + fr) * QKH + ks * 32 + fg * 8);

    f32x4 acc_o[2][8] = {};
    float m_r[2][4], l_r[2][4];
#pragma unroll
    for (int i = 0; i < 2; ++i)
#pragma unroll
        for (int q = 0; q < 4; ++q) { m_r[i][q] = -1e30f; l_r[i][q] = 0.f; }

    int nkt = 2 * qp + 2;
    const bf16* Kbase = Kb + (size_t)h * N_TOK * QKH;
    const bf16* Vbase = Vt + (size_t)h * VH * N_TOK;

    for (int kt = 0; kt < nkt; ++kt) {
        __syncthreads();
        {
            const bf16* Ksrc = Kbase + (size_t)kt * 64 * QKH;
#pragma unroll
            for (int c = 0; c < 6; ++c) {
                int idx = c * 256 + t;
                int row = idx / 24, c16 = idx - row * 24;
                int4 v = *(const int4*)(Ksrc + row * QKH + c16 * 8);
                *(int4*)(Ks + row * 200 + c16 * 8) = v;
            }
            const bf16* Vsrc = Vbase + kt * 64;
#pragma unroll
            for (int c = 0; c < 4; ++c) {
                int idx = c * 256 + t;
                int row = idx >> 3, c8 = idx & 7;
                int4 v = *(const int4*)(Vsrc + (size_t)row * N_TOK + c8 * 8);
                *(int4*)(Vs + row * 72 + c8 * 8) = v;
            }
        }
        __syncthreads();
        f32x4 acc_s[2][4] = {};
#pragma unroll
        for (int ks = 0; ks < 6; ++ks) {
            bf16x8 bv[4];
#pragma unroll
            for (int j = 0; j < 4; ++j)
                bv[j] = *(const bf16x8*)(Ks + (j * 16 + fr) * 200 + ks * 32 + fg * 8);
#pragma unroll
            for (int i = 0; i < 2; ++i)
#pragma unroll
                for (int j = 0; j < 4; ++j)
                    acc_s[i][j] = __builtin_amdgcn_mfma_f32_16x16x32_bf16(aq[i][ks], bv[j], acc_s[i][j], 0, 0, 0);
        }
        if (kt >= 2 * qp) {
            int colb = kt * 64;
            int rowb = qp * 128 + w * 32;
#pragma unroll
            for (int i = 0; i < 2; ++i)
#pragma unroll
                for (int j = 0; j < 4; ++j)
#pragma unroll
                    for (int q = 0; q < 4; ++q)
                        if (colb + j * 16 + fr > rowb + i * 16 + fg * 4 + q)
                            acc_s[i][j][q] = -1e30f;
        }
#pragma unroll
        for (int i = 0; i < 2; ++i) {
#pragma unroll
            for (int q = 0; q < 4; ++q) {
                float tmax = fmaxf(fmaxf(acc_s[i][0][q], acc_s[i][1][q]),
                                   fmaxf(acc_s[i][2][q], acc_s[i][3][q]));
                tmax = fmaxf(tmax, __shfl_xor(tmax, 1, 64));
                tmax = fmaxf(tmax, __shfl_xor(tmax, 2, 64));
                tmax = fmaxf(tmax, __shfl_xor(tmax, 4, 64));
                tmax = fmaxf(tmax, __shfl_xor(tmax, 8, 64));
                float mn = fmaxf(m_r[i][q], tmax);
                float sc = __expf(scale * (m_r[i][q] - mn));
                m_r[i][q] = mn;
                float s0 = 0.f;
#pragma unroll
                for (int j = 0; j < 4; ++j) {
                    float pv = __expf(scale * (acc_s[i][j][q] - mn));
                    acc_s[i][j][q] = pv;
                    s0 += pv;
                }
                s0 += __shfl_xor(s0, 1, 64);
                s0 += __shfl_xor(s0, 2, 64);
                s0 += __shfl_xor(s0, 4, 64);
                s0 += __shfl_xor(s0, 8, 64);
                l_r[i][q] = l_r[i][q] * sc + s0;
#pragma unroll
                for (int jo = 0; jo < 8; ++jo) acc_o[i][jo][q] *= sc;
            }
        }
#pragma unroll
        for (int i = 0; i < 2; ++i)
#pragma unroll
            for (int j = 0; j < 4; ++j)
#pragma unroll
                for (int q = 0; q < 4; ++q)
                    Ps[(w * 32 + i * 16 + fg * 4 + q) * 72 + j * 16 + fr] =
                        (short)f2bfu(acc_s[i][j][q]);
#pragma unroll
        for (int ks2 = 0; ks2 < 2; ++ks2) {
            bf16x8 pa[2];
#pragma unroll
            for (int i = 0; i < 2; ++i)
                pa[i] = *(const bf16x8*)(Ps + (w * 32 + i * 16 + fr) * 72 + ks2 * 32 + fg * 8);
#pragma unroll
            for (int jo = 0; jo < 8; ++jo) {
                bf16x8 vb = *(const bf16x8*)(Vs + (jo * 16 + fr) * 72 + ks2 * 32 + fg * 8);
#pragma unroll
                for (int i = 0; i < 2; ++i)
                    acc_o[i][jo] = __builtin_amdgcn_mfma_f32_16x16x32_bf16(pa[i], vb, acc_o[i][jo], 0, 0, 0);
            }
        }
    }
    bf16* obase = aout + (size_t)(qp * 128 + w * 32) * (NH * VH) + h * VH;
#pragma unroll
    for (int i = 0; i < 2; ++i)
#pragma unroll
        for (int q = 0; q < 4; ++q) {
            float inv = 1.f / l_r[i][q];
#pragma unroll
            for (int jo = 0; jo < 8; ++jo)
                obase[(size_t)(i * 16 + fg * 4 + q) * (NH * VH) + jo * 16 + fr] =
                    __float2bfloat16(acc_o[i][jo][q] * inv);
        }
}

// ---------------- silu(a)*b -> a, bf16 vectorized ----------------
__global__ void k_silu(bf16* __restrict__ a, const bf16* __restrict__ b, int n) {
    int i = (blockIdx.x * blockDim.x + threadIdx.x) * 8;
    int stride = gridDim.x * blockDim.x * 8;
    for (; i < n; i += stride) {
        uint4 ua = *(const uint4*)((const unsigned short*)a + i);
        uint4 ub = *(const uint4*)((const unsigned short*)b + i);
        unsigned* pa = &ua.x; const unsigned* pb = &ub.x;
#pragma unroll
        for (int w = 0; w < 4; ++w) {
            float x0 = bf2f((unsigned short)(pa[w] & 0xffffu));
            float x1 = bf2f((unsigned short)(pa[w] >> 16));
            float y0 = bf2f((unsigned short)(pb[w] & 0xffffu));
            float y1 = bf2f((unsigned short)(pb[w] >> 16));
            float r0 = x0 / (1.f + __expf(-x0)) * y0;
            float r1 = x1 / (1.f + __expf(-x1)) * y1;
            pa[w] = (unsigned)f2bfu(r0) | ((unsigned)f2bfu(r1) << 16);
        }
        *(uint4*)((unsigned short*)a + i) = ua;
    }
}

extern "C" void kernel_launch(void* const* d_in, const int* in_sizes, int n_in,
                              void* d_out, int out_size, void* d_ws, size_t ws_size,
                              hipStream_t stream) {
    (void)in_sizes; (void)n_in; (void)out_size;
    const int* tokens = (const int*)d_in[0];
    const float* emb = (const float*)d_in[1];
    const float* qW = (const float*)d_in[2];
    const float* kvaW = (const float*)d_in[3];
    const float* kvnorm_w = (const float*)d_in[4];
    const float* kvbW = (const float*)d_in[5];
    const float* oW = (const float*)d_in[6];
    const float* w1 = (const float*)d_in[7];
    const float* w2 = (const float*)d_in[8];
    const float* w3 = (const float*)d_in[9];
    const float* attn_norm_w = (const float*)d_in[10];
    const float* ffn_norm_w = (const float*)d_in[11];
    const float* norm_w = (const float*)d_in[12];
    const float* outW = (const float*)d_in[13];
    const float* rope_cos = (const float*)d_in[14];
    const float* rope_sin = (const float*)d_in[15];

    hipFuncSetAttribute((const void*)k_mm8<0>, hipFuncAttributeMaxDynamicSharedMemorySize, 131072);
    hipFuncSetAttribute((const void*)k_mm8<2>, hipFuncAttributeMaxDynamicSharedMemorySize, 131072);

    float* ws = (float*)d_ws;
    size_t off = 0;
    auto allocF = [&](size_t fl) { float* p = ws + off; off += (fl + 63) & ~63ULL; return p; };
    float* h    = allocF(4194304);            // [2048][2048] f32
    bf16* xb    = (bf16*)allocF(2097152);     // [2048][2048] bf16
    float* kvf  = allocF(1179648);            // [2048][576] f32
    bf16* cb    = (bf16*)allocF(524288);      // [2048][512] bf16
    bf16* qb    = (bf16*)allocF(3145728);     // [16][2048][192] bf16
    bf16* Kb    = (bf16*)allocF(3145728);     // [16][2048][192] bf16
    bf16* Vt    = (bf16*)allocF(2097152);     // [16][128][2048] bf16
    bf16* aout  = (bf16*)allocF(2097152);     // [2048][2048] bf16
    bf16* qWt   = (bf16*)allocF(3145728);     // [3072][2048]
    bf16* kvaWt = (bf16*)allocF(655360);      // [640][2048]
    bf16* kvbWt = (bf16*)allocF(1048576);     // [4096][512]
    bf16* oWt   = (bf16*)allocF(2097152);     // [2048][2048]
    bf16* w1t   = (bf16*)allocF(5767168);     // [5632][2048]
    bf16* w2t   = (bf16*)allocF(5767168);
    bf16* w3t   = (bf16*)allocF(5767168);     // [2048][5632]
    float* scr  = ws + off;
    size_t availF = (ws_size / 4 > off) ? ws_size / 4 - off : 0;

    int oc = 25;
    {
        const int ocs[3] = {1, 5, 25};
        for (int i = 0; i < 3; ++i) {
            size_t need = 11534336;                        // ffn f1+f2
            size_t a2 = (size_t)32768000 / ocs[i];         // outW chunk (bf16, in floats)
            if (a2 > need) need = a2;
            if (8388608 > need) need = 8388608;            // kvbf f32
            if (need <= availF) { oc = ocs[i]; break; }
        }
    }
    float* qf   = scr;                          // [2048][3072] f32 (transient)
    float* kvbf = scr;                          // [2048][4096] f32 (transient)
    bf16* f1    = (bf16*)scr;                   // [2048][5632] bf16
    bf16* f2    = f1 + 11534336;
    bf16* oWtc  = (bf16*)scr;                   // outW chunk [cn][2048]

    auto convT = [&](const float* W, bf16* Out, int K, int ldw, int ncols, int npad,
                     int c0) {
        dim3 g(npad / 64, K / 32, 1);
        k_convT<<<g, 256, 0, stream>>>(W, Out, K, ldw, ncols, c0, 0, 0, 0);
    };

    k_embed<<<N_TOK, 256, 0, stream>>>(tokens, emb, h);

    for (int l = 0; l < NLAYER; ++l) {
        convT(qW + (size_t)l * DIM * 3072, qWt, 2048, 3072, 3072, 3072, 0);
        convT(kvaW + (size_t)l * DIM * 576, kvaWt, 2048, 576, 576, 640, 0);
        convT(kvbW + (size_t)l * 512 * 4096, kvbWt, 512, 4096, 4096, 4096, 0);
        convT(oW + (size_t)l * 2048 * 2048, oWt, 2048, 2048, 2048, 2048, 0);
        convT(w1 + (size_t)l * DIM * INTER, w1t, 2048, 5632, 5632, 5632, 0);
        convT(w2 + (size_t)l * DIM * INTER, w2t, 2048, 5632, 5632, 5632, 0);
        convT(w3 + (size_t)l * INTER * DIM, w3t, 5632, 2048, 2048, 2048, 0);

        k_rmsnorm<<<N_TOK, 256, 0, stream>>>(h, 2048, 0, xb, attn_norm_w + (size_t)l * DIM, 2048);
        k_mm<0><<<dim3(16, 24), 256, 0, stream>>>(xb, qWt, qf, 3072, 2048, 2048, 2048, 3072);
        k_mm<0><<<dim3(16, 5), 256, 0, stream>>>(xb, kvaWt, kvf, 576, 2048, 2048, 2048, 576);
        k_qpack<<<N_TOK, 256, 0, stream>>>(qf, rope_cos, rope_sin, qb);
        k_rmsnorm<<<N_TOK, 256, 0, stream>>>(kvf, 576, 64, cb, kvnorm_w + (size_t)l * KVR, 512);
        k_mm<0><<<dim3(16, 32), 256, 0, stream>>>(cb, kvbWt, kvbf, 4096, 512, 512, 512, 4096);
        k_packK<<<N_TOK, 256, 0, stream>>>(kvbf, kvf, rope_cos, rope_sin, Kb);
        {   // V^T per head: [128][2048] bf16 (cols h*256+128 of kvbf)
            dim3 g(2, 64, 16);
            k_convT<<<g, 256, 0, stream>>>(kvbf, Vt, 2048, 4096, 128, 128, 256, 0,
                                           (long long)128 * 2048);
        }
        k_flash<<<dim3(NH, 16), 256, 0, stream>>>(qb, Kb, Vt, aout);
        k_mm<1><<<dim3(16, 16), 256, 0, stream>>>(aout, oWt, h, 2048, 2048, 2048, 2048, 2048);

        k_rmsnorm<<<N_TOK, 256, 0, stream>>>(h, 2048, 0, xb, ffn_norm_w + (size_t)l * DIM, 2048);
        k_mm8<2><<<dim3(8, 22), 512, 131072, stream>>>(xb, w1t, f1, 2048, 2048, 2048, 5632);
        k_mm8<2><<<dim3(8, 22), 512, 131072, stream>>>(xb, w2t, f2, 2048, 2048, 2048, 5632);
        k_silu<<<2048, 256, 0, stream>>>(f1, f2, N_TOK * INTER);
        k_mm<1><<<dim3(16, 16), 256, 0, stream>>>(f1, w3t, h, 2048, 5632, 5632, 5632, 2048);
    }
    k_rmsnorm<<<N_TOK, 256, 0, stream>>>(h, 2048, 0, xb, norm_w, 2048);
    int cn = 32000 / oc;
    for (int c2 = 0; c2 < oc; ++c2) {
        convT(outW, oWtc, 2048, 32000, cn, cn, c2 * cn);
        k_mm8<0><<<dim3(8, cn / 256), 512, 131072, stream>>>(
            xb, oWtc, (float*)d_out + (size_t)c2 * cn, 2048, 2048, 2048, 32000);
    }
}

// Round 6
// 1730.407 us; speedup vs baseline: 9.8231x; 1.0265x over previous
//
#include <hip/hip_runtime.h>
#include <hip/hip_bf16.h>
#include <math.h>

#define N_TOK 2048
#define DIM   2048
#define NH    16
#define NOPE  128
#define ROPE_D 64
#define QKH   192
#define VH    128
#define KVR   512
#define INTER 5632
#define VOCAB 32000
#define NLAYER 2
#define EPS   1e-6f

typedef __hip_bfloat16 bf16;
typedef __bf16 bf16x8 __attribute__((ext_vector_type(8)));
typedef float  f32x4  __attribute__((ext_vector_type(4)));

__device__ __forceinline__ float bf2f(unsigned short u) {
    union { unsigned u; float f; } a; a.u = ((unsigned)u) << 16; return a.f;
}
__device__ __forceinline__ unsigned short f2bfu(float f) {
    union { float f; unsigned u; } a; a.f = f;
    return (unsigned short)((a.u + 0x7fffu + ((a.u >> 16) & 1u)) >> 16);
}

__device__ __forceinline__ void gload16(const void* g, void* l) {
    __builtin_amdgcn_global_load_lds((const __attribute__((address_space(1))) void*)g,
                                     (__attribute__((address_space(3))) void*)l, 16, 0, 0);
}

// ---------------- embedding gather ----------------
__global__ void k_embed(const int* __restrict__ tokens, const float* __restrict__ emb,
                        float* __restrict__ h) {
    int n = blockIdx.x;
    int t = tokens[n];
    const float4* src = (const float4*)(emb + (size_t)t * DIM);
    float4* dst = (float4*)(h + (size_t)n * DIM);
    for (int i = threadIdx.x; i < DIM / 4; i += blockDim.x) dst[i] = src[i];
}

// ---------------- rmsnorm f32 -> bf16 ----------------
__global__ __launch_bounds__(256) void k_rmsnorm(const float* __restrict__ in, int in_stride, int in_off,
                                                 bf16* __restrict__ out, const float* __restrict__ w,
                                                 int len) {
    int row = blockIdx.x;
    const float* x = in + (size_t)row * in_stride + in_off;
    float ss = 0.f;
    for (int i = threadIdx.x; i < len; i += 256) { float v = x[i]; ss += v * v; }
    for (int off = 32; off > 0; off >>= 1) ss += __shfl_down(ss, off, 64);
    __shared__ float red[4];
    if ((threadIdx.x & 63) == 0) red[threadIdx.x >> 6] = ss;
    __syncthreads();
    float tot = red[0] + red[1] + red[2] + red[3];
    float inv = rsqrtf(tot / (float)len + EPS);
    for (int i = threadIdx.x; i < len; i += 256)
        out[(size_t)row * len + i] = __float2bfloat16(x[i] * inv * w[i]);
}

// ---------------- transpose + convert: W[K][ncols] f32 -> Out[npad][K] bf16 ----------------
__global__ __launch_bounds__(256)
void k_convT(const float* __restrict__ W, bf16* __restrict__ Out,
             int K, int ldw, int ncols, int c0base, int c0step,
             long long inz, long long outz) {
    __shared__ float T[32][65];
    const float* Wz = W + (long long)blockIdx.z * inz;
    bf16* Oz = Out + (long long)blockIdx.z * outz;
    int c0 = c0base + blockIdx.z * c0step;
    int n0 = blockIdx.x * 64, k0 = blockIdx.y * 32;
    int tid = threadIdx.x;
    int rr = tid >> 4, cc = (tid & 15) * 4;
#pragma unroll
    for (int p = 0; p < 2; ++p) {
        int k = k0 + rr + p * 16;
        float4 v = make_float4(0.f, 0.f, 0.f, 0.f);
        if (n0 + cc < ncols) v = *(const float4*)(Wz + (size_t)k * ldw + c0 + n0 + cc);
        T[rr + p * 16][cc + 0] = v.x; T[rr + p * 16][cc + 1] = v.y;
        T[rr + p * 16][cc + 2] = v.z; T[rr + p * 16][cc + 3] = v.w;
    }
    __syncthreads();
    int n = tid >> 2, kc = (tid & 3) * 8;
    __align__(16) bf16 tmp[8];
#pragma unroll
    for (int e = 0; e < 8; ++e) tmp[e] = __float2bfloat16(T[kc + e][n]);
    *(int4*)(Oz + (size_t)(n0 + n) * K + k0 + kc) = *(const int4*)tmp;
}

// ---------------- bf16 MFMA GEMM, 128x128 tile, BK=32 (2-phase, for small N) ----------------
template<int OUT>
__global__ __launch_bounds__(256)
void k_mm(const bf16* __restrict__ A, const bf16* __restrict__ Bt, void* __restrict__ Cv,
          int Nreal, int K, int lda, int ldb, int ldc) {
    int row0 = blockIdx.x * 128, col0 = blockIdx.y * 128;
    __shared__ bf16 As[128 * 32];
    __shared__ bf16 Bs[128 * 32];
    int tid = threadIdx.x;
    int lane = tid & 63, wave = tid >> 6;
    int wm = (wave & 1) * 64, wn = (wave >> 1) * 64;
    int fr = lane & 15, fg = lane >> 4;
    f32x4 acc[4][4] = {};
    for (int k0 = 0; k0 < K; k0 += 32) {
#pragma unroll
        for (int it = 0; it < 2; ++it) {
            int idx = it * 256 + tid;
            int m = idx >> 2, c = idx & 3;
            gload16(A + (size_t)(row0 + m) * lda + k0 + c * 8, As + idx * 8);
        }
#pragma unroll
        for (int it = 0; it < 2; ++it) {
            int idx = it * 256 + tid;
            int m = idx >> 2, c = idx & 3;
            gload16(Bt + (size_t)(col0 + m) * ldb + k0 + c * 8, Bs + idx * 8);
        }
        __syncthreads();
        bf16x8 av[4], bv[4];
#pragma unroll
        for (int i = 0; i < 4; ++i) {
            av[i] = *(const bf16x8*)(As + (wm + i * 16 + fr) * 32 + fg * 8);
            bv[i] = *(const bf16x8*)(Bs + (wn + i * 16 + fr) * 32 + fg * 8);
        }
#pragma unroll
        for (int i = 0; i < 4; ++i)
#pragma unroll
            for (int j = 0; j < 4; ++j)
                acc[i][j] = __builtin_amdgcn_mfma_f32_16x16x32_bf16(av[i], bv[j], acc[i][j], 0, 0, 0);
        __syncthreads();
    }
    float* Cf = (float*)Cv;
    bf16* Cb = (bf16*)Cv;
#pragma unroll
    for (int i = 0; i < 4; ++i)
#pragma unroll
        for (int j = 0; j < 4; ++j)
#pragma unroll
            for (int q = 0; q < 4; ++q) {
                int row = row0 + wm + i * 16 + fg * 4 + q;
                int col = col0 + wn + j * 16 + fr;
                if (col < Nreal) {
                    size_t off = (size_t)row * ldc + col;
                    if (OUT == 0) Cf[off] = acc[i][j][q];
                    else if (OUT == 1) Cf[off] += acc[i][j][q];
                    else Cb[off] = __float2bfloat16(acc[i][j][q]);
                }
            }
}

// ---------------- bf16 MFMA GEMM, 256x256 tile, BK=32, ring-4 LDS, 8-phase/group ----------------
// T2 XOR-swizzle: LDS(row, slot) holds global slot (slot ^ ((row>>1)&3)); linear gload_lds dest,
// pre-swizzled global source, matching XOR on ds_read (collapses to per-lane constant).
// Counted vmcnt(8) gates (never 0 mid-loop), setprio around MFMA clusters, raw barriers.
// Requires: M%256==0, N%256==0, K%128==0, K>=512. 128 KiB dynamic LDS.
#define TILE8(u, DOSTAGE, GATE) { \
    const int t = t0 + (u); \
    const bf16* sAb = sA_ + (u) * 8192; \
    const bf16* sBb = sB_ + (u) * 8192; \
    bf16* dA = sA_ + (((u) + 3) & 3) * 8192; \
    bf16* dB = sB_ + (((u) + 3) & 3) * 8192; \
    if (DOSTAGE) { \
        size_t kk = (size_t)(t + 3) * 32; \
        gload16(Ag + (size_t)(row0 + srow) * lda + kk + scol * 8, dA + tid * 8); \
        gload16(Ag + (size_t)(row0 + 128 + srow) * lda + kk + scol * 8, dA + 4096 + tid * 8); \
    } \
    bf16x8 av[8], bv0, bv1; \
    _Pragma("unroll") \
    for (int m = 0; m < 8; ++m) \
        av[m] = *(const bf16x8*)(sAb + (wm * 128 + m * 16 + fr) * 32 + swz); \
    bv0 = *(const bf16x8*)(sBb + (wn * 64 + fr) * 32 + swz); \
    bv1 = *(const bf16x8*)(sBb + (wn * 64 + 16 + fr) * 32 + swz); \
    __builtin_amdgcn_s_barrier(); \
    __builtin_amdgcn_s_setprio(1); \
    _Pragma("unroll") \
    for (int m = 0; m < 8; ++m) { \
        acc[m][0] = __builtin_amdgcn_mfma_f32_16x16x32_bf16(av[m], bv0, acc[m][0], 0, 0, 0); \
        acc[m][1] = __builtin_amdgcn_mfma_f32_16x16x32_bf16(av[m], bv1, acc[m][1], 0, 0, 0); \
    } \
    __builtin_amdgcn_s_setprio(0); \
    __builtin_amdgcn_s_barrier(); \
    if (DOSTAGE) { \
        size_t kk = (size_t)(t + 3) * 32; \
        gload16(Bg + (size_t)(col0 + srow) * ldb + kk + scol * 8, dB + tid * 8); \
        gload16(Bg + (size_t)(col0 + 128 + srow) * ldb + kk + scol * 8, dB + 4096 + tid * 8); \
    } \
    bf16x8 bv2 = *(const bf16x8*)(sBb + (wn * 64 + 32 + fr) * 32 + swz); \
    bf16x8 bv3 = *(const bf16x8*)(sBb + (wn * 64 + 48 + fr) * 32 + swz); \
    __builtin_amdgcn_s_barrier(); \
    __builtin_amdgcn_s_setprio(1); \
    _Pragma("unroll") \
    for (int m = 0; m < 8; ++m) { \
        acc[m][2] = __builtin_amdgcn_mfma_f32_16x16x32_bf16(av[m], bv2, acc[m][2], 0, 0, 0); \
        acc[m][3] = __builtin_amdgcn_mfma_f32_16x16x32_bf16(av[m], bv3, acc[m][3], 0, 0, 0); \
    } \
    __builtin_amdgcn_s_setprio(0); \
    GATE; \
    __builtin_amdgcn_s_barrier(); \
    __builtin_amdgcn_sched_barrier(0); \
}

template<int OUT>
__global__ __launch_bounds__(512, 2)
void k_mm8(const bf16* __restrict__ Ag, const bf16* __restrict__ Bg, void* __restrict__ Cv,
           int K, int lda, int ldb, int ldc) {
    extern __shared__ char smem_raw[];
    bf16* sA_ = (bf16*)smem_raw;            // 4 bufs x 256x32
    bf16* sB_ = sA_ + 4 * 8192;             // 4 bufs x 256x32
    int tid = threadIdx.x;
    int lane = tid & 63, wid = tid >> 6;
    int wm = wid >> 2, wn = wid & 3;        // 2 x 4 waves, wave tile 128x64
    int fr = lane & 15, fg = lane >> 4;
    int row0 = blockIdx.x * 256, col0 = blockIdx.y * 256;
    // T2 swizzle constants
    int srow = tid >> 2;
    int scol = (tid & 3) ^ ((srow >> 1) & 3);            // staging source slot
    int swz = (fg ^ ((fr >> 1) & 3)) * 8;                // read slot (elem offset)

    f32x4 acc[8][4] = {};
    int nt = K >> 5;

    // prologue: stage tiles 0,1,2
#pragma unroll
    for (int t = 0; t < 3; ++t) {
        size_t kk = (size_t)t * 32;
        bf16* dA = sA_ + t * 8192;
        bf16* dB = sB_ + t * 8192;
        gload16(Ag + (size_t)(row0 + srow) * lda + kk + scol * 8, dA + tid * 8);
        gload16(Ag + (size_t)(row0 + 128 + srow) * lda + kk + scol * 8, dA + 4096 + tid * 8);
        gload16(Bg + (size_t)(col0 + srow) * ldb + kk + scol * 8, dB + tid * 8);
        gload16(Bg + (size_t)(col0 + 128 + srow) * ldb + kk + scol * 8, dB + 4096 + tid * 8);
    }
    asm volatile("s_waitcnt vmcnt(8)" ::: "memory");
    __builtin_amdgcn_s_barrier();
    __builtin_amdgcn_sched_barrier(0);

    int ngroups = nt >> 2;
    for (int g = 0; g < ngroups - 1; ++g) {
        int t0 = g * 4;
        TILE8(0, 1, asm volatile("s_waitcnt vmcnt(8)" ::: "memory"));
        TILE8(1, 1, asm volatile("s_waitcnt vmcnt(8)" ::: "memory"));
        TILE8(2, 1, asm volatile("s_waitcnt vmcnt(8)" ::: "memory"));
        TILE8(3, 1, asm volatile("s_waitcnt vmcnt(8)" ::: "memory"));
    }
    {
        int t0 = nt - 4;
        TILE8(0, 1, asm volatile("s_waitcnt vmcnt(8)" ::: "memory"));
        TILE8(1, 0, asm volatile("s_waitcnt vmcnt(4)" ::: "memory"));
        TILE8(2, 0, asm volatile("s_waitcnt vmcnt(0)" ::: "memory"));
        TILE8(3, 0, (void)0);
    }

    float* Cf = (float*)Cv;
    bf16* Cb = (bf16*)Cv;
#pragma unroll
    for (int m = 0; m < 8; ++m)
#pragma unroll
        for (int n = 0; n < 4; ++n)
#pragma unroll
            for (int q = 0; q < 4; ++q) {
                int row = row0 + wm * 128 + m * 16 + fg * 4 + q;
                int col = col0 + wn * 64 + n * 16 + fr;
                size_t off = (size_t)row * ldc + col;
                if (OUT == 0) Cf[off] = acc[m][n][q];
                else if (OUT == 1) Cf[off] += acc[m][n][q];
                else Cb[off] = __float2bfloat16(acc[m][n][q]);
            }
}

// ---------------- q rope + pack to [h][n][192] bf16 ----------------
__global__ __launch_bounds__(256) void k_qpack(const float* __restrict__ q,
        const float* __restrict__ cosb, const float* __restrict__ sinb,
        bf16* __restrict__ qb) {
    int n = blockIdx.x;
    __shared__ float c[32], s[32];
    if (threadIdx.x < 32) {
        c[threadIdx.x] = cosb[n * 32 + threadIdx.x];
        s[threadIdx.x] = sinb[n * 32 + threadIdx.x];
    }
    __syncthreads();
    const float* row = q + (size_t)n * (NH * QKH);
    for (int idx = threadIdx.x; idx < NH * QKH; idx += 256) {
        int h = idx / QKH, d = idx - h * QKH;
        float v;
        if (d < NOPE) v = row[idx];
        else {
            int i = (d - NOPE) >> 1;
            float xr = row[h * QKH + NOPE + 2 * i], xi = row[h * QKH + NOPE + 2 * i + 1];
            v = ((d & 1) == 0) ? xr * c[i] - xi * s[i] : xr * s[i] + xi * c[i];
        }
        qb[(size_t)h * (N_TOK * QKH) + (size_t)n * QKH + d] = __float2bfloat16(v);
    }
}

// ---------------- K pack: [h][key][192] bf16 ----------------
__global__ __launch_bounds__(256) void k_packK(const float* __restrict__ kvb,
        const float* __restrict__ kvf, const float* __restrict__ cosb, const float* __restrict__ sinb,
        bf16* __restrict__ Kb) {
    int key = blockIdx.x;
    __shared__ float rp[ROPE_D];
    if (threadIdx.x < 32) {
        float c = cosb[key * 32 + threadIdx.x], s = sinb[key * 32 + threadIdx.x];
        float xr = kvf[(size_t)key * (ROPE_D + KVR) + 2 * threadIdx.x];
        float xi = kvf[(size_t)key * (ROPE_D + KVR) + 2 * threadIdx.x + 1];
        rp[2 * threadIdx.x] = xr * c - xi * s;
        rp[2 * threadIdx.x + 1] = xr * s + xi * c;
    }
    __syncthreads();
    const float* row = kvb + (size_t)key * (NH * (NOPE + VH));
    for (int idx = threadIdx.x; idx < NH * QKH; idx += 256) {
        int h = idx / QKH, d = idx - h * QKH;
        float v = (d < NOPE) ? row[h * (NOPE + VH) + d] : rp[d - NOPE];
        Kb[(size_t)h * (N_TOK * QKH) + (size_t)key * QKH + d] = __float2bfloat16(v);
    }
}

// ---------------- fused flash attention: grid (NH, 16 q-panels), 4 waves ----------------
__global__ __launch_bounds__(256, 2)
void k_flash(const bf16* __restrict__ qb, const bf16* __restrict__ Kb,
             const bf16* __restrict__ Vt, bf16* __restrict__ aout) {
    int h = blockIdx.x, qp = blockIdx.y;
    __shared__ short Ks[64 * 200];
    __shared__ short Vs[128 * 72];
    __shared__ short Ps[128 * 72];
    int t = threadIdx.x;
    int lane = t & 63, w = t >> 6;
    int fr = lane & 15, fg = lane >> 4;
    const float scale = 0.07216878364870322f;  // 1/sqrt(192)

    bf16x8 aq[2][6];
    const bf16* Qsrc = qb + ((size_t)h * N_TOK + qp * 128 + w * 32) * QKH;
#pragma unroll
    for (int i = 0; i < 2; ++i)
#pragma unroll
        for (int ks = 0; ks < 6; ++ks)
            aq[i][ks] = *(const bf16x8*)(Qsrc + (size_t)(i * 16 + fr) * QKH + ks * 32 + fg * 8);

    f32x4 acc_o[2][8] = {};
    float m_r[2][4], l_r[2][4];
#pragma unroll
    for (int i = 0; i < 2; ++i)
#pragma unroll
        for (int q = 0; q < 4; ++q) { m_r[i][q] = -1e30f; l_r[i][q] = 0.f; }

    int nkt = 2 * qp + 2;
    const bf16* Kbase = Kb + (size_t)h * N_TOK * QKH;
    const bf16* Vbase = Vt + (size_t)h * VH * N_TOK;

    for (int kt = 0; kt < nkt; ++kt) {
        __syncthreads();
        {
            const bf16* Ksrc = Kbase + (size_t)kt * 64 * QKH;
#pragma unroll
            for (int c = 0; c < 6; ++c) {
                int idx = c * 256 + t;
                int row = idx / 24, c16 = idx - row * 24;
                int4 v = *(const int4*)(Ksrc + row * QKH + c16 * 8);
                *(int4*)(Ks + row * 200 + c16 * 8) = v;
            }
            const bf16* Vsrc = Vbase + kt * 64;
#pragma unroll
            for (int c = 0; c < 4; ++c) {
                int idx = c * 256 + t;
                int row = idx >> 3, c8 = idx & 7;
                int4 v = *(const int4*)(Vsrc + (size_t)row * N_TOK + c8 * 8);
                *(int4*)(Vs + row * 72 + c8 * 8) = v;
            }
        }
        __syncthreads();
        f32x4 acc_s[2][4] = {};
#pragma unroll
        for (int ks = 0; ks < 6; ++ks) {
            bf16x8 bv[4];
#pragma unroll
            for (int j = 0; j < 4; ++j)
                bv[j] = *(const bf16x8*)(Ks + (j * 16 + fr) * 200 + ks * 32 + fg * 8);
#pragma unroll
            for (int i = 0; i < 2; ++i)
#pragma unroll
                for (int j = 0; j < 4; ++j)
                    acc_s[i][j] = __builtin_amdgcn_mfma_f32_16x16x32_bf16(aq[i][ks], bv[j], acc_s[i][j], 0, 0, 0);
        }
        if (kt >= 2 * qp) {
            int colb = kt * 64;
            int rowb = qp * 128 + w * 32;
#pragma unroll
            for (int i = 0; i < 2; ++i)
#pragma unroll
                for (int j = 0; j < 4; ++j)
#pragma unroll
                    for (int q = 0; q < 4; ++q)
                        if (colb + j * 16 + fr > rowb + i * 16 + fg * 4 + q)
                            acc_s[i][j][q] = -1e30f;
        }
#pragma unroll
        for (int i = 0; i < 2; ++i) {
#pragma unroll
            for (int q = 0; q < 4; ++q) {
                float tmax = fmaxf(fmaxf(acc_s[i][0][q], acc_s[i][1][q]),
                                   fmaxf(acc_s[i][2][q], acc_s[i][3][q]));
                tmax = fmaxf(tmax, __shfl_xor(tmax, 1, 64));
                tmax = fmaxf(tmax, __shfl_xor(tmax, 2, 64));
                tmax = fmaxf(tmax, __shfl_xor(tmax, 4, 64));
                tmax = fmaxf(tmax, __shfl_xor(tmax, 8, 64));
                float mn = fmaxf(m_r[i][q], tmax);
                float sc = __expf(scale * (m_r[i][q] - mn));
                m_r[i][q] = mn;
                float s0 = 0.f;
#pragma unroll
                for (int j = 0; j < 4; ++j) {
                    float pv = __expf(scale * (acc_s[i][j][q] - mn));
                    acc_s[i][j][q] = pv;
                    s0 += pv;
                }
                s0 += __shfl_xor(s0, 1, 64);
                s0 += __shfl_xor(s0, 2, 64);
                s0 += __shfl_xor(s0, 4, 64);
                s0 += __shfl_xor(s0, 8, 64);
                l_r[i][q] = l_r[i][q] * sc + s0;
#pragma unroll
                for (int jo = 0; jo < 8; ++jo) acc_o[i][jo][q] *= sc;
            }
        }
#pragma unroll
        for (int i = 0; i < 2; ++i)
#pragma unroll
            for (int j = 0; j < 4; ++j)
#pragma unroll
                for (int q = 0; q < 4; ++q)
                    Ps[(w * 32 + i * 16 + fg * 4 + q) * 72 + j * 16 + fr] =
                        (short)f2bfu(acc_s[i][j][q]);
#pragma unroll
        for (int ks2 = 0; ks2 < 2; ++ks2) {
            bf16x8 pa[2];
#pragma unroll
            for (int i = 0; i < 2; ++i)
                pa[i] = *(const bf16x8*)(Ps + (w * 32 + i * 16 + fr) * 72 + ks2 * 32 + fg * 8);
#pragma unroll
            for (int jo = 0; jo < 8; ++jo) {
                bf16x8 vb = *(const bf16x8*)(Vs + (jo * 16 + fr) * 72 + ks2 * 32 + fg * 8);
#pragma unroll
                for (int i = 0; i < 2; ++i)
                    acc_o[i][jo] = __builtin_amdgcn_mfma_f32_16x16x32_bf16(pa[i], vb, acc_o[i][jo], 0, 0, 0);
            }
        }
    }
    bf16* obase = aout + (size_t)(qp * 128 + w * 32) * (NH * VH) + h * VH;
#pragma unroll
    for (int i = 0; i < 2; ++i)
#pragma unroll
        for (int q = 0; q < 4; ++q) {
            float inv = 1.f / l_r[i][q];
#pragma unroll
            for (int jo = 0; jo < 8; ++jo)
                obase[(size_t)(i * 16 + fg * 4 + q) * (NH * VH) + jo * 16 + fr] =
                    __float2bfloat16(acc_o[i][jo][q] * inv);
        }
}

// ---------------- silu(a)*b -> a, bf16 vectorized ----------------
__global__ void k_silu(bf16* __restrict__ a, const bf16* __restrict__ b, int n) {
    int i = (blockIdx.x * blockDim.x + threadIdx.x) * 8;
    int stride = gridDim.x * blockDim.x * 8;
    for (; i < n; i += stride) {
        uint4 ua = *(const uint4*)((const unsigned short*)a + i);
        uint4 ub = *(const uint4*)((const unsigned short*)b + i);
        unsigned* pa = &ua.x; const unsigned* pb = &ub.x;
#pragma unroll
        for (int w = 0; w < 4; ++w) {
            float x0 = bf2f((unsigned short)(pa[w] & 0xffffu));
            float x1 = bf2f((unsigned short)(pa[w] >> 16));
            float y0 = bf2f((unsigned short)(pb[w] & 0xffffu));
            float y1 = bf2f((unsigned short)(pb[w] >> 16));
            float r0 = x0 / (1.f + __expf(-x0)) * y0;
            float r1 = x1 / (1.f + __expf(-x1)) * y1;
            pa[w] = (unsigned)f2bfu(r0) | ((unsigned)f2bfu(r1) << 16);
        }
        *(uint4*)((unsigned short*)a + i) = ua;
    }
}

extern "C" void kernel_launch(void* const* d_in, const int* in_sizes, int n_in,
                              void* d_out, int out_size, void* d_ws, size_t ws_size,
                              hipStream_t stream) {
    (void)in_sizes; (void)n_in; (void)out_size;
    const int* tokens = (const int*)d_in[0];
    const float* emb = (const float*)d_in[1];
    const float* qW = (const float*)d_in[2];
    const float* kvaW = (const float*)d_in[3];
    const float* kvnorm_w = (const float*)d_in[4];
    const float* kvbW = (const float*)d_in[5];
    const float* oW = (const float*)d_in[6];
    const float* w1 = (const float*)d_in[7];
    const float* w2 = (const float*)d_in[8];
    const float* w3 = (const float*)d_in[9];
    const float* attn_norm_w = (const float*)d_in[10];
    const float* ffn_norm_w = (const float*)d_in[11];
    const float* norm_w = (const float*)d_in[12];
    const float* outW = (const float*)d_in[13];
    const float* rope_cos = (const float*)d_in[14];
    const float* rope_sin = (const float*)d_in[15];

    hipFuncSetAttribute((const void*)k_mm8<0>, hipFuncAttributeMaxDynamicSharedMemorySize, 131072);
    hipFuncSetAttribute((const void*)k_mm8<2>, hipFuncAttributeMaxDynamicSharedMemorySize, 131072);

    float* ws = (float*)d_ws;
    size_t off = 0;
    auto allocF = [&](size_t fl) { float* p = ws + off; off += (fl + 63) & ~63ULL; return p; };
    float* h    = allocF(4194304);            // [2048][2048] f32
    bf16* xb    = (bf16*)allocF(2097152);     // [2048][2048] bf16
    float* kvf  = allocF(1179648);            // [2048][576] f32
    bf16* cb    = (bf16*)allocF(524288);      // [2048][512] bf16
    bf16* qb    = (bf16*)allocF(3145728);     // [16][2048][192] bf16
    bf16* Kb    = (bf16*)allocF(3145728);     // [16][2048][192] bf16
    bf16* Vt    = (bf16*)allocF(2097152);     // [16][128][2048] bf16
    bf16* aout  = (bf16*)allocF(2097152);     // [2048][2048] bf16
    bf16* qWt   = (bf16*)allocF(3145728);     // [3072][2048]
    bf16* kvaWt = (bf16*)allocF(655360);      // [640][2048]
    bf16* kvbWt = (bf16*)allocF(1048576);     // [4096][512]
    bf16* oWt   = (bf16*)allocF(2097152);     // [2048][2048]
    bf16* w1t   = (bf16*)allocF(5767168);     // [5632][2048]
    bf16* w2t   = (bf16*)allocF(5767168);
    bf16* w3t   = (bf16*)allocF(5767168);     // [2048][5632]
    float* scr  = ws + off;
    size_t availF = (ws_size / 4 > off) ? ws_size / 4 - off : 0;

    int oc = 25;
    {
        const int ocs[3] = {1, 5, 25};
        for (int i = 0; i < 3; ++i) {
            size_t need = 11534336;                        // ffn f1+f2
            size_t a2 = (size_t)32768000 / ocs[i];         // outW chunk (bf16, in floats)
            if (a2 > need) need = a2;
            if (8388608 > need) need = 8388608;            // kvbf f32
            if (need <= availF) { oc = ocs[i]; break; }
        }
    }
    float* qf   = scr;                          // [2048][3072] f32 (transient)
    float* kvbf = scr;                          // [2048][4096] f32 (transient)
    bf16* f1    = (bf16*)scr;                   // [2048][5632] bf16
    bf16* f2    = f1 + 11534336;
    bf16* oWtc  = (bf16*)scr;                   // outW chunk [cn][2048]

    auto convT = [&](const float* W, bf16* Out, int K, int ldw, int ncols, int npad,
                     int c0) {
        dim3 g(npad / 64, K / 32, 1);
        k_convT<<<g, 256, 0, stream>>>(W, Out, K, ldw, ncols, c0, 0, 0, 0);
    };

    k_embed<<<N_TOK, 256, 0, stream>>>(tokens, emb, h);

    for (int l = 0; l < NLAYER; ++l) {
        convT(qW + (size_t)l * DIM * 3072, qWt, 2048, 3072, 3072, 3072, 0);
        convT(kvaW + (size_t)l * DIM * 576, kvaWt, 2048, 576, 576, 640, 0);
        convT(kvbW + (size_t)l * 512 * 4096, kvbWt, 512, 4096, 4096, 4096, 0);
        convT(oW + (size_t)l * 2048 * 2048, oWt, 2048, 2048, 2048, 2048, 0);
        convT(w1 + (size_t)l * DIM * INTER, w1t, 2048, 5632, 5632, 5632, 0);
        convT(w2 + (size_t)l * DIM * INTER, w2t, 2048, 5632, 5632, 5632, 0);
        convT(w3 + (size_t)l * INTER * DIM, w3t, 5632, 2048, 2048, 2048, 0);

        k_rmsnorm<<<N_TOK, 256, 0, stream>>>(h, 2048, 0, xb, attn_norm_w + (size_t)l * DIM, 2048);
        k_mm<0><<<dim3(16, 24), 256, 0, stream>>>(xb, qWt, qf, 3072, 2048, 2048, 2048, 3072);
        k_mm<0><<<dim3(16, 5), 256, 0, stream>>>(xb, kvaWt, kvf, 576, 2048, 2048, 2048, 576);
        k_qpack<<<N_TOK, 256, 0, stream>>>(qf, rope_cos, rope_sin, qb);
        k_rmsnorm<<<N_TOK, 256, 0, stream>>>(kvf, 576, 64, cb, kvnorm_w + (size_t)l * KVR, 512);
        k_mm<0><<<dim3(16, 32), 256, 0, stream>>>(cb, kvbWt, kvbf, 4096, 512, 512, 512, 4096);
        k_packK<<<N_TOK, 256, 0, stream>>>(kvbf, kvf, rope_cos, rope_sin, Kb);
        {   // V^T per head: [128][2048] bf16 (cols h*256+128 of kvbf)
            dim3 g(2, 64, 16);
            k_convT<<<g, 256, 0, stream>>>(kvbf, Vt, 2048, 4096, 128, 128, 256, 0,
                                           (long long)128 * 2048);
        }
        k_flash<<<dim3(NH, 16), 256, 0, stream>>>(qb, Kb, Vt, aout);
        k_mm<1><<<dim3(16, 16), 256, 0, stream>>>(aout, oWt, h, 2048, 2048, 2048, 2048, 2048);

        k_rmsnorm<<<N_TOK, 256, 0, stream>>>(h, 2048, 0, xb, ffn_norm_w + (size_t)l * DIM, 2048);
        k_mm8<2><<<dim3(8, 22), 512, 131072, stream>>>(xb, w1t, f1, 2048, 2048, 2048, 5632);
        k_mm8<2><<<dim3(8, 22), 512, 131072, stream>>>(xb, w2t, f2, 2048, 2048, 2048, 5632);
        k_silu<<<2048, 256, 0, stream>>>(f1, f2, N_TOK * INTER);
        k_mm<1><<<dim3(16, 16), 256, 0, stream>>>(f1, w3t, h, 2048, 5632, 5632, 5632, 2048);
    }
    k_rmsnorm<<<N_TOK, 256, 0, stream>>>(h, 2048, 0, xb, norm_w, 2048);
    int cn = 32000 / oc;
    for (int c2 = 0; c2 < oc; ++c2) {
        convT(outW, oWtc, 2048, 32000, cn, cn, c2 * cn);
        k_mm8<0><<<dim3(8, cn / 256), 512, 131072, stream>>>(
            xb, oWtc, (float*)d_out + (size_t)c2 * cn, 2048, 2048, 2048, 32000);
    }
}

// Round 7
// 1684.364 us; speedup vs baseline: 10.0916x; 1.0273x over previous
//
#include <hip/hip_runtime.h>
#include <hip/hip_bf16.h>
#include <math.h>

#define N_TOK 2048
#define DIM   2048
#define NH    16
#define NOPE  128
#define ROPE_D 64
#define QKH   192
#define VH    128
#define KVR   512
#define INTER 5632
#define VOCAB 32000
#define NLAYER 2
#define EPS   1e-6f

typedef __hip_bfloat16 bf16;
typedef __bf16 bf16x8 __attribute__((ext_vector_type(8)));
typedef float  f32x4  __attribute__((ext_vector_type(4)));

__device__ __forceinline__ float bf2f(unsigned short u) {
    union { unsigned u; float f; } a; a.u = ((unsigned)u) << 16; return a.f;
}
__device__ __forceinline__ unsigned short f2bfu(float f) {
    union { float f; unsigned u; } a; a.f = f;
    return (unsigned short)((a.u + 0x7fffu + ((a.u >> 16) & 1u)) >> 16);
}

__device__ __forceinline__ void gload16(const void* g, void* l) {
    __builtin_amdgcn_global_load_lds((const __attribute__((address_space(1))) void*)g,
                                     (__attribute__((address_space(3))) void*)l, 16, 0, 0);
}

// ---------------- embedding gather ----------------
__global__ void k_embed(const int* __restrict__ tokens, const float* __restrict__ emb,
                        float* __restrict__ h) {
    int n = blockIdx.x;
    int t = tokens[n];
    const float4* src = (const float4*)(emb + (size_t)t * DIM);
    float4* dst = (float4*)(h + (size_t)n * DIM);
    for (int i = threadIdx.x; i < DIM / 4; i += blockDim.x) dst[i] = src[i];
}

// ---------------- rmsnorm f32 -> bf16 ----------------
__global__ __launch_bounds__(256) void k_rmsnorm(const float* __restrict__ in, int in_stride, int in_off,
                                                 bf16* __restrict__ out, const float* __restrict__ w,
                                                 int len) {
    int row = blockIdx.x;
    const float* x = in + (size_t)row * in_stride + in_off;
    float ss = 0.f;
    for (int i = threadIdx.x; i < len; i += 256) { float v = x[i]; ss += v * v; }
    for (int off = 32; off > 0; off >>= 1) ss += __shfl_down(ss, off, 64);
    __shared__ float red[4];
    if ((threadIdx.x & 63) == 0) red[threadIdx.x >> 6] = ss;
    __syncthreads();
    float tot = red[0] + red[1] + red[2] + red[3];
    float inv = rsqrtf(tot / (float)len + EPS);
    for (int i = threadIdx.x; i < len; i += 256)
        out[(size_t)row * len + i] = __float2bfloat16(x[i] * inv * w[i]);
}

// ---------------- transpose + convert: W[K][ncols] f32 -> Out[npad][K] bf16 ----------------
__global__ __launch_bounds__(256)
void k_convT(const float* __restrict__ W, bf16* __restrict__ Out,
             int K, int ldw, int ncols, int c0base, int c0step,
             long long inz, long long outz) {
    __shared__ float T[32][65];
    const float* Wz = W + (long long)blockIdx.z * inz;
    bf16* Oz = Out + (long long)blockIdx.z * outz;
    int c0 = c0base + blockIdx.z * c0step;
    int n0 = blockIdx.x * 64, k0 = blockIdx.y * 32;
    int tid = threadIdx.x;
    int rr = tid >> 4, cc = (tid & 15) * 4;
#pragma unroll
    for (int p = 0; p < 2; ++p) {
        int k = k0 + rr + p * 16;
        float4 v = make_float4(0.f, 0.f, 0.f, 0.f);
        if (n0 + cc < ncols) v = *(const float4*)(Wz + (size_t)k * ldw + c0 + n0 + cc);
        T[rr + p * 16][cc + 0] = v.x; T[rr + p * 16][cc + 1] = v.y;
        T[rr + p * 16][cc + 2] = v.z; T[rr + p * 16][cc + 3] = v.w;
    }
    __syncthreads();
    int n = tid >> 2, kc = (tid & 3) * 8;
    __align__(16) bf16 tmp[8];
#pragma unroll
    for (int e = 0; e < 8; ++e) tmp[e] = __float2bfloat16(T[kc + e][n]);
    *(int4*)(Oz + (size_t)(n0 + n) * K + k0 + kc) = *(const int4*)tmp;
}

// ---------------- bf16 MFMA GEMM, 128x128 tile, BK=32 (2-phase) ----------------
// 1-D grid (M/128=16 row panels), XCD-chunked swizzle: col-panel-major logical order.
template<int OUT>
__global__ __launch_bounds__(256)
void k_mm(const bf16* __restrict__ A, const bf16* __restrict__ Bt, void* __restrict__ Cv,
          int Nreal, int K, int lda, int ldb, int ldc) {
    int cpx = gridDim.x >> 3;
    int logical = ((int)blockIdx.x & 7) * cpx + ((int)blockIdx.x >> 3);
    int row0 = (logical & 15) * 128, col0 = (logical >> 4) * 128;
    __shared__ bf16 As[128 * 32];
    __shared__ bf16 Bs[128 * 32];
    int tid = threadIdx.x;
    int lane = tid & 63, wave = tid >> 6;
    int wm = (wave & 1) * 64, wn = (wave >> 1) * 64;
    int fr = lane & 15, fg = lane >> 4;
    f32x4 acc[4][4] = {};
    for (int k0 = 0; k0 < K; k0 += 32) {
#pragma unroll
        for (int it = 0; it < 2; ++it) {
            int idx = it * 256 + tid;
            int m = idx >> 2, c = idx & 3;
            gload16(A + (size_t)(row0 + m) * lda + k0 + c * 8, As + idx * 8);
        }
#pragma unroll
        for (int it = 0; it < 2; ++it) {
            int idx = it * 256 + tid;
            int m = idx >> 2, c = idx & 3;
            gload16(Bt + (size_t)(col0 + m) * ldb + k0 + c * 8, Bs + idx * 8);
        }
        __syncthreads();
        bf16x8 av[4], bv[4];
#pragma unroll
        for (int i = 0; i < 4; ++i) {
            av[i] = *(const bf16x8*)(As + (wm + i * 16 + fr) * 32 + fg * 8);
            bv[i] = *(const bf16x8*)(Bs + (wn + i * 16 + fr) * 32 + fg * 8);
        }
#pragma unroll
        for (int i = 0; i < 4; ++i)
#pragma unroll
            for (int j = 0; j < 4; ++j)
                acc[i][j] = __builtin_amdgcn_mfma_f32_16x16x32_bf16(av[i], bv[j], acc[i][j], 0, 0, 0);
        __syncthreads();
    }
    float* Cf = (float*)Cv;
    bf16* Cb = (bf16*)Cv;
#pragma unroll
    for (int i = 0; i < 4; ++i)
#pragma unroll
        for (int j = 0; j < 4; ++j)
#pragma unroll
            for (int q = 0; q < 4; ++q) {
                int row = row0 + wm + i * 16 + fg * 4 + q;
                int col = col0 + wn + j * 16 + fr;
                if (col < Nreal) {
                    size_t off = (size_t)row * ldc + col;
                    if (OUT == 0) Cf[off] = acc[i][j][q];
                    else if (OUT == 1) Cf[off] += acc[i][j][q];
                    else Cb[off] = __float2bfloat16(acc[i][j][q]);
                }
            }
}

// ---------------- bf16 MFMA GEMM, 256x256 tile, BK=32, ring-4 LDS, 8-phase/group ----------------
// 1-D grid (8 row panels x NP col panels), XCD-chunked swizzle (col-panel-major logical).
// T2 XOR-swizzle staging/read; counted vmcnt(8); setprio; raw barriers. 128 KiB dynamic LDS.
#define TILE8(u, DOSTAGE, GATE) { \
    const int t = t0 + (u); \
    const bf16* sAb = sA_ + (u) * 8192; \
    const bf16* sBb = sB_ + (u) * 8192; \
    bf16* dA = sA_ + (((u) + 3) & 3) * 8192; \
    bf16* dB = sB_ + (((u) + 3) & 3) * 8192; \
    if (DOSTAGE) { \
        size_t kk = (size_t)(t + 3) * 32; \
        gload16(Ag + (size_t)(row0 + srow) * lda + kk + scol * 8, dA + tid * 8); \
        gload16(Ag + (size_t)(row0 + 128 + srow) * lda + kk + scol * 8, dA + 4096 + tid * 8); \
    } \
    bf16x8 av[8], bv0, bv1; \
    _Pragma("unroll") \
    for (int m = 0; m < 8; ++m) \
        av[m] = *(const bf16x8*)(sAb + (wm * 128 + m * 16 + fr) * 32 + swz); \
    bv0 = *(const bf16x8*)(sBb + (wn * 64 + fr) * 32 + swz); \
    bv1 = *(const bf16x8*)(sBb + (wn * 64 + 16 + fr) * 32 + swz); \
    __builtin_amdgcn_s_barrier(); \
    __builtin_amdgcn_s_setprio(1); \
    _Pragma("unroll") \
    for (int m = 0; m < 8; ++m) { \
        acc[m][0] = __builtin_amdgcn_mfma_f32_16x16x32_bf16(av[m], bv0, acc[m][0], 0, 0, 0); \
        acc[m][1] = __builtin_amdgcn_mfma_f32_16x16x32_bf16(av[m], bv1, acc[m][1], 0, 0, 0); \
    } \
    __builtin_amdgcn_s_setprio(0); \
    __builtin_amdgcn_s_barrier(); \
    if (DOSTAGE) { \
        size_t kk = (size_t)(t + 3) * 32; \
        gload16(Bg + (size_t)(col0 + srow) * ldb + kk + scol * 8, dB + tid * 8); \
        gload16(Bg + (size_t)(col0 + 128 + srow) * ldb + kk + scol * 8, dB + 4096 + tid * 8); \
    } \
    bf16x8 bv2 = *(const bf16x8*)(sBb + (wn * 64 + 32 + fr) * 32 + swz); \
    bf16x8 bv3 = *(const bf16x8*)(sBb + (wn * 64 + 48 + fr) * 32 + swz); \
    __builtin_amdgcn_s_barrier(); \
    __builtin_amdgcn_s_setprio(1); \
    _Pragma("unroll") \
    for (int m = 0; m < 8; ++m) { \
        acc[m][2] = __builtin_amdgcn_mfma_f32_16x16x32_bf16(av[m], bv2, acc[m][2], 0, 0, 0); \
        acc[m][3] = __builtin_amdgcn_mfma_f32_16x16x32_bf16(av[m], bv3, acc[m][3], 0, 0, 0); \
    } \
    __builtin_amdgcn_s_setprio(0); \
    GATE; \
    __builtin_amdgcn_s_barrier(); \
    __builtin_amdgcn_sched_barrier(0); \
}

template<int OUT>
__global__ __launch_bounds__(512, 2)
void k_mm8(const bf16* __restrict__ Ag, const bf16* __restrict__ Bg, void* __restrict__ Cv,
           int K, int lda, int ldb, int ldc) {
    extern __shared__ char smem_raw[];
    bf16* sA_ = (bf16*)smem_raw;            // 4 bufs x 256x32
    bf16* sB_ = sA_ + 4 * 8192;             // 4 bufs x 256x32
    int tid = threadIdx.x;
    int lane = tid & 63, wid = tid >> 6;
    int wm = wid >> 2, wn = wid & 3;        // 2 x 4 waves, wave tile 128x64
    int fr = lane & 15, fg = lane >> 4;
    int cpx = gridDim.x >> 3;
    int logical = ((int)blockIdx.x & 7) * cpx + ((int)blockIdx.x >> 3);
    int row0 = (logical & 7) * 256, col0 = (logical >> 3) * 256;
    // T2 swizzle constants
    int srow = tid >> 2;
    int scol = (tid & 3) ^ ((srow >> 1) & 3);            // staging source slot
    int swz = (fg ^ ((fr >> 1) & 3)) * 8;                // read slot (elem offset)

    f32x4 acc[8][4] = {};
    int nt = K >> 5;

    // prologue: stage tiles 0,1,2
#pragma unroll
    for (int t = 0; t < 3; ++t) {
        size_t kk = (size_t)t * 32;
        bf16* dA = sA_ + t * 8192;
        bf16* dB = sB_ + t * 8192;
        gload16(Ag + (size_t)(row0 + srow) * lda + kk + scol * 8, dA + tid * 8);
        gload16(Ag + (size_t)(row0 + 128 + srow) * lda + kk + scol * 8, dA + 4096 + tid * 8);
        gload16(Bg + (size_t)(col0 + srow) * ldb + kk + scol * 8, dB + tid * 8);
        gload16(Bg + (size_t)(col0 + 128 + srow) * ldb + kk + scol * 8, dB + 4096 + tid * 8);
    }
    asm volatile("s_waitcnt vmcnt(8)" ::: "memory");
    __builtin_amdgcn_s_barrier();
    __builtin_amdgcn_sched_barrier(0);

    int ngroups = nt >> 2;
    for (int g = 0; g < ngroups - 1; ++g) {
        int t0 = g * 4;
        TILE8(0, 1, asm volatile("s_waitcnt vmcnt(8)" ::: "memory"));
        TILE8(1, 1, asm volatile("s_waitcnt vmcnt(8)" ::: "memory"));
        TILE8(2, 1, asm volatile("s_waitcnt vmcnt(8)" ::: "memory"));
        TILE8(3, 1, asm volatile("s_waitcnt vmcnt(8)" ::: "memory"));
    }
    {
        int t0 = nt - 4;
        TILE8(0, 1, asm volatile("s_waitcnt vmcnt(8)" ::: "memory"));
        TILE8(1, 0, asm volatile("s_waitcnt vmcnt(4)" ::: "memory"));
        TILE8(2, 0, asm volatile("s_waitcnt vmcnt(0)" ::: "memory"));
        TILE8(3, 0, (void)0);
    }

    float* Cf = (float*)Cv;
    bf16* Cb = (bf16*)Cv;
#pragma unroll
    for (int m = 0; m < 8; ++m)
#pragma unroll
        for (int n = 0; n < 4; ++n)
#pragma unroll
            for (int q = 0; q < 4; ++q) {
                int row = row0 + wm * 128 + m * 16 + fg * 4 + q;
                int col = col0 + wn * 64 + n * 16 + fr;
                size_t off = (size_t)row * ldc + col;
                if (OUT == 0) Cf[off] = acc[m][n][q];
                else if (OUT == 1) Cf[off] += acc[m][n][q];
                else Cb[off] = __float2bfloat16(acc[m][n][q]);
            }
}

// ---------------- q rope + pack to [h][n][192] bf16 ----------------
__global__ __launch_bounds__(256) void k_qpack(const float* __restrict__ q,
        const float* __restrict__ cosb, const float* __restrict__ sinb,
        bf16* __restrict__ qb) {
    int n = blockIdx.x;
    __shared__ float c[32], s[32];
    if (threadIdx.x < 32) {
        c[threadIdx.x] = cosb[n * 32 + threadIdx.x];
        s[threadIdx.x] = sinb[n * 32 + threadIdx.x];
    }
    __syncthreads();
    const float* row = q + (size_t)n * (NH * QKH);
    for (int idx = threadIdx.x; idx < NH * QKH; idx += 256) {
        int h = idx / QKH, d = idx - h * QKH;
        float v;
        if (d < NOPE) v = row[idx];
        else {
            int i = (d - NOPE) >> 1;
            float xr = row[h * QKH + NOPE + 2 * i], xi = row[h * QKH + NOPE + 2 * i + 1];
            v = ((d & 1) == 0) ? xr * c[i] - xi * s[i] : xr * s[i] + xi * c[i];
        }
        qb[(size_t)h * (N_TOK * QKH) + (size_t)n * QKH + d] = __float2bfloat16(v);
    }
}

// ---------------- K pack: [h][key][192] bf16 ----------------
__global__ __launch_bounds__(256) void k_packK(const float* __restrict__ kvb,
        const float* __restrict__ kvf, const float* __restrict__ cosb, const float* __restrict__ sinb,
        bf16* __restrict__ Kb) {
    int key = blockIdx.x;
    __shared__ float rp[ROPE_D];
    if (threadIdx.x < 32) {
        float c = cosb[key * 32 + threadIdx.x], s = sinb[key * 32 + threadIdx.x];
        float xr = kvf[(size_t)key * (ROPE_D + KVR) + 2 * threadIdx.x];
        float xi = kvf[(size_t)key * (ROPE_D + KVR) + 2 * threadIdx.x + 1];
        rp[2 * threadIdx.x] = xr * c - xi * s;
        rp[2 * threadIdx.x + 1] = xr * s + xi * c;
    }
    __syncthreads();
    const float* row = kvb + (size_t)key * (NH * (NOPE + VH));
    for (int idx = threadIdx.x; idx < NH * QKH; idx += 256) {
        int h = idx / QKH, d = idx - h * QKH;
        float v = (d < NOPE) ? row[h * (NOPE + VH) + d] : rp[d - NOPE];
        Kb[(size_t)h * (N_TOK * QKH) + (size_t)key * QKH + d] = __float2bfloat16(v);
    }
}

// ---------------- fused flash attention, load-balanced ----------------
// grid (NH, 16): block handles q-panels yp and 31-yp (QBLK=64) -> exactly 34 K-tiles each.
// 4 waves x 16 q-rows. K/V staged per 64-key tile; P through wave-private LDS band.
__global__ __launch_bounds__(256, 2)
void k_flash(const bf16* __restrict__ qb, const bf16* __restrict__ Kb,
             const bf16* __restrict__ Vt, bf16* __restrict__ aout) {
    int h = blockIdx.x, yp = blockIdx.y;
    __shared__ short Ks[64 * 200];   // [key][192] pad->200
    __shared__ short Vs[128 * 72];   // [vdim][key64] pad->72
    __shared__ short Ps[64 * 72];    // [qrow][key64] pad->72
    int t = threadIdx.x;
    int lane = t & 63, w = t >> 6;
    int fr = lane & 15, fg = lane >> 4;
    const float scale = 0.07216878364870322f;  // 1/sqrt(192)
    const bf16* Kbase = Kb + (size_t)h * N_TOK * QKH;
    const bf16* Vbase = Vt + (size_t)h * VH * N_TOK;

    for (int pi = 0; pi < 2; ++pi) {
        int qp = pi ? 31 - yp : yp;
        // Q fragments in registers (A-operand: row=fr, k=ks*32+fg*8)
        bf16x8 aq[6];
        const bf16* Qsrc = qb + ((size_t)h * N_TOK + qp * 64 + w * 16) * QKH;
#pragma unroll
        for (int ks = 0; ks < 6; ++ks)
            aq[ks] = *(const bf16x8*)(Qsrc + (size_t)fr * QKH + ks * 32 + fg * 8);

        f32x4 acc_o[8] = {};
        float m_r[4], l_r[4];
#pragma unroll
        for (int q = 0; q < 4; ++q) { m_r[q] = -1e30f; l_r[q] = 0.f; }

        int nkt = qp + 1;
        for (int kt = 0; kt < nkt; ++kt) {
            __syncthreads();
            {
                const bf16* Ksrc = Kbase + (size_t)kt * 64 * QKH;
#pragma unroll
                for (int c = 0; c < 6; ++c) {
                    int idx = c * 256 + t;
                    int row = idx / 24, c16 = idx - row * 24;
                    int4 v = *(const int4*)(Ksrc + row * QKH + c16 * 8);
                    *(int4*)(Ks + row * 200 + c16 * 8) = v;
                }
                const bf16* Vsrc = Vbase + kt * 64;
#pragma unroll
                for (int c = 0; c < 4; ++c) {
                    int idx = c * 256 + t;
                    int row = idx >> 3, c8 = idx & 7;
                    int4 v = *(const int4*)(Vsrc + (size_t)row * N_TOK + c8 * 8);
                    *(int4*)(Vs + row * 72 + c8 * 8) = v;
                }
            }
            __syncthreads();
            // S = Q @ K^T
            f32x4 acc_s[4] = {};
#pragma unroll
            for (int ks = 0; ks < 6; ++ks) {
                bf16x8 bv[4];
#pragma unroll
                for (int j = 0; j < 4; ++j)
                    bv[j] = *(const bf16x8*)(Ks + (j * 16 + fr) * 200 + ks * 32 + fg * 8);
#pragma unroll
                for (int j = 0; j < 4; ++j)
                    acc_s[j] = __builtin_amdgcn_mfma_f32_16x16x32_bf16(aq[ks], bv[j], acc_s[j], 0, 0, 0);
            }
            if (kt == qp) {  // diagonal tile: causal mask
                int colb = kt * 64;
                int rowb = qp * 64 + w * 16;
#pragma unroll
                for (int j = 0; j < 4; ++j)
#pragma unroll
                    for (int q = 0; q < 4; ++q)
                        if (colb + j * 16 + fr > rowb + fg * 4 + q)
                            acc_s[j][q] = -1e30f;
            }
            // online softmax (row = w*16 + fg*4 + q, reduce across fr via 16-lane group)
#pragma unroll
            for (int q = 0; q < 4; ++q) {
                float tmax = fmaxf(fmaxf(acc_s[0][q], acc_s[1][q]),
                                   fmaxf(acc_s[2][q], acc_s[3][q]));
                tmax = fmaxf(tmax, __shfl_xor(tmax, 1, 64));
                tmax = fmaxf(tmax, __shfl_xor(tmax, 2, 64));
                tmax = fmaxf(tmax, __shfl_xor(tmax, 4, 64));
                tmax = fmaxf(tmax, __shfl_xor(tmax, 8, 64));
                float mn = fmaxf(m_r[q], tmax);
                float sc = __expf(scale * (m_r[q] - mn));
                m_r[q] = mn;
                float s0 = 0.f;
#pragma unroll
                for (int j = 0; j < 4; ++j) {
                    float pv = __expf(scale * (acc_s[j][q] - mn));
                    acc_s[j][q] = pv;
                    s0 += pv;
                }
                s0 += __shfl_xor(s0, 1, 64);
                s0 += __shfl_xor(s0, 2, 64);
                s0 += __shfl_xor(s0, 4, 64);
                s0 += __shfl_xor(s0, 8, 64);
                l_r[q] = l_r[q] * sc + s0;
#pragma unroll
                for (int jo = 0; jo < 8; ++jo) acc_o[jo][q] *= sc;
            }
            // P -> LDS band (16 rows/wave), re-layout to A-operand
#pragma unroll
            for (int j = 0; j < 4; ++j)
#pragma unroll
                for (int q = 0; q < 4; ++q)
                    Ps[(w * 16 + fg * 4 + q) * 72 + j * 16 + fr] = (short)f2bfu(acc_s[j][q]);
            // O += P @ V
#pragma unroll
            for (int ks2 = 0; ks2 < 2; ++ks2) {
                bf16x8 pa = *(const bf16x8*)(Ps + (w * 16 + fr) * 72 + ks2 * 32 + fg * 8);
#pragma unroll
                for (int jo = 0; jo < 8; ++jo) {
                    bf16x8 vb = *(const bf16x8*)(Vs + (jo * 16 + fr) * 72 + ks2 * 32 + fg * 8);
                    acc_o[jo] = __builtin_amdgcn_mfma_f32_16x16x32_bf16(pa, vb, acc_o[jo], 0, 0, 0);
                }
            }
        }
        bf16* obase = aout + (size_t)(qp * 64 + w * 16) * (NH * VH) + h * VH;
#pragma unroll
        for (int q = 0; q < 4; ++q) {
            float inv = 1.f / l_r[q];
#pragma unroll
            for (int jo = 0; jo < 8; ++jo)
                obase[(size_t)(fg * 4 + q) * (NH * VH) + jo * 16 + fr] =
                    __float2bfloat16(acc_o[jo][q] * inv);
        }
    }
}

// ---------------- silu(a)*b -> a, bf16 vectorized ----------------
__global__ void k_silu(bf16* __restrict__ a, const bf16* __restrict__ b, int n) {
    int i = (blockIdx.x * blockDim.x + threadIdx.x) * 8;
    int stride = gridDim.x * blockDim.x * 8;
    for (; i < n; i += stride) {
        uint4 ua = *(const uint4*)((const unsigned short*)a + i);
        uint4 ub = *(const uint4*)((const unsigned short*)b + i);
        unsigned* pa = &ua.x; const unsigned* pb = &ub.x;
#pragma unroll
        for (int w = 0; w < 4; ++w) {
            float x0 = bf2f((unsigned short)(pa[w] & 0xffffu));
            float x1 = bf2f((unsigned short)(pa[w] >> 16));
            float y0 = bf2f((unsigned short)(pb[w] & 0xffffu));
            float y1 = bf2f((unsigned short)(pb[w] >> 16));
            float r0 = x0 / (1.f + __expf(-x0)) * y0;
            float r1 = x1 / (1.f + __expf(-x1)) * y1;
            pa[w] = (unsigned)f2bfu(r0) | ((unsigned)f2bfu(r1) << 16);
        }
        *(uint4*)((unsigned short*)a + i) = ua;
    }
}

extern "C" void kernel_launch(void* const* d_in, const int* in_sizes, int n_in,
                              void* d_out, int out_size, void* d_ws, size_t ws_size,
                              hipStream_t stream) {
    (void)in_sizes; (void)n_in; (void)out_size;
    const int* tokens = (const int*)d_in[0];
    const float* emb = (const float*)d_in[1];
    const float* qW = (const float*)d_in[2];
    const float* kvaW = (const float*)d_in[3];
    const float* kvnorm_w = (const float*)d_in[4];
    const float* kvbW = (const float*)d_in[5];
    const float* oW = (const float*)d_in[6];
    const float* w1 = (const float*)d_in[7];
    const float* w2 = (const float*)d_in[8];
    const float* w3 = (const float*)d_in[9];
    const float* attn_norm_w = (const float*)d_in[10];
    const float* ffn_norm_w = (const float*)d_in[11];
    const float* norm_w = (const float*)d_in[12];
    const float* outW = (const float*)d_in[13];
    const float* rope_cos = (const float*)d_in[14];
    const float* rope_sin = (const float*)d_in[15];

    hipFuncSetAttribute((const void*)k_mm8<0>, hipFuncAttributeMaxDynamicSharedMemorySize, 131072);
    hipFuncSetAttribute((const void*)k_mm8<2>, hipFuncAttributeMaxDynamicSharedMemorySize, 131072);

    float* ws = (float*)d_ws;
    size_t off = 0;
    auto allocF = [&](size_t fl) { float* p = ws + off; off += (fl + 63) & ~63ULL; return p; };
    float* h    = allocF(4194304);            // [2048][2048] f32
    bf16* xb    = (bf16*)allocF(2097152);     // [2048][2048] bf16
    float* kvf  = allocF(1179648);            // [2048][576] f32
    bf16* cb    = (bf16*)allocF(524288);      // [2048][512] bf16
    bf16* qb    = (bf16*)allocF(3145728);     // [16][2048][192] bf16
    bf16* Kb    = (bf16*)allocF(3145728);     // [16][2048][192] bf16
    bf16* Vt    = (bf16*)allocF(2097152);     // [16][128][2048] bf16
    bf16* aout  = (bf16*)allocF(2097152);     // [2048][2048] bf16
    bf16* qWt   = (bf16*)allocF(3145728);     // [3072][2048]
    bf16* kvaWt = (bf16*)allocF(655360);      // [640][2048]
    bf16* kvbWt = (bf16*)allocF(1048576);     // [4096][512]
    bf16* oWt   = (bf16*)allocF(2097152);     // [2048][2048]
    bf16* w1t   = (bf16*)allocF(5767168);     // [5632][2048]
    bf16* w2t   = (bf16*)allocF(5767168);
    bf16* w3t   = (bf16*)allocF(5767168);     // [2048][5632]
    float* scr  = ws + off;
    size_t availF = (ws_size / 4 > off) ? ws_size / 4 - off : 0;

    int oc = 25;
    {
        const int ocs[3] = {1, 5, 25};
        for (int i = 0; i < 3; ++i) {
            size_t need = 11534336;                        // ffn f1+f2
            size_t a2 = (size_t)32768000 / ocs[i];         // outW chunk (bf16, in floats)
            if (a2 > need) need = a2;
            if (8388608 > need) need = 8388608;            // kvbf f32
            if (need <= availF) { oc = ocs[i]; break; }
        }
    }
    float* qf   = scr;                          // [2048][3072] f32 (transient)
    float* kvbf = scr;                          // [2048][4096] f32 (transient)
    bf16* f1    = (bf16*)scr;                   // [2048][5632] bf16
    bf16* f2    = f1 + 11534336;
    bf16* oWtc  = (bf16*)scr;                   // outW chunk [cn][2048]

    auto convT = [&](const float* W, bf16* Out, int K, int ldw, int ncols, int npad,
                     int c0) {
        dim3 g(npad / 64, K / 32, 1);
        k_convT<<<g, 256, 0, stream>>>(W, Out, K, ldw, ncols, c0, 0, 0, 0);
    };

    k_embed<<<N_TOK, 256, 0, stream>>>(tokens, emb, h);

    for (int l = 0; l < NLAYER; ++l) {
        convT(qW + (size_t)l * DIM * 3072, qWt, 2048, 3072, 3072, 3072, 0);
        convT(kvaW + (size_t)l * DIM * 576, kvaWt, 2048, 576, 576, 640, 0);
        convT(kvbW + (size_t)l * 512 * 4096, kvbWt, 512, 4096, 4096, 4096, 0);
        convT(oW + (size_t)l * 2048 * 2048, oWt, 2048, 2048, 2048, 2048, 0);
        convT(w1 + (size_t)l * DIM * INTER, w1t, 2048, 5632, 5632, 5632, 0);
        convT(w2 + (size_t)l * DIM * INTER, w2t, 2048, 5632, 5632, 5632, 0);
        convT(w3 + (size_t)l * INTER * DIM, w3t, 5632, 2048, 2048, 2048, 0);

        k_rmsnorm<<<N_TOK, 256, 0, stream>>>(h, 2048, 0, xb, attn_norm_w + (size_t)l * DIM, 2048);
        k_mm<0><<<dim3(384), 256, 0, stream>>>(xb, qWt, qf, 3072, 2048, 2048, 2048, 3072);
        k_mm<0><<<dim3(80), 256, 0, stream>>>(xb, kvaWt, kvf, 576, 2048, 2048, 2048, 576);
        k_qpack<<<N_TOK, 256, 0, stream>>>(qf, rope_cos, rope_sin, qb);
        k_rmsnorm<<<N_TOK, 256, 0, stream>>>(kvf, 576, 64, cb, kvnorm_w + (size_t)l * KVR, 512);
        k_mm<0><<<dim3(512), 256, 0, stream>>>(cb, kvbWt, kvbf, 4096, 512, 512, 512, 4096);
        k_packK<<<N_TOK, 256, 0, stream>>>(kvbf, kvf, rope_cos, rope_sin, Kb);
        {   // V^T per head: [128][2048] bf16 (cols h*256+128 of kvbf)
            dim3 g(2, 64, 16);
            k_convT<<<g, 256, 0, stream>>>(kvbf, Vt, 2048, 4096, 128, 128, 256, 0,
                                           (long long)128 * 2048);
        }
        k_flash<<<dim3(NH, 16), 256, 0, stream>>>(qb, Kb, Vt, aout);
        k_mm<1><<<dim3(256), 256, 0, stream>>>(aout, oWt, h, 2048, 2048, 2048, 2048, 2048);

        k_rmsnorm<<<N_TOK, 256, 0, stream>>>(h, 2048, 0, xb, ffn_norm_w + (size_t)l * DIM, 2048);
        k_mm8<2><<<dim3(176), 512, 131072, stream>>>(xb, w1t, f1, 2048, 2048, 2048, 5632);
        k_mm8<2><<<dim3(176), 512, 131072, stream>>>(xb, w2t, f2, 2048, 2048, 2048, 5632);
        k_silu<<<2048, 256, 0, stream>>>(f1, f2, N_TOK * INTER);
        k_mm<1><<<dim3(256), 256, 0, stream>>>(f1, w3t, h, 2048, 5632, 5632, 5632, 2048);
    }
    k_rmsnorm<<<N_TOK, 256, 0, stream>>>(h, 2048, 0, xb, norm_w, 2048);
    int cn = 32000 / oc;
    for (int c2 = 0; c2 < oc; ++c2) {
        convT(outW, oWtc, 2048, 32000, cn, cn, c2 * cn);
        k_mm8<0><<<dim3(8 * (cn / 256)), 512, 131072, stream>>>(
            xb, oWtc, (float*)d_out + (size_t)c2 * cn, 2048, 2048, 2048, 32000);
    }
}

// Round 9
// 1573.214 us; speedup vs baseline: 10.8046x; 1.0707x over previous
//
#include <hip/hip_runtime.h>
#include <hip/hip_bf16.h>
#include <math.h>

#define N_TOK 2048
#define DIM   2048
#define NH    16
#define NOPE  128
#define ROPE_D 64
#define QKH   192
#define VH    128
#define KVR   512
#define INTER 5632
#define VOCAB 32000
#define NLAYER 2
#define EPS   1e-6f

typedef __hip_bfloat16 bf16;
typedef __bf16 bf16x8 __attribute__((ext_vector_type(8)));
typedef float  f32x4  __attribute__((ext_vector_type(4)));

__device__ __forceinline__ float bf2f(unsigned short u) {
    union { unsigned u; float f; } a; a.u = ((unsigned)u) << 16; return a.f;
}
__device__ __forceinline__ unsigned short f2bfu(float f) {
    union { float f; unsigned u; } a; a.f = f;
    return (unsigned short)((a.u + 0x7fffu + ((a.u >> 16) & 1u)) >> 16);
}

__device__ __forceinline__ void gload16(const void* g, void* l) {
    __builtin_amdgcn_global_load_lds((const __attribute__((address_space(1))) void*)g,
                                     (__attribute__((address_space(3))) void*)l, 16, 0, 0);
}

// ---------------- embedding gather ----------------
__global__ void k_embed(const int* __restrict__ tokens, const float* __restrict__ emb,
                        float* __restrict__ h) {
    int n = blockIdx.x;
    int t = tokens[n];
    const float4* src = (const float4*)(emb + (size_t)t * DIM);
    float4* dst = (float4*)(h + (size_t)n * DIM);
    for (int i = threadIdx.x; i < DIM / 4; i += blockDim.x) dst[i] = src[i];
}

// ---------------- rmsnorm f32 -> bf16 ----------------
__global__ __launch_bounds__(256) void k_rmsnorm(const float* __restrict__ in, int in_stride, int in_off,
                                                 bf16* __restrict__ out, const float* __restrict__ w,
                                                 int len) {
    int row = blockIdx.x;
    const float* x = in + (size_t)row * in_stride + in_off;
    float ss = 0.f;
    for (int i = threadIdx.x; i < len; i += 256) { float v = x[i]; ss += v * v; }
    for (int off = 32; off > 0; off >>= 1) ss += __shfl_down(ss, off, 64);
    __shared__ float red[4];
    if ((threadIdx.x & 63) == 0) red[threadIdx.x >> 6] = ss;
    __syncthreads();
    float tot = red[0] + red[1] + red[2] + red[3];
    float inv = rsqrtf(tot / (float)len + EPS);
    for (int i = threadIdx.x; i < len; i += 256)
        out[(size_t)row * len + i] = __float2bfloat16(x[i] * inv * w[i]);
}

// ---------------- transpose + convert: W[K][ncols] f32 -> Out[npad][K] bf16 ----------------
__global__ __launch_bounds__(256)
void k_convT(const float* __restrict__ W, bf16* __restrict__ Out,
             int K, int ldw, int ncols, int c0base, int c0step,
             long long inz, long long outz) {
    __shared__ float T[32][65];
    const float* Wz = W + (long long)blockIdx.z * inz;
    bf16* Oz = Out + (long long)blockIdx.z * outz;
    int c0 = c0base + blockIdx.z * c0step;
    int n0 = blockIdx.x * 64, k0 = blockIdx.y * 32;
    int tid = threadIdx.x;
    int rr = tid >> 4, cc = (tid & 15) * 4;
#pragma unroll
    for (int p = 0; p < 2; ++p) {
        int k = k0 + rr + p * 16;
        float4 v = make_float4(0.f, 0.f, 0.f, 0.f);
        if (n0 + cc < ncols) v = *(const float4*)(Wz + (size_t)k * ldw + c0 + n0 + cc);
        T[rr + p * 16][cc + 0] = v.x; T[rr + p * 16][cc + 1] = v.y;
        T[rr + p * 16][cc + 2] = v.z; T[rr + p * 16][cc + 3] = v.w;
    }
    __syncthreads();
    int n = tid >> 2, kc = (tid & 3) * 8;
    __align__(16) bf16 tmp[8];
#pragma unroll
    for (int e = 0; e < 8; ++e) tmp[e] = __float2bfloat16(T[kc + e][n]);
    *(int4*)(Oz + (size_t)(n0 + n) * K + k0 + kc) = *(const int4*)tmp;
}

// ---------------- bf16 MFMA GEMM, 128x128 tile, BK=32 (2-phase) ----------------
// 1-D grid, XCD-chunked swizzle: col-panel-major logical order (16 row panels fixed).
template<int OUT>
__global__ __launch_bounds__(256)
void k_mm(const bf16* __restrict__ A, const bf16* __restrict__ Bt, void* __restrict__ Cv,
          int Nreal, int K, int lda, int ldb, int ldc) {
    int cpx = gridDim.x >> 3;
    int logical = ((int)blockIdx.x & 7) * cpx + ((int)blockIdx.x >> 3);
    int row0 = (logical & 15) * 128, col0 = (logical >> 4) * 128;
    __shared__ bf16 As[128 * 32];
    __shared__ bf16 Bs[128 * 32];
    int tid = threadIdx.x;
    int lane = tid & 63, wave = tid >> 6;
    int wm = (wave & 1) * 64, wn = (wave >> 1) * 64;
    int fr = lane & 15, fg = lane >> 4;
    f32x4 acc[4][4] = {};
    for (int k0 = 0; k0 < K; k0 += 32) {
#pragma unroll
        for (int it = 0; it < 2; ++it) {
            int idx = it * 256 + tid;
            int m = idx >> 2, c = idx & 3;
            gload16(A + (size_t)(row0 + m) * lda + k0 + c * 8, As + idx * 8);
        }
#pragma unroll
        for (int it = 0; it < 2; ++it) {
            int idx = it * 256 + tid;
            int m = idx >> 2, c = idx & 3;
            gload16(Bt + (size_t)(col0 + m) * ldb + k0 + c * 8, Bs + idx * 8);
        }
        __syncthreads();
        bf16x8 av[4], bv[4];
#pragma unroll
        for (int i = 0; i < 4; ++i) {
            av[i] = *(const bf16x8*)(As + (wm + i * 16 + fr) * 32 + fg * 8);
            bv[i] = *(const bf16x8*)(Bs + (wn + i * 16 + fr) * 32 + fg * 8);
        }
#pragma unroll
        for (int i = 0; i < 4; ++i)
#pragma unroll
            for (int j = 0; j < 4; ++j)
                acc[i][j] = __builtin_amdgcn_mfma_f32_16x16x32_bf16(av[i], bv[j], acc[i][j], 0, 0, 0);
        __syncthreads();
    }
    float* Cf = (float*)Cv;
    bf16* Cb = (bf16*)Cv;
#pragma unroll
    for (int i = 0; i < 4; ++i)
#pragma unroll
        for (int j = 0; j < 4; ++j)
#pragma unroll
            for (int q = 0; q < 4; ++q) {
                int row = row0 + wm + i * 16 + fg * 4 + q;
                int col = col0 + wn + j * 16 + fr;
                if (col < Nreal) {
                    size_t off = (size_t)row * ldc + col;
                    if (OUT == 0) Cf[off] = acc[i][j][q];
                    else if (OUT == 1) Cf[off] += acc[i][j][q];
                    else Cb[off] = __float2bfloat16(acc[i][j][q]);
                }
            }
}

// ---------------- bf16 MFMA GEMM, 256x256 tile, BK=32, ring-4 LDS, 8-phase/group ----------------
#define TILE8(u, DOSTAGE, GATE) { \
    const int t = t0 + (u); \
    const bf16* sAb = sA_ + (u) * 8192; \
    const bf16* sBb = sB_ + (u) * 8192; \
    bf16* dA = sA_ + (((u) + 3) & 3) * 8192; \
    bf16* dB = sB_ + (((u) + 3) & 3) * 8192; \
    if (DOSTAGE) { \
        size_t kk = (size_t)(t + 3) * 32; \
        gload16(Ag + (size_t)(row0 + srow) * lda + kk + scol * 8, dA + tid * 8); \
        gload16(Ag + (size_t)(row0 + 128 + srow) * lda + kk + scol * 8, dA + 4096 + tid * 8); \
    } \
    bf16x8 av[8], bv0, bv1; \
    _Pragma("unroll") \
    for (int m = 0; m < 8; ++m) \
        av[m] = *(const bf16x8*)(sAb + (wm * 128 + m * 16 + fr) * 32 + swz); \
    bv0 = *(const bf16x8*)(sBb + (wn * 64 + fr) * 32 + swz); \
    bv1 = *(const bf16x8*)(sBb + (wn * 64 + 16 + fr) * 32 + swz); \
    __builtin_amdgcn_s_barrier(); \
    __builtin_amdgcn_s_setprio(1); \
    _Pragma("unroll") \
    for (int m = 0; m < 8; ++m) { \
        acc[m][0] = __builtin_amdgcn_mfma_f32_16x16x32_bf16(av[m], bv0, acc[m][0], 0, 0, 0); \
        acc[m][1] = __builtin_amdgcn_mfma_f32_16x16x32_bf16(av[m], bv1, acc[m][1], 0, 0, 0); \
    } \
    __builtin_amdgcn_s_setprio(0); \
    __builtin_amdgcn_s_barrier(); \
    if (DOSTAGE) { \
        size_t kk = (size_t)(t + 3) * 32; \
        gload16(Bg + (size_t)(col0 + srow) * ldb + kk + scol * 8, dB + tid * 8); \
        gload16(Bg + (size_t)(col0 + 128 + srow) * ldb + kk + scol * 8, dB + 4096 + tid * 8); \
    } \
    bf16x8 bv2 = *(const bf16x8*)(sBb + (wn * 64 + 32 + fr) * 32 + swz); \
    bf16x8 bv3 = *(const bf16x8*)(sBb + (wn * 64 + 48 + fr) * 32 + swz); \
    __builtin_amdgcn_s_barrier(); \
    __builtin_amdgcn_s_setprio(1); \
    _Pragma("unroll") \
    for (int m = 0; m < 8; ++m) { \
        acc[m][2] = __builtin_amdgcn_mfma_f32_16x16x32_bf16(av[m], bv2, acc[m][2], 0, 0, 0); \
        acc[m][3] = __builtin_amdgcn_mfma_f32_16x16x32_bf16(av[m], bv3, acc[m][3], 0, 0, 0); \
    } \
    __builtin_amdgcn_s_setprio(0); \
    GATE; \
    __builtin_amdgcn_s_barrier(); \
    __builtin_amdgcn_sched_barrier(0); \
}

template<int OUT>
__global__ __launch_bounds__(512, 2)
void k_mm8(const bf16* __restrict__ Ag, const bf16* __restrict__ Bg, void* __restrict__ Cv,
           int K, int lda, int ldb, int ldc) {
    extern __shared__ char smem_raw[];
    bf16* sA_ = (bf16*)smem_raw;            // 4 bufs x 256x32
    bf16* sB_ = sA_ + 4 * 8192;             // 4 bufs x 256x32
    int tid = threadIdx.x;
    int lane = tid & 63, wid = tid >> 6;
    int wm = wid >> 2, wn = wid & 3;        // 2 x 4 waves, wave tile 128x64
    int fr = lane & 15, fg = lane >> 4;
    int cpx = gridDim.x >> 3;
    int logical = ((int)blockIdx.x & 7) * cpx + ((int)blockIdx.x >> 3);
    int row0 = (logical & 7) * 256, col0 = (logical >> 3) * 256;
    int srow = tid >> 2;
    int scol = (tid & 3) ^ ((srow >> 1) & 3);            // T2 staging source slot
    int swz = (fg ^ ((fr >> 1) & 3)) * 8;                // T2 read slot (elem offset)

    f32x4 acc[8][4] = {};
    int nt = K >> 5;

#pragma unroll
    for (int t = 0; t < 3; ++t) {
        size_t kk = (size_t)t * 32;
        bf16* dA = sA_ + t * 8192;
        bf16* dB = sB_ + t * 8192;
        gload16(Ag + (size_t)(row0 + srow) * lda + kk + scol * 8, dA + tid * 8);
        gload16(Ag + (size_t)(row0 + 128 + srow) * lda + kk + scol * 8, dA + 4096 + tid * 8);
        gload16(Bg + (size_t)(col0 + srow) * ldb + kk + scol * 8, dB + tid * 8);
        gload16(Bg + (size_t)(col0 + 128 + srow) * ldb + kk + scol * 8, dB + 4096 + tid * 8);
    }
    asm volatile("s_waitcnt vmcnt(8)" ::: "memory");
    __builtin_amdgcn_s_barrier();
    __builtin_amdgcn_sched_barrier(0);

    int ngroups = nt >> 2;
    for (int g = 0; g < ngroups - 1; ++g) {
        int t0 = g * 4;
        TILE8(0, 1, asm volatile("s_waitcnt vmcnt(8)" ::: "memory"));
        TILE8(1, 1, asm volatile("s_waitcnt vmcnt(8)" ::: "memory"));
        TILE8(2, 1, asm volatile("s_waitcnt vmcnt(8)" ::: "memory"));
        TILE8(3, 1, asm volatile("s_waitcnt vmcnt(8)" ::: "memory"));
    }
    {
        int t0 = nt - 4;
        TILE8(0, 1, asm volatile("s_waitcnt vmcnt(8)" ::: "memory"));
        TILE8(1, 0, asm volatile("s_waitcnt vmcnt(4)" ::: "memory"));
        TILE8(2, 0, asm volatile("s_waitcnt vmcnt(0)" ::: "memory"));
        TILE8(3, 0, (void)0);
    }

    float* Cf = (float*)Cv;
    bf16* Cb = (bf16*)Cv;
#pragma unroll
    for (int m = 0; m < 8; ++m)
#pragma unroll
        for (int n = 0; n < 4; ++n)
#pragma unroll
            for (int q = 0; q < 4; ++q) {
                int row = row0 + wm * 128 + m * 16 + fg * 4 + q;
                int col = col0 + wn * 64 + n * 16 + fr;
                size_t off = (size_t)row * ldc + col;
                if (OUT == 0) Cf[off] = acc[m][n][q];
                else if (OUT == 1) Cf[off] += acc[m][n][q];
                else Cb[off] = __float2bfloat16(acc[m][n][q]);
            }
}

// ---------------- q rope + pack to [h][n][192] bf16; also save k-rope cols to kr ----------------
__global__ __launch_bounds__(256) void k_qpack(const float* __restrict__ q, int qstride, int kvoff,
        const float* __restrict__ cosb, const float* __restrict__ sinb,
        bf16* __restrict__ qb, float* __restrict__ kr) {
    int n = blockIdx.x;
    __shared__ float c[32], s[32];
    if (threadIdx.x < 32) {
        c[threadIdx.x] = cosb[n * 32 + threadIdx.x];
        s[threadIdx.x] = sinb[n * 32 + threadIdx.x];
    }
    __syncthreads();
    const float* row = q + (size_t)n * qstride;
    if (threadIdx.x < 64) kr[(size_t)n * 64 + threadIdx.x] = row[kvoff + threadIdx.x];
    for (int idx = threadIdx.x; idx < NH * QKH; idx += 256) {
        int h = idx / QKH, d = idx - h * QKH;
        float v;
        if (d < NOPE) v = row[idx];
        else {
            int i = (d - NOPE) >> 1;
            float xr = row[h * QKH + NOPE + 2 * i], xi = row[h * QKH + NOPE + 2 * i + 1];
            v = ((d & 1) == 0) ? xr * c[i] - xi * s[i] : xr * s[i] + xi * c[i];
        }
        qb[(size_t)h * (N_TOK * QKH) + (size_t)n * QKH + d] = __float2bfloat16(v);
    }
}

// ---------------- K pack: [h][key][192] bf16 (k-rope from kr, stride 64) ----------------
__global__ __launch_bounds__(256) void k_packK(const float* __restrict__ kvb,
        const float* __restrict__ kr,
        const float* __restrict__ cosb, const float* __restrict__ sinb,
        bf16* __restrict__ Kb) {
    int key = blockIdx.x;
    __shared__ float rp[ROPE_D];
    if (threadIdx.x < 32) {
        float c = cosb[key * 32 + threadIdx.x], s = sinb[key * 32 + threadIdx.x];
        float xr = kr[(size_t)key * 64 + 2 * threadIdx.x];
        float xi = kr[(size_t)key * 64 + 2 * threadIdx.x + 1];
        rp[2 * threadIdx.x] = xr * c - xi * s;
        rp[2 * threadIdx.x + 1] = xr * s + xi * c;
    }
    __syncthreads();
    const float* row = kvb + (size_t)key * (NH * (NOPE + VH));
    for (int idx = threadIdx.x; idx < NH * QKH; idx += 256) {
        int h = idx / QKH, d = idx - h * QKH;
        float v = (d < NOPE) ? row[h * (NOPE + VH) + d] : rp[d - NOPE];
        Kb[(size_t)h * (N_TOK * QKH) + (size_t)key * QKH + d] = __float2bfloat16(v);
    }
}

// ---------------- fused flash attention, QBLK=32, 2 waves, paired panels ----------------
// grid (NH, 32): block handles 32-row q-panels yp and 63-yp -> 33 K-tiles each.
__global__ __launch_bounds__(128, 2)
void k_flash(const bf16* __restrict__ qb, const bf16* __restrict__ Kb,
             const bf16* __restrict__ Vt, bf16* __restrict__ aout) {
    int h = blockIdx.x, yp = blockIdx.y;
    __shared__ short Ks[64 * 200];   // [key][192] pad->200
    __shared__ short Vs[128 * 72];   // [vdim][key64] pad->72
    __shared__ short Ps[32 * 72];    // [qrow][key64] pad->72
    int t = threadIdx.x;
    int lane = t & 63, w = t >> 6;
    int fr = lane & 15, fg = lane >> 4;
    const float scale = 0.07216878364870322f;  // 1/sqrt(192)
    const bf16* Kbase = Kb + (size_t)h * N_TOK * QKH;
    const bf16* Vbase = Vt + (size_t)h * VH * N_TOK;

    for (int pi = 0; pi < 2; ++pi) {
        int qp = pi ? 63 - yp : yp;
        bf16x8 aq[6];
        const bf16* Qsrc = qb + ((size_t)h * N_TOK + qp * 32 + w * 16) * QKH;
#pragma unroll
        for (int ks = 0; ks < 6; ++ks)
            aq[ks] = *(const bf16x8*)(Qsrc + (size_t)fr * QKH + ks * 32 + fg * 8);

        f32x4 acc_o[8] = {};
        float m_r[4], l_r[4];
#pragma unroll
        for (int q = 0; q < 4; ++q) { m_r[q] = -1e30f; l_r[q] = 0.f; }

        int nkt = (qp >> 1) + 1;
        for (int kt = 0; kt < nkt; ++kt) {
            __syncthreads();
            {
                const bf16* Ksrc = Kbase + (size_t)kt * 64 * QKH;
#pragma unroll
                for (int c = 0; c < 12; ++c) {
                    int idx = c * 128 + t;
                    int row = idx / 24, c16 = idx - row * 24;
                    int4 v = *(const int4*)(Ksrc + row * QKH + c16 * 8);
                    *(int4*)(Ks + row * 200 + c16 * 8) = v;
                }
                const bf16* Vsrc = Vbase + kt * 64;
#pragma unroll
                for (int c = 0; c < 8; ++c) {
                    int idx = c * 128 + t;
                    int row = idx >> 3, c8 = idx & 7;
                    int4 v = *(const int4*)(Vsrc + (size_t)row * N_TOK + c8 * 8);
                    *(int4*)(Vs + row * 72 + c8 * 8) = v;
                }
            }
            __syncthreads();
            f32x4 acc_s[4] = {};
#pragma unroll
            for (int ks = 0; ks < 6; ++ks) {
                bf16x8 bv[4];
#pragma unroll
                for (int j = 0; j < 4; ++j)
                    bv[j] = *(const bf16x8*)(Ks + (j * 16 + fr) * 200 + ks * 32 + fg * 8);
#pragma unroll
                for (int j = 0; j < 4; ++j)
                    acc_s[j] = __builtin_amdgcn_mfma_f32_16x16x32_bf16(aq[ks], bv[j], acc_s[j], 0, 0, 0);
            }
            if (kt == nkt - 1) {  // diagonal tile: causal mask
                int colb = kt * 64;
                int rowb = qp * 32 + w * 16;
#pragma unroll
                for (int j = 0; j < 4; ++j)
#pragma unroll
                    for (int q = 0; q < 4; ++q)
                        if (colb + j * 16 + fr > rowb + fg * 4 + q)
                            acc_s[j][q] = -1e30f;
            }
#pragma unroll
            for (int q = 0; q < 4; ++q) {
                float tmax = fmaxf(fmaxf(acc_s[0][q], acc_s[1][q]),
                                   fmaxf(acc_s[2][q], acc_s[3][q]));
                tmax = fmaxf(tmax, __shfl_xor(tmax, 1, 64));
                tmax = fmaxf(tmax, __shfl_xor(tmax, 2, 64));
                tmax = fmaxf(tmax, __shfl_xor(tmax, 4, 64));
                tmax = fmaxf(tmax, __shfl_xor(tmax, 8, 64));
                float mn = fmaxf(m_r[q], tmax);
                float sc = __expf(scale * (m_r[q] - mn));
                m_r[q] = mn;
                float s0 = 0.f;
#pragma unroll
                for (int j = 0; j < 4; ++j) {
                    float pv = __expf(scale * (acc_s[j][q] - mn));
                    acc_s[j][q] = pv;
                    s0 += pv;
                }
                s0 += __shfl_xor(s0, 1, 64);
                s0 += __shfl_xor(s0, 2, 64);
                s0 += __shfl_xor(s0, 4, 64);
                s0 += __shfl_xor(s0, 8, 64);
                l_r[q] = l_r[q] * sc + s0;
#pragma unroll
                for (int jo = 0; jo < 8; ++jo) acc_o[jo][q] *= sc;
            }
#pragma unroll
            for (int j = 0; j < 4; ++j)
#pragma unroll
                for (int q = 0; q < 4; ++q)
                    Ps[(w * 16 + fg * 4 + q) * 72 + j * 16 + fr] = (short)f2bfu(acc_s[j][q]);
#pragma unroll
            for (int ks2 = 0; ks2 < 2; ++ks2) {
                bf16x8 pa = *(const bf16x8*)(Ps + (w * 16 + fr) * 72 + ks2 * 32 + fg * 8);
#pragma unroll
                for (int jo = 0; jo < 8; ++jo) {
                    bf16x8 vb = *(const bf16x8*)(Vs + (jo * 16 + fr) * 72 + ks2 * 32 + fg * 8);
                    acc_o[jo] = __builtin_amdgcn_mfma_f32_16x16x32_bf16(pa, vb, acc_o[jo], 0, 0, 0);
                }
            }
        }
        bf16* obase = aout + (size_t)(qp * 32 + w * 16) * (NH * VH) + h * VH;
#pragma unroll
        for (int q = 0; q < 4; ++q) {
            float inv = 1.f / l_r[q];
#pragma unroll
            for (int jo = 0; jo < 8; ++jo)
                obase[(size_t)(fg * 4 + q) * (NH * VH) + jo * 16 + fr] =
                    __float2bfloat16(acc_o[jo][q] * inv);
        }
    }
}

// ---------------- silu on combined ffn buffer [2048][11264]: cols 0-5631 = silu(a)*b ----------------
__global__ void k_silu(bf16* __restrict__ fbig) {
    int idx = blockIdx.x * blockDim.x + threadIdx.x;   // over 2048*704
    int row = idx / 704, c8 = idx - row * 704;
    size_t base = (size_t)row * 11264 + (size_t)c8 * 8;
    uint4 ua = *(const uint4*)((const unsigned short*)fbig + base);
    uint4 ub = *(const uint4*)((const unsigned short*)fbig + base + 5632);
    unsigned* pa = &ua.x; const unsigned* pb = &ub.x;
#pragma unroll
    for (int w = 0; w < 4; ++w) {
        float x0 = bf2f((unsigned short)(pa[w] & 0xffffu));
        float x1 = bf2f((unsigned short)(pa[w] >> 16));
        float y0 = bf2f((unsigned short)(pb[w] & 0xffffu));
        float y1 = bf2f((unsigned short)(pb[w] >> 16));
        float r0 = x0 / (1.f + __expf(-x0)) * y0;
        float r1 = x1 / (1.f + __expf(-x1)) * y1;
        pa[w] = (unsigned)f2bfu(r0) | ((unsigned)f2bfu(r1) << 16);
    }
    *(uint4*)((unsigned short*)fbig + base) = ua;
}

extern "C" void kernel_launch(void* const* d_in, const int* in_sizes, int n_in,
                              void* d_out, int out_size, void* d_ws, size_t ws_size,
                              hipStream_t stream) {
    (void)in_sizes; (void)n_in; (void)out_size;
    const int* tokens = (const int*)d_in[0];
    const float* emb = (const float*)d_in[1];
    const float* qW = (const float*)d_in[2];
    const float* kvaW = (const float*)d_in[3];
    const float* kvnorm_w = (const float*)d_in[4];
    const float* kvbW = (const float*)d_in[5];
    const float* oW = (const float*)d_in[6];
    const float* w1 = (const float*)d_in[7];
    const float* w2 = (const float*)d_in[8];
    const float* w3 = (const float*)d_in[9];
    const float* attn_norm_w = (const float*)d_in[10];
    const float* ffn_norm_w = (const float*)d_in[11];
    const float* norm_w = (const float*)d_in[12];
    const float* outW = (const float*)d_in[13];
    const float* rope_cos = (const float*)d_in[14];
    const float* rope_sin = (const float*)d_in[15];

    hipFuncSetAttribute((const void*)k_mm8<0>, hipFuncAttributeMaxDynamicSharedMemorySize, 131072);
    hipFuncSetAttribute((const void*)k_mm8<2>, hipFuncAttributeMaxDynamicSharedMemorySize, 131072);

    float* ws = (float*)d_ws;
    size_t off = 0;
    auto allocF = [&](size_t fl) { float* p = ws + off; off += (fl + 63) & ~63ULL; return p; };
    float* h    = allocF(4194304);            // [2048][2048] f32
    bf16* xb    = (bf16*)allocF(2097152);     // [2048][2048] bf16
    bf16* cb    = (bf16*)allocF(524288);      // [2048][512] bf16
    float* kr   = allocF(131072);             // [2048][64] f32 (k-rope save)
    bf16* qb    = (bf16*)allocF(3145728);     // [16][2048][192] bf16
    bf16* Kb    = (bf16*)allocF(3145728);     // [16][2048][192] bf16
    bf16* Vt    = (bf16*)allocF(2097152);     // [16][128][2048] bf16
    bf16* aout  = (bf16*)allocF(2097152);     // [2048][2048] bf16
    bf16* qWt   = (bf16*)allocF(3145728);     // [3072][2048]  (contiguous with kvaWt)
    bf16* kvaWt = (bf16*)allocF(655360);      // [640][2048]
    bf16* kvbWt = (bf16*)allocF(1048576);     // [4096][512]
    bf16* oWt   = (bf16*)allocF(2097152);     // [2048][2048]
    bf16* w1t   = (bf16*)allocF(5767168);     // [5632][2048]  (contiguous with w2t)
    bf16* w2t   = (bf16*)allocF(5767168);
    bf16* w3t   = (bf16*)allocF(5767168);     // [2048][5632]
    float* scr  = ws + off;
    size_t availF = (ws_size / 4 > off) ? ws_size / 4 - off : 0;

    int oc = 25;
    {
        const int ocs[3] = {1, 5, 25};
        for (int i = 0; i < 3; ++i) {
            size_t need = 11534336;                        // fbig [2048][11264] bf16
            size_t a2 = (size_t)32768000 / ocs[i];         // outW chunk (bf16, in floats)
            if (a2 > need) need = a2;
            if (8388608 > need) need = 8388608;            // kvbf f32
            if (need <= availF) { oc = ocs[i]; break; }
        }
    }
    float* qkv  = scr;                          // [2048][3712] f32 (transient; dead before kvbf)
    float* kvbf = scr;                          // [2048][4096] f32 (transient, aliases qkv)
    bf16* fbig  = (bf16*)scr;                   // [2048][11264] bf16
    bf16* oWtc  = (bf16*)scr;                   // outW chunk [cn][2048]

    auto convT = [&](const float* W, bf16* Out, int K, int ldw, int ncols, int npad,
                     int c0) {
        dim3 g(npad / 64, K / 32, 1);
        k_convT<<<g, 256, 0, stream>>>(W, Out, K, ldw, ncols, c0, 0, 0, 0);
    };

    k_embed<<<N_TOK, 256, 0, stream>>>(tokens, emb, h);

    for (int l = 0; l < NLAYER; ++l) {
        convT(qW + (size_t)l * DIM * 3072, qWt, 2048, 3072, 3072, 3072, 0);
        convT(kvaW + (size_t)l * DIM * 576, kvaWt, 2048, 576, 576, 640, 0);
        convT(kvbW + (size_t)l * 512 * 4096, kvbWt, 512, 4096, 4096, 4096, 0);
        convT(oW + (size_t)l * 2048 * 2048, oWt, 2048, 2048, 2048, 2048, 0);
        convT(w1 + (size_t)l * DIM * INTER, w1t, 2048, 5632, 5632, 5632, 0);
        convT(w2 + (size_t)l * DIM * INTER, w2t, 2048, 5632, 5632, 5632, 0);
        convT(w3 + (size_t)l * INTER * DIM, w3t, 5632, 2048, 2048, 2048, 0);

        k_rmsnorm<<<N_TOK, 256, 0, stream>>>(h, 2048, 0, xb, attn_norm_w + (size_t)l * DIM, 2048);
        // merged q + kva projection: N = 3072 + 640 = 3712
        k_mm<0><<<dim3(464), 256, 0, stream>>>(xb, qWt, qkv, 3712, 2048, 2048, 2048, 3712);
        // qpack also snapshots k-rope cols (qkv[.., 3072..3135]) into kr BEFORE qkv is reused
        k_qpack<<<N_TOK, 256, 0, stream>>>(qkv, 3712, 3072, rope_cos, rope_sin, qb, kr);
        k_rmsnorm<<<N_TOK, 256, 0, stream>>>(qkv, 3712, 3072 + 64, cb, kvnorm_w + (size_t)l * KVR, 512);
        // qkv now dead; kvbf may alias it
        k_mm<0><<<dim3(512), 256, 0, stream>>>(cb, kvbWt, kvbf, 4096, 512, 512, 512, 4096);
        k_packK<<<N_TOK, 256, 0, stream>>>(kvbf, kr, rope_cos, rope_sin, Kb);
        {   // V^T per head: [128][2048] bf16 (cols h*256+128 of kvbf)
            dim3 g(2, 64, 16);
            k_convT<<<g, 256, 0, stream>>>(kvbf, Vt, 2048, 4096, 128, 128, 256, 0,
                                           (long long)128 * 2048);
        }
        k_flash<<<dim3(NH, 32), 128, 0, stream>>>(qb, Kb, Vt, aout);
        k_mm<1><<<dim3(256), 256, 0, stream>>>(aout, oWt, h, 2048, 2048, 2048, 2048, 2048);

        k_rmsnorm<<<N_TOK, 256, 0, stream>>>(h, 2048, 0, xb, ffn_norm_w + (size_t)l * DIM, 2048);
        // merged w1 + w2: N = 11264 -> fbig
        k_mm8<2><<<dim3(352), 512, 131072, stream>>>(xb, w1t, fbig, 2048, 2048, 2048, 11264);
        k_silu<<<2048 * 704 / 256, 256, 0, stream>>>(fbig);
        k_mm<1><<<dim3(256), 256, 0, stream>>>(fbig, w3t, h, 2048, 5632, 11264, 5632, 2048);
    }
    k_rmsnorm<<<N_TOK, 256, 0, stream>>>(h, 2048, 0, xb, norm_w, 2048);
    int cn = 32000 / oc;
    for (int c2 = 0; c2 < oc; ++c2) {
        convT(outW, oWtc, 2048, 32000, cn, cn, c2 * cn);
        k_mm8<0><<<dim3(8 * (cn / 256)), 512, 131072, stream>>>(
            xb, oWtc, (float*)d_out + (size_t)c2 * cn, 2048, 2048, 2048, 32000);
    }
}

// Round 10
// 1525.013 us; speedup vs baseline: 11.1461x; 1.0316x over previous
//
#include <hip/hip_runtime.h>
#include <hip/hip_bf16.h>
#include <math.h>

#define N_TOK 2048
#define DIM   2048
#define NH    16
#define NOPE  128
#define ROPE_D 64
#define QKH   192
#define VH    128
#define KVR   512
#define INTER 5632
#define VOCAB 32000
#define NLAYER 2
#define EPS   1e-6f

typedef __hip_bfloat16 bf16;
typedef __bf16 bf16x8 __attribute__((ext_vector_type(8)));
typedef float  f32x4  __attribute__((ext_vector_type(4)));

__device__ __forceinline__ float bf2f(unsigned short u) {
    union { unsigned u; float f; } a; a.u = ((unsigned)u) << 16; return a.f;
}
__device__ __forceinline__ unsigned short f2bfu(float f) {
    union { float f; unsigned u; } a; a.f = f;
    return (unsigned short)((a.u + 0x7fffu + ((a.u >> 16) & 1u)) >> 16);
}

__device__ __forceinline__ void gload16(const void* g, void* l) {
    __builtin_amdgcn_global_load_lds((const __attribute__((address_space(1))) void*)g,
                                     (__attribute__((address_space(3))) void*)l, 16, 0, 0);
}

// ---------------- embedding gather ----------------
__global__ void k_embed(const int* __restrict__ tokens, const float* __restrict__ emb,
                        float* __restrict__ h) {
    int n = blockIdx.x;
    int t = tokens[n];
    const float4* src = (const float4*)(emb + (size_t)t * DIM);
    float4* dst = (float4*)(h + (size_t)n * DIM);
    for (int i = threadIdx.x; i < DIM / 4; i += blockDim.x) dst[i] = src[i];
}

// ---------------- rmsnorm f32 -> bf16 ----------------
__global__ __launch_bounds__(256) void k_rmsnorm(const float* __restrict__ in, int in_stride, int in_off,
                                                 bf16* __restrict__ out, const float* __restrict__ w,
                                                 int len) {
    int row = blockIdx.x;
    const float* x = in + (size_t)row * in_stride + in_off;
    float ss = 0.f;
    for (int i = threadIdx.x; i < len; i += 256) { float v = x[i]; ss += v * v; }
    for (int off = 32; off > 0; off >>= 1) ss += __shfl_down(ss, off, 64);
    __shared__ float red[4];
    if ((threadIdx.x & 63) == 0) red[threadIdx.x >> 6] = ss;
    __syncthreads();
    float tot = red[0] + red[1] + red[2] + red[3];
    float inv = rsqrtf(tot / (float)len + EPS);
    for (int i = threadIdx.x; i < len; i += 256)
        out[(size_t)row * len + i] = __float2bfloat16(x[i] * inv * w[i]);
}

// ---------------- transpose + convert: W[K][ncols] f32 -> Out bf16 ----------------
// ilv < 0: Out[n][K] plain. ilv >= 0: phys row = ((n>>4)<<5) + (n&15) + ilv  (w1/w2 16-col interleave).
__global__ __launch_bounds__(256)
void k_convT(const float* __restrict__ W, bf16* __restrict__ Out,
             int K, int ldw, int ncols, int c0, int ilv) {
    __shared__ float T[32][65];
    int n0 = blockIdx.x * 64, k0 = blockIdx.y * 32;
    int tid = threadIdx.x;
    int rr = tid >> 4, cc = (tid & 15) * 4;
#pragma unroll
    for (int p = 0; p < 2; ++p) {
        int k = k0 + rr + p * 16;
        float4 v = make_float4(0.f, 0.f, 0.f, 0.f);
        if (n0 + cc < ncols) v = *(const float4*)(W + (size_t)k * ldw + c0 + n0 + cc);
        T[rr + p * 16][cc + 0] = v.x; T[rr + p * 16][cc + 1] = v.y;
        T[rr + p * 16][cc + 2] = v.z; T[rr + p * 16][cc + 3] = v.w;
    }
    __syncthreads();
    int n = tid >> 2, kc = (tid & 3) * 8;
    __align__(16) bf16 tmp[8];
#pragma unroll
    for (int e = 0; e < 8; ++e) tmp[e] = __float2bfloat16(T[kc + e][n]);
    int nl = n0 + n;
    int prow = (ilv < 0) ? nl : (((nl >> 4) << 5) + (nl & 15) + ilv);
    *(int4*)(Out + (size_t)prow * K + k0 + kc) = *(const int4*)tmp;
}

// ---------------- bf16 transpose: in[z][K][ncols] -> out[z][ncols][K] (bf16) ----------------
__global__ __launch_bounds__(256)
void k_tr16(const bf16* __restrict__ in, bf16* __restrict__ out, int K, int ncols) {
    __shared__ short T[32][68];
    const bf16* iz = in + (size_t)blockIdx.z * K * ncols;
    bf16* oz = out + (size_t)blockIdx.z * K * ncols;
    int n0 = blockIdx.x * 64, k0 = blockIdx.y * 32;
    int tid = threadIdx.x;
    int rr = tid >> 4, cc = (tid & 15) * 4;
#pragma unroll
    for (int p = 0; p < 2; ++p) {
        int k = k0 + rr + p * 16;
        short4 v = *(const short4*)(iz + (size_t)k * ncols + n0 + cc);
        T[rr + p * 16][cc + 0] = v.x; T[rr + p * 16][cc + 1] = v.y;
        T[rr + p * 16][cc + 2] = v.z; T[rr + p * 16][cc + 3] = v.w;
    }
    __syncthreads();
    int n = tid >> 2, kc = (tid & 3) * 8;
    __align__(16) short tmp[8];
#pragma unroll
    for (int e = 0; e < 8; ++e) tmp[e] = T[kc + e][n];
    *(int4*)(oz + (size_t)(n0 + n) * K + k0 + kc) = *(const int4*)tmp;
}

// ---------------- bf16 MFMA GEMM, 128x128 tile, BK=32 (2-phase) ----------------
// OUT: 0=f32 store, 1=f32 +=, 4=split pack (Cv=Kb bf16 [h][key][192] nope, Cv2=Vkd bf16 [h][key][128]).
template<int OUT>
__global__ __launch_bounds__(256)
void k_mm(const bf16* __restrict__ A, const bf16* __restrict__ Bt, void* __restrict__ Cv,
          void* __restrict__ Cv2, int Nreal, int K, int lda, int ldb, int ldc) {
    int cpx = gridDim.x >> 3;
    int logical = ((int)blockIdx.x & 7) * cpx + ((int)blockIdx.x >> 3);
    int row0 = (logical & 15) * 128, col0 = (logical >> 4) * 128;
    __shared__ bf16 As[128 * 32];
    __shared__ bf16 Bs[128 * 32];
    int tid = threadIdx.x;
    int lane = tid & 63, wave = tid >> 6;
    int wm = (wave & 1) * 64, wn = (wave >> 1) * 64;
    int fr = lane & 15, fg = lane >> 4;
    f32x4 acc[4][4] = {};
    for (int k0 = 0; k0 < K; k0 += 32) {
#pragma unroll
        for (int it = 0; it < 2; ++it) {
            int idx = it * 256 + tid;
            int m = idx >> 2, c = idx & 3;
            gload16(A + (size_t)(row0 + m) * lda + k0 + c * 8, As + idx * 8);
        }
#pragma unroll
        for (int it = 0; it < 2; ++it) {
            int idx = it * 256 + tid;
            int m = idx >> 2, c = idx & 3;
            gload16(Bt + (size_t)(col0 + m) * ldb + k0 + c * 8, Bs + idx * 8);
        }
        __syncthreads();
        bf16x8 av[4], bv[4];
#pragma unroll
        for (int i = 0; i < 4; ++i) {
            av[i] = *(const bf16x8*)(As + (wm + i * 16 + fr) * 32 + fg * 8);
            bv[i] = *(const bf16x8*)(Bs + (wn + i * 16 + fr) * 32 + fg * 8);
        }
#pragma unroll
        for (int i = 0; i < 4; ++i)
#pragma unroll
            for (int j = 0; j < 4; ++j)
                acc[i][j] = __builtin_amdgcn_mfma_f32_16x16x32_bf16(av[i], bv[j], acc[i][j], 0, 0, 0);
        __syncthreads();
    }
    float* Cf = (float*)Cv;
    bf16* Kbp = (bf16*)Cv;
    bf16* Vp = (bf16*)Cv2;
#pragma unroll
    for (int i = 0; i < 4; ++i)
#pragma unroll
        for (int j = 0; j < 4; ++j)
#pragma unroll
            for (int q = 0; q < 4; ++q) {
                int row = row0 + wm + i * 16 + fg * 4 + q;
                int col = col0 + wn + j * 16 + fr;
                if (col < Nreal) {
                    if (OUT == 0) Cf[(size_t)row * ldc + col] = acc[i][j][q];
                    else if (OUT == 1) Cf[(size_t)row * ldc + col] += acc[i][j][q];
                    else {  // OUT == 4: kvb pack
                        int head = col >> 8, d = col & 255;
                        if (d < NOPE)
                            Kbp[(size_t)head * N_TOK * QKH + (size_t)row * QKH + d] =
                                __float2bfloat16(acc[i][j][q]);
                        else
                            Vp[(size_t)head * N_TOK * VH + (size_t)row * VH + (d - NOPE)] =
                                __float2bfloat16(acc[i][j][q]);
                    }
                }
            }
}

// ---------------- bf16 MFMA GEMM, 256x256 tile, BK=32, ring-4 LDS, 8-phase/group ----------------
#define TILE8(u, DOSTAGE, GATE) { \
    const int t = t0 + (u); \
    const bf16* sAb = sA_ + (u) * 8192; \
    const bf16* sBb = sB_ + (u) * 8192; \
    bf16* dA = sA_ + (((u) + 3) & 3) * 8192; \
    bf16* dB = sB_ + (((u) + 3) & 3) * 8192; \
    if (DOSTAGE) { \
        size_t kk = (size_t)(t + 3) * 32; \
        gload16(Ag + (size_t)(row0 + srow) * lda + kk + scol * 8, dA + tid * 8); \
        gload16(Ag + (size_t)(row0 + 128 + srow) * lda + kk + scol * 8, dA + 4096 + tid * 8); \
    } \
    bf16x8 av[8], bv0, bv1; \
    _Pragma("unroll") \
    for (int m = 0; m < 8; ++m) \
        av[m] = *(const bf16x8*)(sAb + (wm * 128 + m * 16 + fr) * 32 + swz); \
    bv0 = *(const bf16x8*)(sBb + (wn * 64 + fr) * 32 + swz); \
    bv1 = *(const bf16x8*)(sBb + (wn * 64 + 16 + fr) * 32 + swz); \
    __builtin_amdgcn_s_barrier(); \
    __builtin_amdgcn_s_setprio(1); \
    _Pragma("unroll") \
    for (int m = 0; m < 8; ++m) { \
        acc[m][0] = __builtin_amdgcn_mfma_f32_16x16x32_bf16(av[m], bv0, acc[m][0], 0, 0, 0); \
        acc[m][1] = __builtin_amdgcn_mfma_f32_16x16x32_bf16(av[m], bv1, acc[m][1], 0, 0, 0); \
    } \
    __builtin_amdgcn_s_setprio(0); \
    __builtin_amdgcn_s_barrier(); \
    if (DOSTAGE) { \
        size_t kk = (size_t)(t + 3) * 32; \
        gload16(Bg + (size_t)(col0 + srow) * ldb + kk + scol * 8, dB + tid * 8); \
        gload16(Bg + (size_t)(col0 + 128 + srow) * ldb + kk + scol * 8, dB + 4096 + tid * 8); \
    } \
    bf16x8 bv2 = *(const bf16x8*)(sBb + (wn * 64 + 32 + fr) * 32 + swz); \
    bf16x8 bv3 = *(const bf16x8*)(sBb + (wn * 64 + 48 + fr) * 32 + swz); \
    __builtin_amdgcn_s_barrier(); \
    __builtin_amdgcn_s_setprio(1); \
    _Pragma("unroll") \
    for (int m = 0; m < 8; ++m) { \
        acc[m][2] = __builtin_amdgcn_mfma_f32_16x16x32_bf16(av[m], bv2, acc[m][2], 0, 0, 0); \
        acc[m][3] = __builtin_amdgcn_mfma_f32_16x16x32_bf16(av[m], bv3, acc[m][3], 0, 0, 0); \
    } \
    __builtin_amdgcn_s_setprio(0); \
    GATE; \
    __builtin_amdgcn_s_barrier(); \
    __builtin_amdgcn_sched_barrier(0); \
}

// OUT: 0 = f32 store (ldc), 3 = fused silu on interleaved w1w2 -> bf16 [M][5632] (ldc=5632)
template<int OUT>
__global__ __launch_bounds__(512, 2)
void k_mm8(const bf16* __restrict__ Ag, const bf16* __restrict__ Bg, void* __restrict__ Cv,
           int K, int lda, int ldb, int ldc) {
    extern __shared__ char smem_raw[];
    bf16* sA_ = (bf16*)smem_raw;            // 4 bufs x 256x32
    bf16* sB_ = sA_ + 4 * 8192;             // 4 bufs x 256x32
    int tid = threadIdx.x;
    int lane = tid & 63, wid = tid >> 6;
    int wm = wid >> 2, wn = wid & 3;        // 2 x 4 waves, wave tile 128x64
    int fr = lane & 15, fg = lane >> 4;
    int cpx = gridDim.x >> 3;
    int logical = ((int)blockIdx.x & 7) * cpx + ((int)blockIdx.x >> 3);
    int row0 = (logical & 7) * 256, col0 = (logical >> 3) * 256;
    int srow = tid >> 2;
    int scol = (tid & 3) ^ ((srow >> 1) & 3);            // T2 staging source slot
    int swz = (fg ^ ((fr >> 1) & 3)) * 8;                // T2 read slot (elem offset)

    f32x4 acc[8][4] = {};
    int nt = K >> 5;

#pragma unroll
    for (int t = 0; t < 3; ++t) {
        size_t kk = (size_t)t * 32;
        bf16* dA = sA_ + t * 8192;
        bf16* dB = sB_ + t * 8192;
        gload16(Ag + (size_t)(row0 + srow) * lda + kk + scol * 8, dA + tid * 8);
        gload16(Ag + (size_t)(row0 + 128 + srow) * lda + kk + scol * 8, dA + 4096 + tid * 8);
        gload16(Bg + (size_t)(col0 + srow) * ldb + kk + scol * 8, dB + tid * 8);
        gload16(Bg + (size_t)(col0 + 128 + srow) * ldb + kk + scol * 8, dB + 4096 + tid * 8);
    }
    asm volatile("s_waitcnt vmcnt(8)" ::: "memory");
    __builtin_amdgcn_s_barrier();
    __builtin_amdgcn_sched_barrier(0);

    int ngroups = nt >> 2;
    for (int g = 0; g < ngroups - 1; ++g) {
        int t0 = g * 4;
        TILE8(0, 1, asm volatile("s_waitcnt vmcnt(8)" ::: "memory"));
        TILE8(1, 1, asm volatile("s_waitcnt vmcnt(8)" ::: "memory"));
        TILE8(2, 1, asm volatile("s_waitcnt vmcnt(8)" ::: "memory"));
        TILE8(3, 1, asm volatile("s_waitcnt vmcnt(8)" ::: "memory"));
    }
    {
        int t0 = nt - 4;
        TILE8(0, 1, asm volatile("s_waitcnt vmcnt(8)" ::: "memory"));
        TILE8(1, 0, asm volatile("s_waitcnt vmcnt(4)" ::: "memory"));
        TILE8(2, 0, asm volatile("s_waitcnt vmcnt(0)" ::: "memory"));
        TILE8(3, 0, (void)0);
    }

    if (OUT == 0) {
        float* Cf = (float*)Cv;
#pragma unroll
        for (int m = 0; m < 8; ++m)
#pragma unroll
            for (int n = 0; n < 4; ++n)
#pragma unroll
                for (int q = 0; q < 4; ++q) {
                    int row = row0 + wm * 128 + m * 16 + fg * 4 + q;
                    int col = col0 + wn * 64 + n * 16 + fr;
                    Cf[(size_t)row * ldc + col] = acc[m][n][q];
                }
    } else {  // OUT == 3: silu(w1)*w2 fused, interleaved-16 layout -> bf16
        bf16* Cb = (bf16*)Cv;
#pragma unroll
        for (int m = 0; m < 8; ++m)
#pragma unroll
            for (int p2 = 0; p2 < 2; ++p2)
#pragma unroll
                for (int q = 0; q < 4; ++q) {
                    int row = row0 + wm * 128 + m * 16 + fg * 4 + q;
                    int col = (col0 >> 1) + wn * 32 + p2 * 16 + fr;
                    float a = acc[m][2 * p2][q], b = acc[m][2 * p2 + 1][q];
                    float r = a / (1.f + __expf(-a)) * b;
                    Cb[(size_t)row * ldc + col] = __float2bfloat16(r);
                }
    }
}

// ---------------- q rope + pack to [h][n][192] bf16; also write rope'd K to all heads ----------------
__global__ __launch_bounds__(256) void k_qpack(const float* __restrict__ q, int qstride, int kvoff,
        const float* __restrict__ cosb, const float* __restrict__ sinb,
        bf16* __restrict__ qb, bf16* __restrict__ Kb) {
    int n = blockIdx.x;
    __shared__ float c[32], s[32];
    if (threadIdx.x < 32) {
        c[threadIdx.x] = cosb[n * 32 + threadIdx.x];
        s[threadIdx.x] = sinb[n * 32 + threadIdx.x];
    }
    __syncthreads();
    const float* row = q + (size_t)n * qstride;
    if (threadIdx.x < 32) {
        int i = threadIdx.x;
        float xr = row[kvoff + 2 * i], xi = row[kvoff + 2 * i + 1];
        float r0 = xr * c[i] - xi * s[i];
        float r1 = xr * s[i] + xi * c[i];
        unsigned pk = (unsigned)f2bfu(r0) | ((unsigned)f2bfu(r1) << 16);
#pragma unroll
        for (int hh = 0; hh < NH; ++hh)
            *(unsigned*)(Kb + (size_t)hh * N_TOK * QKH + (size_t)n * QKH + NOPE + 2 * i) = pk;
    }
    for (int idx = threadIdx.x; idx < NH * QKH; idx += 256) {
        int h = idx / QKH, d = idx - h * QKH;
        float v;
        if (d < NOPE) v = row[idx];
        else {
            int i = (d - NOPE) >> 1;
            float xr = row[h * QKH + NOPE + 2 * i], xi = row[h * QKH + NOPE + 2 * i + 1];
            v = ((d & 1) == 0) ? xr * c[i] - xi * s[i] : xr * s[i] + xi * c[i];
        }
        qb[(size_t)h * (N_TOK * QKH) + (size_t)n * QKH + d] = __float2bfloat16(v);
    }
}

// ---------------- fused flash attention, QBLK=32, 2 waves, paired panels ----------------
__global__ __launch_bounds__(128, 2)
void k_flash(const bf16* __restrict__ qb, const bf16* __restrict__ Kb,
             const bf16* __restrict__ Vt, bf16* __restrict__ aout) {
    int h = blockIdx.x, yp = blockIdx.y;
    __shared__ short Ks[64 * 200];   // [key][192] pad->200
    __shared__ short Vs[128 * 72];   // [vdim][key64] pad->72
    __shared__ short Ps[32 * 72];    // [qrow][key64] pad->72
    int t = threadIdx.x;
    int lane = t & 63, w = t >> 6;
    int fr = lane & 15, fg = lane >> 4;
    const float scale = 0.07216878364870322f;  // 1/sqrt(192)
    const bf16* Kbase = Kb + (size_t)h * N_TOK * QKH;
    const bf16* Vbase = Vt + (size_t)h * VH * N_TOK;

    for (int pi = 0; pi < 2; ++pi) {
        int qp = pi ? 63 - yp : yp;
        bf16x8 aq[6];
        const bf16* Qsrc = qb + ((size_t)h * N_TOK + qp * 32 + w * 16) * QKH;
#pragma unroll
        for (int ks = 0; ks < 6; ++ks)
            aq[ks] = *(const bf16x8*)(Qsrc + (size_t)fr * QKH + ks * 32 + fg * 8);

        f32x4 acc_o[8] = {};
        float m_r[4], l_r[4];
#pragma unroll
        for (int q = 0; q < 4; ++q) { m_r[q] = -1e30f; l_r[q] = 0.f; }

        int nkt = (qp >> 1) + 1;
        for (int kt = 0; kt < nkt; ++kt) {
            __syncthreads();
            {
                const bf16* Ksrc = Kbase + (size_t)kt * 64 * QKH;
#pragma unroll
                for (int c = 0; c < 12; ++c) {
                    int idx = c * 128 + t;
                    int row = idx / 24, c16 = idx - row * 24;
                    int4 v = *(const int4*)(Ksrc + row * QKH + c16 * 8);
                    *(int4*)(Ks + row * 200 + c16 * 8) = v;
                }
                const bf16* Vsrc = Vbase + kt * 64;
#pragma unroll
                for (int c = 0; c < 8; ++c) {
                    int idx = c * 128 + t;
                    int row = idx >> 3, c8 = idx & 7;
                    int4 v = *(const int4*)(Vsrc + (size_t)row * N_TOK + c8 * 8);
                    *(int4*)(Vs + row * 72 + c8 * 8) = v;
                }
            }
            __syncthreads();
            f32x4 acc_s[4] = {};
#pragma unroll
            for (int ks = 0; ks < 6; ++ks) {
                bf16x8 bv[4];
#pragma unroll
                for (int j = 0; j < 4; ++j)
                    bv[j] = *(const bf16x8*)(Ks + (j * 16 + fr) * 200 + ks * 32 + fg * 8);
#pragma unroll
                for (int j = 0; j < 4; ++j)
                    acc_s[j] = __builtin_amdgcn_mfma_f32_16x16x32_bf16(aq[ks], bv[j], acc_s[j], 0, 0, 0);
            }
            if (kt == nkt - 1) {  // diagonal tile: causal mask
                int colb = kt * 64;
                int rowb = qp * 32 + w * 16;
#pragma unroll
                for (int j = 0; j < 4; ++j)
#pragma unroll
                    for (int q = 0; q < 4; ++q)
                        if (colb + j * 16 + fr > rowb + fg * 4 + q)
                            acc_s[j][q] = -1e30f;
            }
#pragma unroll
            for (int q = 0; q < 4; ++q) {
                float tmax = fmaxf(fmaxf(acc_s[0][q], acc_s[1][q]),
                                   fmaxf(acc_s[2][q], acc_s[3][q]));
                tmax = fmaxf(tmax, __shfl_xor(tmax, 1, 64));
                tmax = fmaxf(tmax, __shfl_xor(tmax, 2, 64));
                tmax = fmaxf(tmax, __shfl_xor(tmax, 4, 64));
                tmax = fmaxf(tmax, __shfl_xor(tmax, 8, 64));
                float mn = fmaxf(m_r[q], tmax);
                float sc = __expf(scale * (m_r[q] - mn));
                m_r[q] = mn;
                float s0 = 0.f;
#pragma unroll
                for (int j = 0; j < 4; ++j) {
                    float pv = __expf(scale * (acc_s[j][q] - mn));
                    acc_s[j][q] = pv;
                    s0 += pv;
                }
                s0 += __shfl_xor(s0, 1, 64);
                s0 += __shfl_xor(s0, 2, 64);
                s0 += __shfl_xor(s0, 4, 64);
                s0 += __shfl_xor(s0, 8, 64);
                l_r[q] = l_r[q] * sc + s0;
#pragma unroll
                for (int jo = 0; jo < 8; ++jo) acc_o[jo][q] *= sc;
            }
#pragma unroll
            for (int j = 0; j < 4; ++j)
#pragma unroll
                for (int q = 0; q < 4; ++q)
                    Ps[(w * 16 + fg * 4 + q) * 72 + j * 16 + fr] = (short)f2bfu(acc_s[j][q]);
#pragma unroll
            for (int ks2 = 0; ks2 < 2; ++ks2) {
                bf16x8 pa = *(const bf16x8*)(Ps + (w * 16 + fr) * 72 + ks2 * 32 + fg * 8);
#pragma unroll
                for (int jo = 0; jo < 8; ++jo) {
                    bf16x8 vb = *(const bf16x8*)(Vs + (jo * 16 + fr) * 72 + ks2 * 32 + fg * 8);
                    acc_o[jo] = __builtin_amdgcn_mfma_f32_16x16x32_bf16(pa, vb, acc_o[jo], 0, 0, 0);
                }
            }
        }
        bf16* obase = aout + (size_t)(qp * 32 + w * 16) * (NH * VH) + h * VH;
#pragma unroll
        for (int q = 0; q < 4; ++q) {
            float inv = 1.f / l_r[q];
#pragma unroll
            for (int jo = 0; jo < 8; ++jo)
                obase[(size_t)(fg * 4 + q) * (NH * VH) + jo * 16 + fr] =
                    __float2bfloat16(acc_o[jo][q] * inv);
        }
    }
}

extern "C" void kernel_launch(void* const* d_in, const int* in_sizes, int n_in,
                              void* d_out, int out_size, void* d_ws, size_t ws_size,
                              hipStream_t stream) {
    (void)in_sizes; (void)n_in; (void)out_size;
    const int* tokens = (const int*)d_in[0];
    const float* emb = (const float*)d_in[1];
    const float* qW = (const float*)d_in[2];
    const float* kvaW = (const float*)d_in[3];
    const float* kvnorm_w = (const float*)d_in[4];
    const float* kvbW = (const float*)d_in[5];
    const float* oW = (const float*)d_in[6];
    const float* w1 = (const float*)d_in[7];
    const float* w2 = (const float*)d_in[8];
    const float* w3 = (const float*)d_in[9];
    const float* attn_norm_w = (const float*)d_in[10];
    const float* ffn_norm_w = (const float*)d_in[11];
    const float* norm_w = (const float*)d_in[12];
    const float* outW = (const float*)d_in[13];
    const float* rope_cos = (const float*)d_in[14];
    const float* rope_sin = (const float*)d_in[15];

    hipFuncSetAttribute((const void*)k_mm8<0>, hipFuncAttributeMaxDynamicSharedMemorySize, 131072);
    hipFuncSetAttribute((const void*)k_mm8<3>, hipFuncAttributeMaxDynamicSharedMemorySize, 131072);

    float* ws = (float*)d_ws;
    size_t off = 0;
    auto allocF = [&](size_t fl) { float* p = ws + off; off += (fl + 63) & ~63ULL; return p; };
    float* h    = allocF(4194304);            // [2048][2048] f32
    bf16* xb    = (bf16*)allocF(2097152);     // [2048][2048] bf16
    bf16* cb    = (bf16*)allocF(524288);      // [2048][512] bf16
    bf16* qb    = (bf16*)allocF(3145728);     // [16][2048][192] bf16
    bf16* Kb    = (bf16*)allocF(3145728);     // [16][2048][192] bf16
    bf16* Vkd   = (bf16*)allocF(2097152);     // [16][2048][128] bf16
    bf16* Vt    = (bf16*)allocF(2097152);     // [16][128][2048] bf16
    bf16* aout  = (bf16*)allocF(2097152);     // [2048][2048] bf16
    bf16* qWt   = (bf16*)allocF(3145728);     // [3072][2048] (contiguous with kvaWt)
    bf16* kvaWt = (bf16*)allocF(655360);      // [640][2048]
    bf16* kvbWt = (bf16*)allocF(1048576);     // [4096][512]
    bf16* oWt   = (bf16*)allocF(2097152);     // [2048][2048]
    bf16* w12t  = (bf16*)allocF(11534336);    // [11264][2048] interleaved w1/w2
    bf16* w3t   = (bf16*)allocF(5767168);     // [2048][5632]
    float* scr  = ws + off;
    size_t availF = (ws_size / 4 > off) ? ws_size / 4 - off : 0;

    int oc = 25;
    {
        const int ocs[3] = {1, 5, 25};
        for (int i = 0; i < 3; ++i) {
            size_t need = 7602176;                         // qkv [2048][3712] f32
            size_t a2 = (size_t)32768000 / ocs[i];         // outW chunk (bf16, in floats)
            if (a2 > need) need = a2;
            if (5767168 > need) need = 5767168;            // fbig [2048][5632] bf16
            if (need <= availF) { oc = ocs[i]; break; }
        }
    }
    float* qkv  = scr;                          // [2048][3712] f32 (dead after rmsnorm->cb)
    bf16* fbig  = (bf16*)scr;                   // [2048][5632] bf16
    bf16* oWtc  = (bf16*)scr;                   // outW chunk [cn][2048]

    auto convT = [&](const float* W, bf16* Out, int K, int ldw, int ncols, int npad,
                     int c0, int ilv) {
        dim3 g(npad / 64, K / 32, 1);
        k_convT<<<g, 256, 0, stream>>>(W, Out, K, ldw, ncols, c0, ilv);
    };

    k_embed<<<N_TOK, 256, 0, stream>>>(tokens, emb, h);

    for (int l = 0; l < NLAYER; ++l) {
        convT(qW + (size_t)l * DIM * 3072, qWt, 2048, 3072, 3072, 3072, 0, -1);
        convT(kvaW + (size_t)l * DIM * 576, kvaWt, 2048, 576, 576, 640, 0, -1);
        convT(kvbW + (size_t)l * 512 * 4096, kvbWt, 512, 4096, 4096, 4096, 0, -1);
        convT(oW + (size_t)l * 2048 * 2048, oWt, 2048, 2048, 2048, 2048, 0, -1);
        convT(w1 + (size_t)l * DIM * INTER, w12t, 2048, 5632, 5632, 5632, 0, 0);
        convT(w2 + (size_t)l * DIM * INTER, w12t, 2048, 5632, 5632, 5632, 0, 16);
        convT(w3 + (size_t)l * INTER * DIM, w3t, 5632, 2048, 2048, 2048, 0, -1);

        k_rmsnorm<<<N_TOK, 256, 0, stream>>>(h, 2048, 0, xb, attn_norm_w + (size_t)l * DIM, 2048);
        // merged q + kva projection: N = 3072 + 640 = 3712
        k_mm<0><<<dim3(464), 256, 0, stream>>>(xb, qWt, qkv, nullptr, 3712, 2048, 2048, 2048, 3712);
        // qpack: q rope + pack, and broadcast rope'd K (qkv cols 3072..3135) into Kb[.., 128..191]
        k_qpack<<<N_TOK, 256, 0, stream>>>(qkv, 3712, 3072, rope_cos, rope_sin, qb, Kb);
        k_rmsnorm<<<N_TOK, 256, 0, stream>>>(qkv, 3712, 3072 + 64, cb, kvnorm_w + (size_t)l * KVR, 512);
        // qkv now dead; kvb GEMM writes Kb-nope + Vkd directly (OUT=4)
        k_mm<4><<<dim3(512), 256, 0, stream>>>(cb, kvbWt, Kb, Vkd, 4096, 512, 512, 512, 0);
        k_tr16<<<dim3(2, 64, 16), 256, 0, stream>>>(Vkd, Vt, 2048, 128);
        k_flash<<<dim3(NH, 32), 128, 0, stream>>>(qb, Kb, Vt, aout);
        k_mm<1><<<dim3(256), 256, 0, stream>>>(aout, oWt, h, nullptr, 2048, 2048, 2048, 2048, 2048);

        k_rmsnorm<<<N_TOK, 256, 0, stream>>>(h, 2048, 0, xb, ffn_norm_w + (size_t)l * DIM, 2048);
        // merged w1+w2 (interleaved) with fused silu epilogue -> fbig [2048][5632] bf16
        k_mm8<3><<<dim3(352), 512, 131072, stream>>>(xb, w12t, fbig, 2048, 2048, 2048, 5632);
        k_mm<1><<<dim3(256), 256, 0, stream>>>(fbig, w3t, h, nullptr, 2048, 5632, 5632, 5632, 2048);
    }
    k_rmsnorm<<<N_TOK, 256, 0, stream>>>(h, 2048, 0, xb, norm_w, 2048);
    int cn = 32000 / oc;
    for (int c2 = 0; c2 < oc; ++c2) {
        convT(outW, oWtc, 2048, 32000, cn, cn, c2 * cn, -1);
        k_mm8<0><<<dim3(8 * (cn / 256)), 512, 131072, stream>>>(
            xb, oWtc, (float*)d_out + (size_t)c2 * cn, 2048, 2048, 2048, 32000);
    }
}